// Round 1
// baseline (2840.138 us; speedup 1.0000x reference)
//
#include <hip/hip_runtime.h>
#include <cstddef>
#include <cstdint>

#define N_TOK 1024
#define D_MODEL 512
#define H_HEADS 16
#define DHEAD 32
#define DFF 2048

__device__ __forceinline__ float sigmoidf_(float x){ return 1.f/(1.f+__expf(-x)); }

// ---------------- LayerNorm over rows of (N_TOK, D_MODEL) ----------------
__global__ __launch_bounds__(256) void ln_rows(const float* __restrict__ x,
                                               const float* __restrict__ w,
                                               const float* __restrict__ b,
                                               float* __restrict__ y) {
  int row = blockIdx.x;
  const float* xr = x + (size_t)row * D_MODEL;
  float s = 0.f, s2 = 0.f;
  for (int i = threadIdx.x; i < D_MODEL; i += 256) { float v = xr[i]; s += v; s2 += v*v; }
  #pragma unroll
  for (int off = 32; off; off >>= 1) { s += __shfl_down(s, off); s2 += __shfl_down(s2, off); }
  __shared__ float rs[4], rs2[4];
  int wave = threadIdx.x >> 6, lane = threadIdx.x & 63;
  if (lane == 0) { rs[wave] = s; rs2[wave] = s2; }
  __syncthreads();
  s  = rs[0] + rs[1] + rs[2] + rs[3];
  s2 = rs2[0] + rs2[1] + rs2[2] + rs2[3];
  float mean = s * (1.f / D_MODEL);
  float var  = s2 * (1.f / D_MODEL) - mean * mean;
  float r = rsqrtf(var + 1e-5f);
  float* yr = y + (size_t)row * D_MODEL;
  for (int i = threadIdx.x; i < D_MODEL; i += 256)
    yr[i] = (xr[i] - mean) * r * w[i] + b[i];
}

// ---------------- C = A @ B^T  (+ optional epilogue: C = add + C*maskrow) ----------------
// A: (M,K) row-major, B: (Nout,K) row-major. 64x64 tile, 16x16 threads, 4x4 per thread.
__global__ __launch_bounds__(256) void gemm_bt(const float* __restrict__ A,
                                               const float* __restrict__ B,
                                               float* __restrict__ C,
                                               int M, int K, int Nout,
                                               const float* __restrict__ addmat,
                                               const float* __restrict__ maskrow) {
  __shared__ float As[16][65];
  __shared__ float Bs[16][65];
  int tx = threadIdx.x, ty = threadIdx.y;
  int tid = ty * 16 + tx;
  int m0 = blockIdx.y * 64, n0 = blockIdx.x * 64;
  float acc[4][4] = {};
  for (int kk = 0; kk < K; kk += 16) {
    #pragma unroll
    for (int r = 0; r < 4; ++r) {
      int idx = tid + r * 256;
      int mi = idx >> 4, ki = idx & 15;
      As[ki][mi] = A[(size_t)(m0 + mi) * K + kk + ki];
      Bs[ki][mi] = B[(size_t)(n0 + mi) * K + kk + ki];
    }
    __syncthreads();
    #pragma unroll
    for (int k = 0; k < 16; ++k) {
      float a[4], bb[4];
      #pragma unroll
      for (int i = 0; i < 4; ++i) a[i] = As[k][ty * 4 + i];
      #pragma unroll
      for (int j = 0; j < 4; ++j) bb[j] = Bs[k][tx * 4 + j];
      #pragma unroll
      for (int i = 0; i < 4; ++i)
        #pragma unroll
        for (int j = 0; j < 4; ++j) acc[i][j] += a[i] * bb[j];
    }
    __syncthreads();
  }
  #pragma unroll
  for (int i = 0; i < 4; ++i) {
    int m = m0 + ty * 4 + i;
    #pragma unroll
    for (int j = 0; j < 4; ++j) {
      int n = n0 + tx * 4 + j;
      float v = acc[i][j];
      if (addmat) v = addmat[(size_t)m * Nout + n] + v * maskrow[m];
      C[(size_t)m * Nout + n] = v;
    }
  }
}

// ---------------- per-head LN (no affine) over contiguous 32-groups, in place ----------------
__global__ __launch_bounds__(256) void headln(float* __restrict__ q, int ngroups) {
  int g = blockIdx.x * 256 + threadIdx.x;
  if (g >= ngroups) return;
  float* p = q + (size_t)g * DHEAD;
  float s = 0.f, s2 = 0.f;
  #pragma unroll
  for (int i = 0; i < DHEAD; ++i) { float v = p[i]; s += v; s2 += v*v; }
  float m = s * (1.f / DHEAD);
  float var = s2 * (1.f / DHEAD) - m * m;
  float r = rsqrtf(var + 1e-5f);
  #pragma unroll
  for (int i = 0; i < DHEAD; ++i) p[i] = (p[i] - m) * r;
}

// ---------------- build logK (H, N, N) ----------------
__global__ __launch_bounds__(256) void build_logK(const float* __restrict__ Q0,
                                                  const float* __restrict__ K0,
                                                  const float* __restrict__ xres,
                                                  const int* __restrict__ bins,
                                                  const float* __restrict__ posw,
                                                  const float* __restrict__ wdl,
                                                  const float* __restrict__ epsp,
                                                  const float* __restrict__ mask,
                                                  float* __restrict__ logK) {
  int h = blockIdx.z;
  int i0 = blockIdx.y * 32, j0 = blockIdx.x * 32;
  __shared__ float Qs[32][33], Ks[32][33];
  __shared__ float xi[32][3], xj[32][3], mi_s[32], mj_s[32];
  int tid = threadIdx.x;
  #pragma unroll
  for (int r = 0; r < 4; ++r) {
    int idx = tid + r * 256;
    int ii = idx >> 5, k = idx & 31;
    Qs[ii][k] = Q0[(size_t)(i0 + ii) * D_MODEL + h * DHEAD + k];
    Ks[ii][k] = K0[(size_t)(j0 + ii) * D_MODEL + h * DHEAD + k];
  }
  if (tid < 32) {
    xi[tid][0] = xres[(i0 + tid) * 3 + 0];
    xi[tid][1] = xres[(i0 + tid) * 3 + 1];
    xi[tid][2] = xres[(i0 + tid) * 3 + 2];
    xj[tid][0] = xres[(j0 + tid) * 3 + 0];
    xj[tid][1] = xres[(j0 + tid) * 3 + 1];
    xj[tid][2] = xres[(j0 + tid) * 3 + 2];
    mi_s[tid] = mask[i0 + tid];
    mj_s[tid] = mask[j0 + tid];
  }
  __syncthreads();
  float wd = sigmoidf_(wdl[h]);
  float inv_eps = 1.f / epsp[h];
  const float inv_sqrt = 0.17677669529663687f; // 1/sqrt(32)
  #pragma unroll
  for (int r = 0; r < 4; ++r) {
    int jl = tid & 31;
    int il = (tid >> 5) + r * 8;
    float dot = 0.f;
    #pragma unroll
    for (int k = 0; k < 32; ++k) dot += Qs[il][k] * Ks[jl][k];
    float d0 = xi[il][0] - xj[jl][0];
    float d1 = xi[il][1] - xj[jl][1];
    float d2c = xi[il][2] - xj[jl][2];
    float d2 = d0*d0 + d1*d1 + d2c*d2c;
    int gi = i0 + il, gj = j0 + jl;
    float bias = posw[bins[(size_t)gi * N_TOK + gj] * H_HEADS + h];
    float logit = dot * inv_sqrt + bias - wd * d2 * 0.01f;  // /R0^2 = /100
    float outv = (mi_s[il] * mj_s[jl] > 0.f) ? logit * inv_eps : -1e9f;
    logK[((size_t)h * N_TOK + gi) * N_TOK + gj] = outv;
  }
}

// ---------------- Sinkhorn row pass: log_u[h,i] = fi*(log_mu - lse_j(logK+log_v)) ----------------
__global__ __launch_bounds__(256) void sink_row(const float* __restrict__ logK,
                                                const float* __restrict__ logv,
                                                const float* __restrict__ mu,
                                                float* __restrict__ logu,
                                                const float* __restrict__ epsp) {
  int wave = threadIdx.x >> 6, lane = threadIdx.x & 63;
  int row = blockIdx.x * 4 + wave;        // 0..H*N-1
  int h = row >> 10, i = row & (N_TOK - 1);
  const float* Krow = logK + (size_t)row * N_TOK;
  float m = -3.0e38f, s = 0.f;
  #pragma unroll
  for (int it = 0; it < N_TOK / 64; ++it) {
    int j = lane + it * 64;
    float x = Krow[j] + logv[h * N_TOK + j];
    float M = fmaxf(m, x);
    s = s * __expf(m - M) + __expf(x - M);
    m = M;
  }
  #pragma unroll
  for (int off = 32; off; off >>= 1) {
    float m2 = __shfl_down(m, off);
    float s2 = __shfl_down(s, off);
    float M = fmaxf(m, m2);
    s = s * __expf(m - M) + s2 * __expf(m2 - M);
    m = M;
  }
  if (lane == 0) {
    float lse = m + __logf(s);
    float fi = 1.f / (1.f + epsp[h]);   // LAM=1
    float lmu = __logf(fmaxf(mu[h * N_TOK + i], 1e-8f));
    logu[h * N_TOK + i] = fi * (lmu - lse);
  }
}

// ---------------- Sinkhorn col pass: log_v[h,j] = fi*(log_nu - lse_i(logK+log_u)) ----------------
__global__ __launch_bounds__(256) void sink_col(const float* __restrict__ logK,
                                                const float* __restrict__ logu,
                                                const float* __restrict__ nu,
                                                float* __restrict__ logv,
                                                const float* __restrict__ epsp) {
  int h = blockIdx.y;
  int j = blockIdx.x * 256 + threadIdx.x;
  __shared__ float lu[N_TOK];
  for (int i = threadIdx.x; i < N_TOK; i += 256) lu[i] = logu[h * N_TOK + i];
  __syncthreads();
  const float* base = logK + (size_t)h * N_TOK * N_TOK + j;
  float m = -3.0e38f, s = 0.f;
  for (int i = 0; i < N_TOK; ++i) {
    float x = base[(size_t)i * N_TOK] + lu[i];
    float M = fmaxf(m, x);
    s = s * __expf(m - M) + __expf(x - M);
    m = M;
  }
  float lse = m + __logf(s);
  float fi = 1.f / (1.f + epsp[h]);
  float lnu = __logf(fmaxf(nu[h * N_TOK + j], 1e-8f));
  logv[h * N_TOK + j] = fi * (lnu - lse);
}

// ---------------- finalize: P row-normalize, attn=Pn@V * sig(G) -> o ; centroid x update ----------------
__global__ __launch_bounds__(256) void finalize(const float* __restrict__ logK,
                                                const float* __restrict__ logu,
                                                const float* __restrict__ logv,
                                                const float* __restrict__ V0,
                                                const float* __restrict__ G0,
                                                const float* __restrict__ xres,
                                                const float* __restrict__ mask,
                                                float* __restrict__ o,
                                                float* __restrict__ x_out,
                                                const float* __restrict__ gamma) {
  int i = blockIdx.x, h = blockIdx.y;
  int t = threadIdx.x;
  const float* Krow = logK + ((size_t)h * N_TOK + i) * N_TOK;
  float lu = logu[h * N_TOK + i];
  float mi = mask[i];
  float acc_v[DHEAD];
  #pragma unroll
  for (int d = 0; d < DHEAD; ++d) acc_v[d] = 0.f;
  float acc_row = 0.f, ax0 = 0.f, ax1 = 0.f, ax2 = 0.f;
  #pragma unroll
  for (int jj = 0; jj < N_TOK / 256; ++jj) {
    int j = t + jj * 256;
    float p = __expf(Krow[j] + lu + logv[h * N_TOK + j]) * mi * mask[j];
    acc_row += p;
    const float4* vv = (const float4*)(V0 + (size_t)j * D_MODEL + h * DHEAD);
    #pragma unroll
    for (int q = 0; q < 8; ++q) {
      float4 v4 = vv[q];
      acc_v[q*4+0] += p * v4.x; acc_v[q*4+1] += p * v4.y;
      acc_v[q*4+2] += p * v4.z; acc_v[q*4+3] += p * v4.w;
    }
    ax0 += p * xres[j * 3 + 0];
    ax1 += p * xres[j * 3 + 1];
    ax2 += p * xres[j * 3 + 2];
  }
  #pragma unroll
  for (int off = 32; off; off >>= 1) {
    acc_row += __shfl_down(acc_row, off);
    #pragma unroll
    for (int d = 0; d < DHEAD; ++d) acc_v[d] += __shfl_down(acc_v[d], off);
    ax0 += __shfl_down(ax0, off);
    ax1 += __shfl_down(ax1, off);
    ax2 += __shfl_down(ax2, off);
  }
  __shared__ float red[4][36];
  __shared__ float fin[36];
  int wave = t >> 6, lane = t & 63;
  if (lane == 0) {
    red[wave][0] = acc_row;
    #pragma unroll
    for (int d = 0; d < DHEAD; ++d) red[wave][1 + d] = acc_v[d];
    red[wave][33] = ax0; red[wave][34] = ax1; red[wave][35] = ax2;
  }
  __syncthreads();
  if (t < 36) fin[t] = red[0][t] + red[1][t] + red[2][t] + red[3][t];
  __syncthreads();
  float row = fmaxf(fin[0], 1e-8f);
  if (t < DHEAD) {
    size_t oi = (size_t)i * D_MODEL + h * DHEAD + t;
    o[oi] = (fin[1 + t] / row) * sigmoidf_(G0[oi]);
  } else if (t >= 64 && t < 67) {
    int c = t - 64;
    float xc = fin[33 + c] / row;
    float tg = tanhf(gamma[h]) * (1.f / H_HEADS);
    atomicAdd(&x_out[i * 3 + c], tg * (xres[i * 3 + c] - xc) * mi);
  }
}

// ---------------- elementwise: a = silu(a)*b ----------------
__global__ __launch_bounds__(256) void silu_mul(float* __restrict__ a,
                                                const float* __restrict__ b, int n) {
  int i = blockIdx.x * 256 + threadIdx.x;
  if (i < n) { float x = a[i]; a[i] = x * sigmoidf_(x) * b[i]; }
}

__global__ __launch_bounds__(256) void copyf(const float* __restrict__ src,
                                             float* __restrict__ dst, int n) {
  int i = blockIdx.x * 256 + threadIdx.x;
  if (i < n) dst[i] = src[i];
}

extern "C" void kernel_launch(void* const* d_in, const int* in_sizes, int n_in,
                              void* d_out, int out_size, void* d_ws, size_t ws_size,
                              hipStream_t stream) {
  const float* h_in  = (const float*)d_in[0];
  const float* x_res = (const float*)d_in[1];
  const float* mu    = (const float*)d_in[2];
  const float* nu    = (const float*)d_in[3];
  const float* lu0   = (const float*)d_in[4];
  const float* lv0   = (const float*)d_in[5];
  const float* mask  = (const float*)d_in[6];
  const float* lnw   = (const float*)d_in[7];
  const float* lnb   = (const float*)d_in[8];
  const float* wq    = (const float*)d_in[9];
  const float* wk    = (const float*)d_in[10];
  const float* wv    = (const float*)d_in[11];
  const float* wg    = (const float*)d_in[12];
  const float* wo    = (const float*)d_in[13];
  const float* gamma = (const float*)d_in[14];
  const float* posw  = (const float*)d_in[15];
  const float* wdl   = (const float*)d_in[16];
  const float* lnfw  = (const float*)d_in[17];
  const float* lnfb  = (const float*)d_in[18];
  const float* w1    = (const float*)d_in[19];
  const float* w3    = (const float*)d_in[20];
  const float* w2    = (const float*)d_in[21];
  const int*   bins  = (const int*)d_in[22];
  const float* eps   = (const float*)d_in[23];

  float* out    = (float*)d_out;
  float* out_h  = out;                     // 1024*512
  float* out_x  = out + 524288;            // 1024*3
  float* out_lu = out + 527360;            // 16*1024
  float* out_lv = out + 543744;            // 16*1024

  float* ws   = (float*)d_ws;
  float* h_n   = ws;
  float* Q0    = ws + 1 * 524288;
  float* K0    = ws + 2 * 524288;
  float* V0    = ws + 3 * 524288;
  float* G0    = ws + 4 * 524288;
  float* o_buf = ws + 5 * 524288;
  float* h_mid = ws + 6 * 524288;
  float* h2    = ws + 7 * 524288;
  float* ffa   = ws + 8 * 524288;                 // N*DFF
  float* ffb   = ws + 8 * 524288 + 2097152;       // N*DFF
  float* logK  = ws + 8 * 524288 + 2 * 2097152;   // H*N*N = 16777216 floats (64 MB)

  dim3 b256(256);
  dim3 tb(16, 16);

  ln_rows<<<N_TOK, b256, 0, stream>>>(h_in, lnw, lnb, h_n);

  dim3 g512(D_MODEL / 64, N_TOK / 64);
  gemm_bt<<<g512, tb, 0, stream>>>(h_n, wq, Q0, N_TOK, D_MODEL, D_MODEL, nullptr, nullptr);
  gemm_bt<<<g512, tb, 0, stream>>>(h_n, wk, K0, N_TOK, D_MODEL, D_MODEL, nullptr, nullptr);
  gemm_bt<<<g512, tb, 0, stream>>>(h_n, wv, V0, N_TOK, D_MODEL, D_MODEL, nullptr, nullptr);
  gemm_bt<<<g512, tb, 0, stream>>>(h_n, wg, G0, N_TOK, D_MODEL, D_MODEL, nullptr, nullptr);

  headln<<<(N_TOK * H_HEADS + 255) / 256, b256, 0, stream>>>(Q0, N_TOK * H_HEADS);
  headln<<<(N_TOK * H_HEADS + 255) / 256, b256, 0, stream>>>(K0, N_TOK * H_HEADS);

  copyf<<<64, b256, 0, stream>>>(lu0, out_lu, H_HEADS * N_TOK);
  copyf<<<64, b256, 0, stream>>>(lv0, out_lv, H_HEADS * N_TOK);
  copyf<<<12, b256, 0, stream>>>(x_res, out_x, N_TOK * 3);

  build_logK<<<dim3(N_TOK / 32, N_TOK / 32, H_HEADS), b256, 0, stream>>>(
      Q0, K0, x_res, bins, posw, wdl, eps, mask, logK);

  for (int it = 0; it < 20; ++it) {
    sink_row<<<H_HEADS * N_TOK / 4, b256, 0, stream>>>(logK, out_lv, mu, out_lu, eps);
    sink_col<<<dim3(N_TOK / 256, H_HEADS), b256, 0, stream>>>(logK, out_lu, nu, out_lv, eps);
  }

  finalize<<<dim3(N_TOK, H_HEADS), b256, 0, stream>>>(
      logK, out_lu, out_lv, V0, G0, x_res, mask, o_buf, out_x, gamma);

  gemm_bt<<<g512, tb, 0, stream>>>(o_buf, wo, h_mid, N_TOK, D_MODEL, D_MODEL, h_in, mask);

  ln_rows<<<N_TOK, b256, 0, stream>>>(h_mid, lnfw, lnfb, h2);

  dim3 g2048(DFF / 64, N_TOK / 64);
  gemm_bt<<<g2048, tb, 0, stream>>>(h2, w1, ffa, N_TOK, D_MODEL, DFF, nullptr, nullptr);
  gemm_bt<<<g2048, tb, 0, stream>>>(h2, w3, ffb, N_TOK, D_MODEL, DFF, nullptr, nullptr);
  silu_mul<<<(N_TOK * DFF + 255) / 256, b256, 0, stream>>>(ffa, ffb, N_TOK * DFF);
  gemm_bt<<<g512, tb, 0, stream>>>(ffa, w2, out_h, N_TOK, DFF, D_MODEL, h_mid, mask);
}

// Round 2
// 1369.785 us; speedup vs baseline: 2.0734x; 2.0734x over previous
//
#include <hip/hip_runtime.h>
#include <cstddef>
#include <cstdint>

#define N_TOK 1024
#define D_MODEL 512
#define H_HEADS 16
#define DHEAD 32
#define DFF 2048

__device__ __forceinline__ float sigmoidf_(float x){ return 1.f/(1.f+__expf(-x)); }

__device__ __forceinline__ unsigned short f2bf(float f){
  union { float f; unsigned u; } v; v.f = f;
  unsigned r = (v.u + 0x7FFFu + ((v.u >> 16) & 1u)) >> 16;
  return (unsigned short)r;
}
__device__ __forceinline__ float bf_lo(unsigned u){ return __uint_as_float(u << 16); }
__device__ __forceinline__ float bf_hi(unsigned u){ return __uint_as_float(u & 0xFFFF0000u); }

// ---------------- LayerNorm over rows of (N_TOK, D_MODEL) ----------------
__global__ __launch_bounds__(256) void ln_rows(const float* __restrict__ x,
                                               const float* __restrict__ w,
                                               const float* __restrict__ b,
                                               float* __restrict__ y) {
  int row = blockIdx.x;
  const float* xr = x + (size_t)row * D_MODEL;
  float s = 0.f, s2 = 0.f;
  for (int i = threadIdx.x; i < D_MODEL; i += 256) { float v = xr[i]; s += v; s2 += v*v; }
  #pragma unroll
  for (int off = 32; off; off >>= 1) { s += __shfl_down(s, off); s2 += __shfl_down(s2, off); }
  __shared__ float rs[4], rs2[4];
  int wave = threadIdx.x >> 6, lane = threadIdx.x & 63;
  if (lane == 0) { rs[wave] = s; rs2[wave] = s2; }
  __syncthreads();
  s  = rs[0] + rs[1] + rs[2] + rs[3];
  s2 = rs2[0] + rs2[1] + rs2[2] + rs2[3];
  float mean = s * (1.f / D_MODEL);
  float var  = s2 * (1.f / D_MODEL) - mean * mean;
  float r = rsqrtf(var + 1e-5f);
  float* yr = y + (size_t)row * D_MODEL;
  for (int i = threadIdx.x; i < D_MODEL; i += 256)
    yr[i] = (xr[i] - mean) * r * w[i] + b[i];
}

// ---------------- C = A @ B^T  (+ optional epilogue: C = add + C*maskrow) ----------------
__global__ __launch_bounds__(256) void gemm_bt(const float* __restrict__ A,
                                               const float* __restrict__ B,
                                               float* __restrict__ C,
                                               int M, int K, int Nout,
                                               const float* __restrict__ addmat,
                                               const float* __restrict__ maskrow) {
  __shared__ float As[16][65];
  __shared__ float Bs[16][65];
  int tx = threadIdx.x, ty = threadIdx.y;
  int tid = ty * 16 + tx;
  int m0 = blockIdx.y * 64, n0 = blockIdx.x * 64;
  float acc[4][4] = {};
  for (int kk = 0; kk < K; kk += 16) {
    #pragma unroll
    for (int r = 0; r < 4; ++r) {
      int idx = tid + r * 256;
      int mi = idx >> 4, ki = idx & 15;
      As[ki][mi] = A[(size_t)(m0 + mi) * K + kk + ki];
      Bs[ki][mi] = B[(size_t)(n0 + mi) * K + kk + ki];
    }
    __syncthreads();
    #pragma unroll
    for (int k = 0; k < 16; ++k) {
      float a[4], bb[4];
      #pragma unroll
      for (int i = 0; i < 4; ++i) a[i] = As[k][ty * 4 + i];
      #pragma unroll
      for (int j = 0; j < 4; ++j) bb[j] = Bs[k][tx * 4 + j];
      #pragma unroll
      for (int i = 0; i < 4; ++i)
        #pragma unroll
        for (int j = 0; j < 4; ++j) acc[i][j] += a[i] * bb[j];
    }
    __syncthreads();
  }
  #pragma unroll
  for (int i = 0; i < 4; ++i) {
    int m = m0 + ty * 4 + i;
    #pragma unroll
    for (int j = 0; j < 4; ++j) {
      int n = n0 + tx * 4 + j;
      float v = acc[i][j];
      if (addmat) v = addmat[(size_t)m * Nout + n] + v * maskrow[m];
      C[(size_t)m * Nout + n] = v;
    }
  }
}

// ---------------- per-head LN (no affine) over contiguous 32-groups, in place ----------------
__global__ __launch_bounds__(256) void headln(float* __restrict__ q, int ngroups) {
  int g = blockIdx.x * 256 + threadIdx.x;
  if (g >= ngroups) return;
  float* p = q + (size_t)g * DHEAD;
  float s = 0.f, s2 = 0.f;
  #pragma unroll
  for (int i = 0; i < DHEAD; ++i) { float v = p[i]; s += v; s2 += v*v; }
  float m = s * (1.f / DHEAD);
  float var = s2 * (1.f / DHEAD) - m * m;
  float r = rsqrtf(var + 1e-5f);
  #pragma unroll
  for (int i = 0; i < DHEAD; ++i) p[i] = (p[i] - m) * r;
}

// ---------------- build logK (H, N, N) in bf16, row-major AND transposed ----------------
__global__ __launch_bounds__(256) void build_logK(const float* __restrict__ Q0,
                                                  const float* __restrict__ K0,
                                                  const float* __restrict__ xres,
                                                  const int* __restrict__ bins,
                                                  const float* __restrict__ posw,
                                                  const float* __restrict__ wdl,
                                                  const float* __restrict__ epsp,
                                                  const float* __restrict__ mask,
                                                  unsigned short* __restrict__ logK,
                                                  unsigned short* __restrict__ logKT) {
  int h = blockIdx.z;
  int i0 = blockIdx.y * 32, j0 = blockIdx.x * 32;
  __shared__ float Qs[32][33], Ks[32][33], tileS[32][33];
  __shared__ float xi[32][3], xj[32][3], mi_s[32], mj_s[32];
  int tid = threadIdx.x;
  #pragma unroll
  for (int r = 0; r < 4; ++r) {
    int idx = tid + r * 256;
    int ii = idx >> 5, k = idx & 31;
    Qs[ii][k] = Q0[(size_t)(i0 + ii) * D_MODEL + h * DHEAD + k];
    Ks[ii][k] = K0[(size_t)(j0 + ii) * D_MODEL + h * DHEAD + k];
  }
  if (tid < 32) {
    xi[tid][0] = xres[(i0 + tid) * 3 + 0];
    xi[tid][1] = xres[(i0 + tid) * 3 + 1];
    xi[tid][2] = xres[(i0 + tid) * 3 + 2];
    xj[tid][0] = xres[(j0 + tid) * 3 + 0];
    xj[tid][1] = xres[(j0 + tid) * 3 + 1];
    xj[tid][2] = xres[(j0 + tid) * 3 + 2];
    mi_s[tid] = mask[i0 + tid];
    mj_s[tid] = mask[j0 + tid];
  }
  __syncthreads();
  float wd = sigmoidf_(wdl[h]);
  float inv_eps = 1.f / epsp[h];
  const float inv_sqrt = 0.17677669529663687f; // 1/sqrt(32)
  #pragma unroll
  for (int r = 0; r < 4; ++r) {
    int jl = tid & 31;
    int il = (tid >> 5) + r * 8;
    float dot = 0.f;
    #pragma unroll
    for (int k = 0; k < 32; ++k) dot += Qs[il][k] * Ks[jl][k];
    float d0 = xi[il][0] - xj[jl][0];
    float d1 = xi[il][1] - xj[jl][1];
    float d2c = xi[il][2] - xj[jl][2];
    float d2 = d0*d0 + d1*d1 + d2c*d2c;
    int gi = i0 + il, gj = j0 + jl;
    float bias = posw[bins[(size_t)gi * N_TOK + gj] * H_HEADS + h];
    float logit = dot * inv_sqrt + bias - wd * d2 * 0.01f;  // /R0^2 = /100
    float outv = (mi_s[il] * mj_s[jl] > 0.f) ? logit * inv_eps : -1e9f;
    tileS[il][jl] = outv;
  }
  __syncthreads();
  // row-major write: thread -> (row il8, 4 cols at c8)
  {
    int il8 = tid >> 3, c8 = (tid & 7) * 4;
    unsigned lo = ((unsigned)f2bf(tileS[il8][c8 + 1]) << 16) | f2bf(tileS[il8][c8 + 0]);
    unsigned hi = ((unsigned)f2bf(tileS[il8][c8 + 3]) << 16) | f2bf(tileS[il8][c8 + 2]);
    uint2* dst = (uint2*)(logK + ((size_t)h * N_TOK + (i0 + il8)) * N_TOK + j0 + c8);
    *dst = make_uint2(lo, hi);
  }
  // transposed write: thread -> (col jt as row, 4 i's at c8)
  {
    int jt = tid >> 3, c8 = (tid & 7) * 4;
    unsigned lo = ((unsigned)f2bf(tileS[c8 + 1][jt]) << 16) | f2bf(tileS[c8 + 0][jt]);
    unsigned hi = ((unsigned)f2bf(tileS[c8 + 3][jt]) << 16) | f2bf(tileS[c8 + 2][jt]);
    uint2* dst = (uint2*)(logKT + ((size_t)h * N_TOK + (j0 + jt)) * N_TOK + i0 + c8);
    *dst = make_uint2(lo, hi);
  }
}

// ---------------- unified Sinkhorn pass over bf16 matrix (lse over last dim) ----------------
// out[h,i] = fi_h * (log(max(marg[h,i],1e-8)) - lse_j(src[h,i,j] + other[h,j]))
__global__ __launch_bounds__(256) void sink_pass(const unsigned short* __restrict__ src,
                                                 const float* __restrict__ other,
                                                 const float* __restrict__ marg,
                                                 float* __restrict__ outlog,
                                                 const float* __restrict__ epsp) {
  __shared__ float ov[N_TOK];
  int b = blockIdx.x;
  int h = (b * 4) >> 10;
  // stage other[h][:]
  ((float4*)ov)[threadIdx.x] = ((const float4*)(other + h * N_TOK))[threadIdx.x];
  __syncthreads();
  int wave = threadIdx.x >> 6, lane = threadIdx.x & 63;
  int row = b * 4 + wave;                    // global row in (H*N)
  int i = row & (N_TOK - 1);
  const uint4* p = (const uint4*)(src + (size_t)row * N_TOK);
  float m8[8], s8[8];
  #pragma unroll
  for (int c = 0; c < 8; ++c) { m8[c] = -3.0e38f; s8[c] = 0.f; }
  #pragma unroll
  for (int it = 0; it < 2; ++it) {
    int j0 = it * 512 + lane * 8;
    uint4 u = p[it * 64 + lane];
    float4 lva = ((const float4*)ov)[j0 >> 2];
    float4 lvb = ((const float4*)ov)[(j0 >> 2) + 1];
    float xv[8];
    xv[0] = bf_lo(u.x) + lva.x; xv[1] = bf_hi(u.x) + lva.y;
    xv[2] = bf_lo(u.y) + lva.z; xv[3] = bf_hi(u.y) + lva.w;
    xv[4] = bf_lo(u.z) + lvb.x; xv[5] = bf_hi(u.z) + lvb.y;
    xv[6] = bf_lo(u.w) + lvb.z; xv[7] = bf_hi(u.w) + lvb.w;
    #pragma unroll
    for (int c = 0; c < 8; ++c) {
      float M = fmaxf(m8[c], xv[c]);
      s8[c] = s8[c] * __expf(m8[c] - M) + __expf(xv[c] - M);
      m8[c] = M;
    }
  }
  // merge 8 accumulators
  #pragma unroll
  for (int st = 4; st; st >>= 1)
    #pragma unroll
    for (int c = 0; c < 4; ++c) if (c < st) {
      float M = fmaxf(m8[c], m8[c + st]);
      s8[c] = s8[c] * __expf(m8[c] - M) + s8[c + st] * __expf(m8[c + st] - M);
      m8[c] = M;
    }
  float m = m8[0], s = s8[0];
  #pragma unroll
  for (int off = 32; off; off >>= 1) {
    float m2 = __shfl_xor(m, off);
    float s2 = __shfl_xor(s, off);
    float M = fmaxf(m, m2);
    s = s * __expf(m - M) + s2 * __expf(m2 - M);
    m = M;
  }
  if (lane == 0) {
    float lse = m + __logf(s);
    float fi = 1.f / (1.f + epsp[h]);   // LAM=1
    float lm = __logf(fmaxf(marg[h * N_TOK + i], 1e-8f));
    outlog[h * N_TOK + i] = fi * (lm - lse);
  }
}

// ---------------- finalize: tiled Pn@V + centroid, 32-row tile per (block,head) ----------------
__global__ __launch_bounds__(256) void finalize(const unsigned short* __restrict__ logK,
                                                const float* __restrict__ logu,
                                                const float* __restrict__ logv,
                                                const float* __restrict__ V0,
                                                const float* __restrict__ G0,
                                                const float* __restrict__ xres,
                                                const float* __restrict__ mask,
                                                float* __restrict__ o,
                                                float* __restrict__ x_out,
                                                const float* __restrict__ gamma) {
  int i0 = blockIdx.x * 32, h = blockIdx.y;
  int t = threadIdx.x;
  int r = t >> 3;            // row in tile 0..31
  int dsub = t & 7;          // 4-dim slice 0..7
  __shared__ float Ks[32][65];
  __shared__ float Vs[64][32];
  __shared__ float lvs[64], pms[64], xs0[64], xs1[64], xs2[64];
  float lu = logu[h * N_TOK + i0 + r];
  float4 acc = make_float4(0.f, 0.f, 0.f, 0.f);
  float rs = 0.f, ax0 = 0.f, ax1 = 0.f, ax2 = 0.f;
  const unsigned short* Krow = logK + ((size_t)h * N_TOK + i0 + r) * N_TOK;
  for (int j0 = 0; j0 < N_TOK; j0 += 64) {
    // stage K tile: 32 rows x 64 cols bf16 -> float LDS
    {
      uint4 u = *(const uint4*)(Krow + j0 + dsub * 8);
      float* kd = &Ks[r][dsub * 8];
      kd[0] = bf_lo(u.x); kd[1] = bf_hi(u.x);
      kd[2] = bf_lo(u.y); kd[3] = bf_hi(u.y);
      kd[4] = bf_lo(u.z); kd[5] = bf_hi(u.z);
      kd[6] = bf_lo(u.w); kd[7] = bf_hi(u.w);
    }
    // stage V tile: 64 rows x 32 dims
    {
      int jv = t >> 2, c4 = t & 3;
      const float4* vsrc = (const float4*)(V0 + (size_t)(j0 + jv) * D_MODEL + h * DHEAD + c4 * 8);
      float4 a = vsrc[0], bq = vsrc[1];
      float* vd = &Vs[jv][c4 * 8];
      vd[0] = a.x; vd[1] = a.y; vd[2] = a.z; vd[3] = a.w;
      vd[4] = bq.x; vd[5] = bq.y; vd[6] = bq.z; vd[7] = bq.w;
    }
    if (t < 64) {
      int j = j0 + t;
      lvs[t] = logv[h * N_TOK + j];
      pms[t] = mask[j];
      xs0[t] = xres[j * 3 + 0];
      xs1[t] = xres[j * 3 + 1];
      xs2[t] = xres[j * 3 + 2];
    }
    __syncthreads();
    #pragma unroll 8
    for (int jj = 0; jj < 64; ++jj) {
      float parg = Ks[r][jj] + lu + lvs[jj];
      float pv = __expf(parg) * pms[jj];
      rs += pv;
      const float4* vv = (const float4*)&Vs[jj][dsub * 4];
      float4 v4 = *vv;
      acc.x += pv * v4.x; acc.y += pv * v4.y; acc.z += pv * v4.z; acc.w += pv * v4.w;
      if (dsub == 0) {
        ax0 += pv * xs0[jj];
        ax1 += pv * xs1[jj];
        ax2 += pv * xs2[jj];
      }
    }
    __syncthreads();
  }
  float row = fmaxf(rs, 1e-8f);
  float inv = 1.f / row;
  size_t oi = (size_t)(i0 + r) * D_MODEL + h * DHEAD + dsub * 4;
  float4 g4 = *(const float4*)(G0 + oi);
  float4 ov;
  ov.x = acc.x * inv * sigmoidf_(g4.x);
  ov.y = acc.y * inv * sigmoidf_(g4.y);
  ov.z = acc.z * inv * sigmoidf_(g4.z);
  ov.w = acc.w * inv * sigmoidf_(g4.w);
  *(float4*)(o + oi) = ov;
  if (dsub == 0) {
    int gi = i0 + r;
    float mi = mask[gi];
    float tg = tanhf(gamma[h]) * (1.f / H_HEADS) * mi;
    atomicAdd(&x_out[gi * 3 + 0], tg * (xres[gi * 3 + 0] - ax0 * inv));
    atomicAdd(&x_out[gi * 3 + 1], tg * (xres[gi * 3 + 1] - ax1 * inv));
    atomicAdd(&x_out[gi * 3 + 2], tg * (xres[gi * 3 + 2] - ax2 * inv));
  }
}

// ---------------- elementwise: a = silu(a)*b ----------------
__global__ __launch_bounds__(256) void silu_mul(float* __restrict__ a,
                                                const float* __restrict__ b, int n) {
  int i = blockIdx.x * 256 + threadIdx.x;
  if (i < n) { float x = a[i]; a[i] = x * sigmoidf_(x) * b[i]; }
}

__global__ __launch_bounds__(256) void copyf(const float* __restrict__ src,
                                             float* __restrict__ dst, int n) {
  int i = blockIdx.x * 256 + threadIdx.x;
  if (i < n) dst[i] = src[i];
}

extern "C" void kernel_launch(void* const* d_in, const int* in_sizes, int n_in,
                              void* d_out, int out_size, void* d_ws, size_t ws_size,
                              hipStream_t stream) {
  const float* h_in  = (const float*)d_in[0];
  const float* x_res = (const float*)d_in[1];
  const float* mu    = (const float*)d_in[2];
  const float* nu    = (const float*)d_in[3];
  const float* lu0   = (const float*)d_in[4];
  const float* lv0   = (const float*)d_in[5];
  const float* mask  = (const float*)d_in[6];
  const float* lnw   = (const float*)d_in[7];
  const float* lnb   = (const float*)d_in[8];
  const float* wq    = (const float*)d_in[9];
  const float* wk    = (const float*)d_in[10];
  const float* wv    = (const float*)d_in[11];
  const float* wg    = (const float*)d_in[12];
  const float* wo    = (const float*)d_in[13];
  const float* gamma = (const float*)d_in[14];
  const float* posw  = (const float*)d_in[15];
  const float* wdl   = (const float*)d_in[16];
  const float* lnfw  = (const float*)d_in[17];
  const float* lnfb  = (const float*)d_in[18];
  const float* w1    = (const float*)d_in[19];
  const float* w3    = (const float*)d_in[20];
  const float* w2    = (const float*)d_in[21];
  const int*   bins  = (const int*)d_in[22];
  const float* eps   = (const float*)d_in[23];

  float* out    = (float*)d_out;
  float* out_h  = out;                     // 1024*512
  float* out_x  = out + 524288;            // 1024*3
  float* out_lu = out + 527360;            // 16*1024
  float* out_lv = out + 543744;            // 16*1024

  float* ws   = (float*)d_ws;
  float* h_n   = ws;
  float* Q0    = ws + 1 * 524288;
  float* K0    = ws + 2 * 524288;
  float* V0    = ws + 3 * 524288;
  float* G0    = ws + 4 * 524288;
  float* o_buf = ws + 5 * 524288;
  float* h_mid = ws + 6 * 524288;
  float* h2    = ws + 7 * 524288;
  float* ffa   = ws + 8 * 524288;                 // N*DFF
  float* ffb   = ws + 8 * 524288 + 2097152;       // N*DFF
  unsigned short* logKb  = (unsigned short*)(ws + 8 * 524288 + 2 * 2097152); // H*N*N bf16 (32 MB)
  unsigned short* logKTb = logKb + (size_t)H_HEADS * N_TOK * N_TOK;          // transposed (32 MB)

  dim3 b256(256);
  dim3 tb(16, 16);

  ln_rows<<<N_TOK, b256, 0, stream>>>(h_in, lnw, lnb, h_n);

  dim3 g512(D_MODEL / 64, N_TOK / 64);
  gemm_bt<<<g512, tb, 0, stream>>>(h_n, wq, Q0, N_TOK, D_MODEL, D_MODEL, nullptr, nullptr);
  gemm_bt<<<g512, tb, 0, stream>>>(h_n, wk, K0, N_TOK, D_MODEL, D_MODEL, nullptr, nullptr);
  gemm_bt<<<g512, tb, 0, stream>>>(h_n, wv, V0, N_TOK, D_MODEL, D_MODEL, nullptr, nullptr);
  gemm_bt<<<g512, tb, 0, stream>>>(h_n, wg, G0, N_TOK, D_MODEL, D_MODEL, nullptr, nullptr);

  headln<<<(N_TOK * H_HEADS + 255) / 256, b256, 0, stream>>>(Q0, N_TOK * H_HEADS);
  headln<<<(N_TOK * H_HEADS + 255) / 256, b256, 0, stream>>>(K0, N_TOK * H_HEADS);

  copyf<<<64, b256, 0, stream>>>(lu0, out_lu, H_HEADS * N_TOK);
  copyf<<<64, b256, 0, stream>>>(lv0, out_lv, H_HEADS * N_TOK);
  copyf<<<12, b256, 0, stream>>>(x_res, out_x, N_TOK * 3);

  build_logK<<<dim3(N_TOK / 32, N_TOK / 32, H_HEADS), b256, 0, stream>>>(
      Q0, K0, x_res, bins, posw, wdl, eps, mask, logKb, logKTb);

  for (int it = 0; it < 20; ++it) {
    sink_pass<<<H_HEADS * N_TOK / 4, b256, 0, stream>>>(logKb, out_lv, mu, out_lu, eps);
    sink_pass<<<H_HEADS * N_TOK / 4, b256, 0, stream>>>(logKTb, out_lu, nu, out_lv, eps);
  }

  finalize<<<dim3(N_TOK / 32, H_HEADS), b256, 0, stream>>>(
      logKb, out_lu, out_lv, V0, G0, x_res, mask, o_buf, out_x, gamma);

  gemm_bt<<<g512, tb, 0, stream>>>(o_buf, wo, h_mid, N_TOK, D_MODEL, D_MODEL, h_in, mask);

  ln_rows<<<N_TOK, b256, 0, stream>>>(h_mid, lnfw, lnfb, h2);

  dim3 g2048(DFF / 64, N_TOK / 64);
  gemm_bt<<<g2048, tb, 0, stream>>>(h2, w1, ffa, N_TOK, D_MODEL, DFF, nullptr, nullptr);
  gemm_bt<<<g2048, tb, 0, stream>>>(h2, w3, ffb, N_TOK, D_MODEL, DFF, nullptr, nullptr);
  silu_mul<<<(N_TOK * DFF + 255) / 256, b256, 0, stream>>>(ffa, ffb, N_TOK * DFF);
  gemm_bt<<<g512, tb, 0, stream>>>(ffa, w2, out_h, N_TOK, DFF, D_MODEL, h_mid, mask);
}

// Round 3
// 958.564 us; speedup vs baseline: 2.9629x; 1.4290x over previous
//
#include <hip/hip_runtime.h>
#include <cstddef>
#include <cstdint>

#define N_TOK 1024
#define D_MODEL 512
#define H_HEADS 16
#define DHEAD 32
#define DFF 2048

typedef __attribute__((ext_vector_type(8))) short short8;
typedef __attribute__((ext_vector_type(4))) float f32x4_t;

__device__ __forceinline__ float sigmoidf_(float x){ return 1.f/(1.f+__expf(-x)); }

__device__ __forceinline__ unsigned short f2bf(float f){
  union { float f; unsigned u; } v; v.f = f;
  unsigned r = (v.u + 0x7FFFu + ((v.u >> 16) & 1u)) >> 16;
  return (unsigned short)r;
}
__device__ __forceinline__ float bf_lo(unsigned u){ return __uint_as_float(u << 16); }
__device__ __forceinline__ float bf_hi(unsigned u){ return __uint_as_float(u & 0xFFFF0000u); }

// ---------------- LayerNorm over rows -> bf16 out ----------------
__global__ __launch_bounds__(256) void ln_rows(const float* __restrict__ x,
                                               const float* __restrict__ w,
                                               const float* __restrict__ b,
                                               unsigned short* __restrict__ y) {
  int row = blockIdx.x;
  const float* xr = x + (size_t)row * D_MODEL;
  float s = 0.f, s2 = 0.f;
  for (int i = threadIdx.x; i < D_MODEL; i += 256) { float v = xr[i]; s += v; s2 += v*v; }
  #pragma unroll
  for (int off = 32; off; off >>= 1) { s += __shfl_down(s, off); s2 += __shfl_down(s2, off); }
  __shared__ float rs[4], rs2[4];
  int wave = threadIdx.x >> 6, lane = threadIdx.x & 63;
  if (lane == 0) { rs[wave] = s; rs2[wave] = s2; }
  __syncthreads();
  s  = rs[0] + rs[1] + rs[2] + rs[3];
  s2 = rs2[0] + rs2[1] + rs2[2] + rs2[3];
  float mean = s * (1.f / D_MODEL);
  float var  = s2 * (1.f / D_MODEL) - mean * mean;
  float r = rsqrtf(var + 1e-5f);
  unsigned short* yr = y + (size_t)row * D_MODEL;
  for (int i = threadIdx.x; i < D_MODEL; i += 256)
    yr[i] = f2bf((xr[i] - mean) * r * w[i] + b[i]);
}

// ---------------- weight conversion fp32 -> bf16 (all weights, one kernel) ----------------
__global__ __launch_bounds__(256) void conv_weights(const float* __restrict__ wq,
                                                    const float* __restrict__ wk,
                                                    const float* __restrict__ wv,
                                                    const float* __restrict__ wg,
                                                    const float* __restrict__ wo,
                                                    const float* __restrict__ w1,
                                                    const float* __restrict__ w3,
                                                    const float* __restrict__ w2,
                                                    unsigned short* __restrict__ dst) {
  size_t i = ((size_t)blockIdx.x * 256 + threadIdx.x) * 4;
  const float* src; size_t off;
  if      (i < 262144)  { src = wq; off = i; }
  else if (i < 524288)  { src = wk; off = i - 262144; }
  else if (i < 786432)  { src = wv; off = i - 524288; }
  else if (i < 1048576) { src = wg; off = i - 786432; }
  else if (i < 1310720) { src = wo; off = i - 1048576; }
  else if (i < 2359296) { src = w1; off = i - 1310720; }
  else if (i < 3407872) { src = w3; off = i - 2359296; }
  else                  { src = w2; off = i - 3407872; }
  float4 v = *(const float4*)&src[off];
  unsigned lo = ((unsigned)f2bf(v.y) << 16) | f2bf(v.x);
  unsigned hi = ((unsigned)f2bf(v.w) << 16) | f2bf(v.z);
  *(uint2*)&dst[i] = make_uint2(lo, hi);
}

// ---------------- bf16 MFMA GEMM: C = A @ B^T (fp32 out, optional residual+mask epilogue) ----
// A: (M,K) bf16 row-major. B: (Nout,K) bf16 row-major. 128x128 tile, 4 waves, BK=32.
__global__ __launch_bounds__(256) void gemm_mfma(const unsigned short* __restrict__ A,
                                                 const unsigned short* __restrict__ B,
                                                 float* __restrict__ C,
                                                 int M, int K, int Nout,
                                                 const float* __restrict__ addmat,
                                                 const float* __restrict__ maskrow) {
  __shared__ unsigned short As[128][40];   // +8 pad: row stride 80B -> 2-way banks (free)
  __shared__ unsigned short Bs[128][40];
  int t = threadIdx.x;
  int m0 = blockIdx.y * 128, n0 = blockIdx.x * 128;
  int wave = t >> 6, lane = t & 63;
  int wm = (wave >> 1) * 64, wn = (wave & 1) * 64;
  int lm = lane & 15, quad = lane >> 4;
  f32x4_t zero = {0.f, 0.f, 0.f, 0.f};
  f32x4_t acc[4][4];
  #pragma unroll
  for (int i = 0; i < 4; ++i)
    #pragma unroll
    for (int j = 0; j < 4; ++j) acc[i][j] = zero;

  int sr = t >> 2, sc = (t & 3) * 8;
  for (int kk = 0; kk < K; kk += 32) {
    #pragma unroll
    for (int c = 0; c < 2; ++c) {
      int r = sr + c * 64;
      *(uint4*)&As[r][sc] = *(const uint4*)&A[(size_t)(m0 + r) * K + kk + sc];
      *(uint4*)&Bs[r][sc] = *(const uint4*)&B[(size_t)(n0 + r) * K + kk + sc];
    }
    __syncthreads();
    short8 af[4], bfr[4];
    #pragma unroll
    for (int mt = 0; mt < 4; ++mt)
      af[mt] = *(const short8*)&As[wm + mt * 16 + lm][quad * 8];
    #pragma unroll
    for (int nt = 0; nt < 4; ++nt)
      bfr[nt] = *(const short8*)&Bs[wn + nt * 16 + lm][quad * 8];
    #pragma unroll
    for (int mt = 0; mt < 4; ++mt)
      #pragma unroll
      for (int nt = 0; nt < 4; ++nt)
        acc[mt][nt] = __builtin_amdgcn_mfma_f32_16x16x32_bf16(af[mt], bfr[nt], acc[mt][nt], 0, 0, 0);
    __syncthreads();
  }
  #pragma unroll
  for (int mt = 0; mt < 4; ++mt) {
    #pragma unroll
    for (int reg = 0; reg < 4; ++reg) {
      int gm = m0 + wm + mt * 16 + quad * 4 + reg;
      float mk = maskrow ? maskrow[gm] : 0.f;
      #pragma unroll
      for (int nt = 0; nt < 4; ++nt) {
        int gn = n0 + wn + nt * 16 + lm;
        float v = acc[mt][nt][reg];
        if (addmat) v = addmat[(size_t)gm * Nout + gn] + v * mk;
        C[(size_t)gm * Nout + gn] = v;
      }
    }
  }
}

// ---------------- per-head LN (no affine), Q and K regions of QKVG (ld=2048) ----------------
__global__ __launch_bounds__(256) void headln(float* __restrict__ base, int ld) {
  int g = blockIdx.x * 256 + threadIdx.x;   // 32768 = 1024 rows * 32 (16 Q-heads + 16 K-heads)
  int i = g & (N_TOK - 1), hh = g >> 10;    // hh 0..31
  float* p = base + (size_t)i * ld + hh * DHEAD;
  float s = 0.f, s2 = 0.f;
  #pragma unroll
  for (int k = 0; k < DHEAD; ++k) { float v = p[k]; s += v; s2 += v*v; }
  float m = s * (1.f / DHEAD);
  float var = s2 * (1.f / DHEAD) - m * m;
  float r = rsqrtf(var + 1e-5f);
  #pragma unroll
  for (int k = 0; k < DHEAD; ++k) p[k] = (p[k] - m) * r;
}

// ---------------- build logK (H, N, N) in bf16, row-major AND transposed ----------------
__global__ __launch_bounds__(256) void build_logK(const float* __restrict__ Q0,
                                                  const float* __restrict__ K0,
                                                  int ld,
                                                  const float* __restrict__ xres,
                                                  const int* __restrict__ bins,
                                                  const float* __restrict__ posw,
                                                  const float* __restrict__ wdl,
                                                  const float* __restrict__ epsp,
                                                  const float* __restrict__ mask,
                                                  unsigned short* __restrict__ logK,
                                                  unsigned short* __restrict__ logKT) {
  int h = blockIdx.z;
  int i0 = blockIdx.y * 32, j0 = blockIdx.x * 32;
  __shared__ float Qs[32][33], Ks[32][33], tileS[32][33];
  __shared__ float xi[32][3], xj[32][3], mi_s[32], mj_s[32];
  int tid = threadIdx.x;
  #pragma unroll
  for (int r = 0; r < 4; ++r) {
    int idx = tid + r * 256;
    int ii = idx >> 5, k = idx & 31;
    Qs[ii][k] = Q0[(size_t)(i0 + ii) * ld + h * DHEAD + k];
    Ks[ii][k] = K0[(size_t)(j0 + ii) * ld + h * DHEAD + k];
  }
  if (tid < 32) {
    xi[tid][0] = xres[(i0 + tid) * 3 + 0];
    xi[tid][1] = xres[(i0 + tid) * 3 + 1];
    xi[tid][2] = xres[(i0 + tid) * 3 + 2];
    xj[tid][0] = xres[(j0 + tid) * 3 + 0];
    xj[tid][1] = xres[(j0 + tid) * 3 + 1];
    xj[tid][2] = xres[(j0 + tid) * 3 + 2];
    mi_s[tid] = mask[i0 + tid];
    mj_s[tid] = mask[j0 + tid];
  }
  __syncthreads();
  float wd = sigmoidf_(wdl[h]);
  float inv_eps = 1.f / epsp[h];
  const float inv_sqrt = 0.17677669529663687f; // 1/sqrt(32)
  #pragma unroll
  for (int r = 0; r < 4; ++r) {
    int jl = tid & 31;
    int il = (tid >> 5) + r * 8;
    float dot = 0.f;
    #pragma unroll
    for (int k = 0; k < 32; ++k) dot += Qs[il][k] * Ks[jl][k];
    float d0 = xi[il][0] - xj[jl][0];
    float d1 = xi[il][1] - xj[jl][1];
    float d2c = xi[il][2] - xj[jl][2];
    float d2 = d0*d0 + d1*d1 + d2c*d2c;
    int gi = i0 + il, gj = j0 + jl;
    float bias = posw[bins[(size_t)gi * N_TOK + gj] * H_HEADS + h];
    float logit = dot * inv_sqrt + bias - wd * d2 * 0.01f;  // /R0^2 = /100
    float outv = (mi_s[il] * mj_s[jl] > 0.f) ? logit * inv_eps : -1e9f;
    tileS[il][jl] = outv;
  }
  __syncthreads();
  {
    int il8 = tid >> 3, c8 = (tid & 7) * 4;
    unsigned lo = ((unsigned)f2bf(tileS[il8][c8 + 1]) << 16) | f2bf(tileS[il8][c8 + 0]);
    unsigned hi = ((unsigned)f2bf(tileS[il8][c8 + 3]) << 16) | f2bf(tileS[il8][c8 + 2]);
    uint2* dst = (uint2*)(logK + ((size_t)h * N_TOK + (i0 + il8)) * N_TOK + j0 + c8);
    *dst = make_uint2(lo, hi);
  }
  {
    int jt = tid >> 3, c8 = (tid & 7) * 4;
    unsigned lo = ((unsigned)f2bf(tileS[c8 + 1][jt]) << 16) | f2bf(tileS[c8 + 0][jt]);
    unsigned hi = ((unsigned)f2bf(tileS[c8 + 3][jt]) << 16) | f2bf(tileS[c8 + 2][jt]);
    uint2* dst = (uint2*)(logKT + ((size_t)h * N_TOK + (j0 + jt)) * N_TOK + i0 + c8);
    *dst = make_uint2(lo, hi);
  }
}

// ---------------- unified Sinkhorn pass over bf16 matrix (lse over last dim) ----------------
__global__ __launch_bounds__(256) void sink_pass(const unsigned short* __restrict__ src,
                                                 const float* __restrict__ other,
                                                 const float* __restrict__ marg,
                                                 float* __restrict__ outlog,
                                                 const float* __restrict__ epsp) {
  __shared__ float ov[N_TOK];
  int b = blockIdx.x;
  int h = (b * 4) >> 10;
  ((float4*)ov)[threadIdx.x] = ((const float4*)(other + h * N_TOK))[threadIdx.x];
  __syncthreads();
  int wave = threadIdx.x >> 6, lane = threadIdx.x & 63;
  int row = b * 4 + wave;
  int i = row & (N_TOK - 1);
  const uint4* p = (const uint4*)(src + (size_t)row * N_TOK);
  float m8[8], s8[8];
  #pragma unroll
  for (int c = 0; c < 8; ++c) { m8[c] = -3.0e38f; s8[c] = 0.f; }
  #pragma unroll
  for (int it = 0; it < 2; ++it) {
    int j0 = it * 512 + lane * 8;
    uint4 u = p[it * 64 + lane];
    float4 lva = ((const float4*)ov)[j0 >> 2];
    float4 lvb = ((const float4*)ov)[(j0 >> 2) + 1];
    float xv[8];
    xv[0] = bf_lo(u.x) + lva.x; xv[1] = bf_hi(u.x) + lva.y;
    xv[2] = bf_lo(u.y) + lva.z; xv[3] = bf_hi(u.y) + lva.w;
    xv[4] = bf_lo(u.z) + lvb.x; xv[5] = bf_hi(u.z) + lvb.y;
    xv[6] = bf_lo(u.w) + lvb.z; xv[7] = bf_hi(u.w) + lvb.w;
    #pragma unroll
    for (int c = 0; c < 8; ++c) {
      float M = fmaxf(m8[c], xv[c]);
      s8[c] = s8[c] * __expf(m8[c] - M) + __expf(xv[c] - M);
      m8[c] = M;
    }
  }
  #pragma unroll
  for (int st = 4; st; st >>= 1)
    #pragma unroll
    for (int c = 0; c < 4; ++c) if (c < st) {
      float M = fmaxf(m8[c], m8[c + st]);
      s8[c] = s8[c] * __expf(m8[c] - M) + s8[c + st] * __expf(m8[c + st] - M);
      m8[c] = M;
    }
  float m = m8[0], s = s8[0];
  #pragma unroll
  for (int off = 32; off; off >>= 1) {
    float m2 = __shfl_xor(m, off);
    float s2 = __shfl_xor(s, off);
    float M = fmaxf(m, m2);
    s = s * __expf(m - M) + s2 * __expf(m2 - M);
    m = M;
  }
  if (lane == 0) {
    float lse = m + __logf(s);
    float fi = 1.f / (1.f + epsp[h]);   // LAM=1
    float lm = __logf(fmaxf(marg[h * N_TOK + i], 1e-8f));
    outlog[h * N_TOK + i] = fi * (lm - lse);
  }
}

// ---------------- finalize: tiled Pn@V + centroid; o out in bf16 ----------------
__global__ __launch_bounds__(256) void finalize(const unsigned short* __restrict__ logK,
                                                const float* __restrict__ logu,
                                                const float* __restrict__ logv,
                                                const float* __restrict__ V0,
                                                const float* __restrict__ G0,
                                                int ld,
                                                const float* __restrict__ xres,
                                                const float* __restrict__ mask,
                                                unsigned short* __restrict__ o,
                                                float* __restrict__ x_out,
                                                const float* __restrict__ gamma) {
  int i0 = blockIdx.x * 32, h = blockIdx.y;
  int t = threadIdx.x;
  int r = t >> 3;            // row in tile 0..31
  int dsub = t & 7;          // 4-dim slice 0..7
  __shared__ float Ks[32][65];
  __shared__ float Vs[64][32];
  __shared__ float lvs[64], pms[64], xs0[64], xs1[64], xs2[64];
  float lu = logu[h * N_TOK + i0 + r];
  float4 acc = make_float4(0.f, 0.f, 0.f, 0.f);
  float rs = 0.f, ax0 = 0.f, ax1 = 0.f, ax2 = 0.f;
  const unsigned short* Krow = logK + ((size_t)h * N_TOK + i0 + r) * N_TOK;
  for (int j0 = 0; j0 < N_TOK; j0 += 64) {
    {
      uint4 u = *(const uint4*)(Krow + j0 + dsub * 8);
      float* kd = &Ks[r][dsub * 8];
      kd[0] = bf_lo(u.x); kd[1] = bf_hi(u.x);
      kd[2] = bf_lo(u.y); kd[3] = bf_hi(u.y);
      kd[4] = bf_lo(u.z); kd[5] = bf_hi(u.z);
      kd[6] = bf_lo(u.w); kd[7] = bf_hi(u.w);
    }
    {
      int jv = t >> 2, c4 = t & 3;
      const float4* vsrc = (const float4*)(V0 + (size_t)(j0 + jv) * ld + h * DHEAD + c4 * 8);
      float4 a = vsrc[0], bq = vsrc[1];
      float* vd = &Vs[jv][c4 * 8];
      vd[0] = a.x; vd[1] = a.y; vd[2] = a.z; vd[3] = a.w;
      vd[4] = bq.x; vd[5] = bq.y; vd[6] = bq.z; vd[7] = bq.w;
    }
    if (t < 64) {
      int j = j0 + t;
      lvs[t] = logv[h * N_TOK + j];
      pms[t] = mask[j];
      xs0[t] = xres[j * 3 + 0];
      xs1[t] = xres[j * 3 + 1];
      xs2[t] = xres[j * 3 + 2];
    }
    __syncthreads();
    #pragma unroll 8
    for (int jj = 0; jj < 64; ++jj) {
      float parg = Ks[r][jj] + lu + lvs[jj];
      float pv = __expf(parg) * pms[jj];
      rs += pv;
      float4 v4 = *(const float4*)&Vs[jj][dsub * 4];
      acc.x += pv * v4.x; acc.y += pv * v4.y; acc.z += pv * v4.z; acc.w += pv * v4.w;
      if (dsub == 0) {
        ax0 += pv * xs0[jj];
        ax1 += pv * xs1[jj];
        ax2 += pv * xs2[jj];
      }
    }
    __syncthreads();
  }
  float row = fmaxf(rs, 1e-8f);
  float inv = 1.f / row;
  int gi = i0 + r;
  float4 g4 = *(const float4*)(G0 + (size_t)gi * ld + h * DHEAD + dsub * 4);
  float o0 = acc.x * inv * sigmoidf_(g4.x);
  float o1 = acc.y * inv * sigmoidf_(g4.y);
  float o2 = acc.z * inv * sigmoidf_(g4.z);
  float o3 = acc.w * inv * sigmoidf_(g4.w);
  unsigned lo = ((unsigned)f2bf(o1) << 16) | f2bf(o0);
  unsigned hi = ((unsigned)f2bf(o3) << 16) | f2bf(o2);
  *(uint2*)(o + (size_t)gi * D_MODEL + h * DHEAD + dsub * 4) = make_uint2(lo, hi);
  if (dsub == 0) {
    float mi = mask[gi];
    float tg = tanhf(gamma[h]) * (1.f / H_HEADS) * mi;
    atomicAdd(&x_out[gi * 3 + 0], tg * (xres[gi * 3 + 0] - ax0 * inv));
    atomicAdd(&x_out[gi * 3 + 1], tg * (xres[gi * 3 + 1] - ax1 * inv));
    atomicAdd(&x_out[gi * 3 + 2], tg * (xres[gi * 3 + 2] - ax2 * inv));
  }
}

// ---------------- silu+mul from fused ffab (1024x4096) -> bf16 (1024x2048) ----------------
__global__ __launch_bounds__(256) void silu_mul_bf(const float* __restrict__ ffab,
                                                   unsigned short* __restrict__ out, int n) {
  int i = blockIdx.x * 256 + threadIdx.x;
  if (i >= n) return;
  int row = i >> 11, col = i & 2047;
  float a = ffab[(size_t)row * 4096 + col];
  float bb = ffab[(size_t)row * 4096 + 2048 + col];
  out[i] = f2bf(a * sigmoidf_(a) * bb);
}

__global__ __launch_bounds__(256) void copyf(const float* __restrict__ src,
                                             float* __restrict__ dst, int n) {
  int i = blockIdx.x * 256 + threadIdx.x;
  if (i < n) dst[i] = src[i];
}

extern "C" void kernel_launch(void* const* d_in, const int* in_sizes, int n_in,
                              void* d_out, int out_size, void* d_ws, size_t ws_size,
                              hipStream_t stream) {
  const float* h_in  = (const float*)d_in[0];
  const float* x_res = (const float*)d_in[1];
  const float* mu    = (const float*)d_in[2];
  const float* nu    = (const float*)d_in[3];
  const float* lu0   = (const float*)d_in[4];
  const float* lv0   = (const float*)d_in[5];
  const float* mask  = (const float*)d_in[6];
  const float* lnw   = (const float*)d_in[7];
  const float* lnb   = (const float*)d_in[8];
  const float* wq    = (const float*)d_in[9];
  const float* wk    = (const float*)d_in[10];
  const float* wv    = (const float*)d_in[11];
  const float* wg    = (const float*)d_in[12];
  const float* wo    = (const float*)d_in[13];
  const float* gamma = (const float*)d_in[14];
  const float* posw  = (const float*)d_in[15];
  const float* wdl   = (const float*)d_in[16];
  const float* lnfw  = (const float*)d_in[17];
  const float* lnfb  = (const float*)d_in[18];
  const float* w1    = (const float*)d_in[19];
  const float* w3    = (const float*)d_in[20];
  const float* w2    = (const float*)d_in[21];
  const int*   bins  = (const int*)d_in[22];
  const float* eps   = (const float*)d_in[23];

  float* out    = (float*)d_out;
  float* out_h  = out;                     // 1024*512
  float* out_x  = out + 524288;            // 1024*3
  float* out_lu = out + 527360;            // 16*1024
  float* out_lv = out + 543744;            // 16*1024

  float* ws = (float*)d_ws;
  // fp32 region
  float* QKVG  = ws;                       // 1024 x 2048 (Q|K|V|G), 2097152 floats
  float* h_mid = ws + 2097152;             // 1024 x 512
  // bf16 region
  unsigned short* U = (unsigned short*)(ws + 2621440);
  unsigned short* h_n_b  = U;              // 1024x512
  unsigned short* h2_b   = U + 524288;     // 1024x512
  unsigned short* o_b    = U + 1048576;    // 1024x512
  unsigned short* wB     = U + 1572864;    // 4456448 bf16 weights
  // logK region (reused by FFN after finalize)
  unsigned short* logKb  = (unsigned short*)(ws + 5636096);  // H*N*N
  unsigned short* logKTb = logKb + (size_t)H_HEADS * N_TOK * N_TOK;
  float* ffab            = (float*)logKb;        // 1024 x 4096 fp32 (16 MB < 32 MB)
  unsigned short* ff_b   = logKTb;               // 1024 x 2048 bf16 (4 MB < 32 MB)

  unsigned short* wQKVGb = wB;                 // 2048 x 512
  unsigned short* wob    = wB + 1048576;       // 512 x 512
  unsigned short* wFFb   = wB + 1310720;       // 4096 x 512  (w1 rows then w3 rows)
  unsigned short* w2b    = wB + 3407872;       // 512 x 2048

  dim3 b256(256);

  conv_weights<<<4352, b256, 0, stream>>>(wq, wk, wv, wg, wo, w1, w3, w2, wB);
  ln_rows<<<N_TOK, b256, 0, stream>>>(h_in, lnw, lnb, h_n_b);

  // fused QKVG projection: (1024x512) @ (2048x512)^T -> 1024x2048
  gemm_mfma<<<dim3(16, 8), b256, 0, stream>>>(h_n_b, wQKVGb, QKVG,
                                              N_TOK, D_MODEL, 2048, nullptr, nullptr);

  headln<<<128, b256, 0, stream>>>(QKVG, 2048);   // Q (cols 0-511) and K (cols 512-1023)

  copyf<<<64, b256, 0, stream>>>(lu0, out_lu, H_HEADS * N_TOK);
  copyf<<<64, b256, 0, stream>>>(lv0, out_lv, H_HEADS * N_TOK);
  copyf<<<12, b256, 0, stream>>>(x_res, out_x, N_TOK * 3);

  build_logK<<<dim3(N_TOK / 32, N_TOK / 32, H_HEADS), b256, 0, stream>>>(
      QKVG, QKVG + 512, 2048, x_res, bins, posw, wdl, eps, mask, logKb, logKTb);

  for (int it = 0; it < 20; ++it) {
    sink_pass<<<H_HEADS * N_TOK / 4, b256, 0, stream>>>(logKb, out_lv, mu, out_lu, eps);
    sink_pass<<<H_HEADS * N_TOK / 4, b256, 0, stream>>>(logKTb, out_lu, nu, out_lv, eps);
  }

  finalize<<<dim3(N_TOK / 32, H_HEADS), b256, 0, stream>>>(
      logKb, out_lu, out_lv, QKVG + 1024, QKVG + 1536, 2048, x_res, mask, o_b, out_x, gamma);

  // h_mid = h_in + (o @ wo^T) * mask
  gemm_mfma<<<dim3(4, 8), b256, 0, stream>>>(o_b, wob, h_mid,
                                             N_TOK, D_MODEL, D_MODEL, h_in, mask);

  ln_rows<<<N_TOK, b256, 0, stream>>>(h_mid, lnfw, lnfb, h2_b);

  // fused FFN up: (1024x512) @ (4096x512)^T -> 1024x4096 (w1 cols 0-2047, w3 cols 2048-4095)
  gemm_mfma<<<dim3(32, 8), b256, 0, stream>>>(h2_b, wFFb, ffab,
                                              N_TOK, D_MODEL, 4096, nullptr, nullptr);
  silu_mul_bf<<<(N_TOK * DFF) / 256, b256, 0, stream>>>(ffab, ff_b, N_TOK * DFF);

  // out_h = h_mid + (ff @ w2^T) * mask
  gemm_mfma<<<dim3(4, 8), b256, 0, stream>>>(ff_b, w2b, out_h,
                                             N_TOK, DFF, D_MODEL, h_mid, mask);
}

// Round 5
// 854.572 us; speedup vs baseline: 3.3235x; 1.1217x over previous
//
#include <hip/hip_runtime.h>
#include <cstddef>
#include <cstdint>

#define N_TOK 1024
#define D_MODEL 512
#define H_HEADS 16
#define DHEAD 32
#define DFF 2048

typedef __attribute__((ext_vector_type(8))) short short8;
typedef __attribute__((ext_vector_type(4))) float f32x4_t;

__device__ __forceinline__ float sigmoidf_(float x){ return 1.f/(1.f+__expf(-x)); }

__device__ __forceinline__ unsigned short f2bf(float f){
  union { float f; unsigned u; } v; v.f = f;
  unsigned r = (v.u + 0x7FFFu + ((v.u >> 16) & 1u)) >> 16;
  return (unsigned short)r;
}
__device__ __forceinline__ float bf_lo(unsigned u){ return __uint_as_float(u << 16); }
__device__ __forceinline__ float bf_hi(unsigned u){ return __uint_as_float(u & 0xFFFF0000u); }

// ---------------- LayerNorm over rows -> bf16 out ----------------
__global__ __launch_bounds__(256) void ln_rows(const float* __restrict__ x,
                                               const float* __restrict__ w,
                                               const float* __restrict__ b,
                                               unsigned short* __restrict__ y) {
  int row = blockIdx.x;
  const float* xr = x + (size_t)row * D_MODEL;
  float s = 0.f, s2 = 0.f;
  for (int i = threadIdx.x; i < D_MODEL; i += 256) { float v = xr[i]; s += v; s2 += v*v; }
  #pragma unroll
  for (int off = 32; off; off >>= 1) { s += __shfl_down(s, off); s2 += __shfl_down(s2, off); }
  __shared__ float rs[4], rs2[4];
  int wave = threadIdx.x >> 6, lane = threadIdx.x & 63;
  if (lane == 0) { rs[wave] = s; rs2[wave] = s2; }
  __syncthreads();
  s  = rs[0] + rs[1] + rs[2] + rs[3];
  s2 = rs2[0] + rs2[1] + rs2[2] + rs2[3];
  float mean = s * (1.f / D_MODEL);
  float var  = s2 * (1.f / D_MODEL) - mean * mean;
  float r = rsqrtf(var + 1e-5f);
  unsigned short* yr = y + (size_t)row * D_MODEL;
  for (int i = threadIdx.x; i < D_MODEL; i += 256)
    yr[i] = f2bf((xr[i] - mean) * r * w[i] + b[i]);
}

// ---------------- weight conversion fp32 -> bf16 ----------------
__global__ __launch_bounds__(256) void conv_weights(const float* __restrict__ wq,
                                                    const float* __restrict__ wk,
                                                    const float* __restrict__ wv,
                                                    const float* __restrict__ wg,
                                                    const float* __restrict__ wo,
                                                    const float* __restrict__ w1,
                                                    const float* __restrict__ w3,
                                                    const float* __restrict__ w2,
                                                    unsigned short* __restrict__ dst) {
  size_t i = ((size_t)blockIdx.x * 256 + threadIdx.x) * 4;
  const float* src; size_t off;
  if      (i < 262144)  { src = wq; off = i; }
  else if (i < 524288)  { src = wk; off = i - 262144; }
  else if (i < 786432)  { src = wv; off = i - 524288; }
  else if (i < 1048576) { src = wg; off = i - 786432; }
  else if (i < 1310720) { src = wo; off = i - 1048576; }
  else if (i < 2359296) { src = w1; off = i - 1310720; }
  else if (i < 3407872) { src = w3; off = i - 2359296; }
  else                  { src = w2; off = i - 3407872; }
  float4 v = *(const float4*)&src[off];
  unsigned lo = ((unsigned)f2bf(v.y) << 16) | f2bf(v.x);
  unsigned hi = ((unsigned)f2bf(v.w) << 16) | f2bf(v.z);
  *(uint2*)&dst[i] = make_uint2(lo, hi);
}

// ---------------- bf16 MFMA GEMM 128x128: C = A @ B^T ----------------
__global__ __launch_bounds__(256) void gemm_mfma(const unsigned short* __restrict__ A,
                                                 const unsigned short* __restrict__ B,
                                                 float* __restrict__ C,
                                                 int M, int K, int Nout,
                                                 const float* __restrict__ addmat,
                                                 const float* __restrict__ maskrow) {
  __shared__ unsigned short As[128][40];
  __shared__ unsigned short Bs[128][40];
  int t = threadIdx.x;
  int m0 = blockIdx.y * 128, n0 = blockIdx.x * 128;
  int wave = t >> 6, lane = t & 63;
  int wm = (wave >> 1) * 64, wn = (wave & 1) * 64;
  int lm = lane & 15, quad = lane >> 4;
  f32x4_t zero = {0.f, 0.f, 0.f, 0.f};
  f32x4_t acc[4][4];
  #pragma unroll
  for (int i = 0; i < 4; ++i)
    #pragma unroll
    for (int j = 0; j < 4; ++j) acc[i][j] = zero;

  int sr = t >> 2, sc = (t & 3) * 8;
  for (int kk = 0; kk < K; kk += 32) {
    #pragma unroll
    for (int c = 0; c < 2; ++c) {
      int r = sr + c * 64;
      *(uint4*)&As[r][sc] = *(const uint4*)&A[(size_t)(m0 + r) * K + kk + sc];
      *(uint4*)&Bs[r][sc] = *(const uint4*)&B[(size_t)(n0 + r) * K + kk + sc];
    }
    __syncthreads();
    short8 af[4], bfr[4];
    #pragma unroll
    for (int mt = 0; mt < 4; ++mt)
      af[mt] = *(const short8*)&As[wm + mt * 16 + lm][quad * 8];
    #pragma unroll
    for (int nt = 0; nt < 4; ++nt)
      bfr[nt] = *(const short8*)&Bs[wn + nt * 16 + lm][quad * 8];
    #pragma unroll
    for (int mt = 0; mt < 4; ++mt)
      #pragma unroll
      for (int nt = 0; nt < 4; ++nt)
        acc[mt][nt] = __builtin_amdgcn_mfma_f32_16x16x32_bf16(af[mt], bfr[nt], acc[mt][nt], 0, 0, 0);
    __syncthreads();
  }
  #pragma unroll
  for (int mt = 0; mt < 4; ++mt) {
    #pragma unroll
    for (int reg = 0; reg < 4; ++reg) {
      int gm = m0 + wm + mt * 16 + quad * 4 + reg;
      float mk = maskrow ? maskrow[gm] : 0.f;
      #pragma unroll
      for (int nt = 0; nt < 4; ++nt) {
        int gn = n0 + wn + nt * 16 + lm;
        float v = acc[mt][nt][reg];
        if (addmat) v = addmat[(size_t)gm * Nout + gn] + v * mk;
        C[(size_t)gm * Nout + gn] = v;
      }
    }
  }
}

// ---------------- bf16 MFMA GEMM 64x64 (for small GEMMs, 4x the blocks) ----------------
__global__ __launch_bounds__(256) void gemm_mfma64(const unsigned short* __restrict__ A,
                                                   const unsigned short* __restrict__ B,
                                                   float* __restrict__ C,
                                                   int M, int K, int Nout,
                                                   const float* __restrict__ addmat,
                                                   const float* __restrict__ maskrow) {
  __shared__ unsigned short As[64][40];
  __shared__ unsigned short Bs[64][40];
  int t = threadIdx.x;
  int m0 = blockIdx.y * 64, n0 = blockIdx.x * 64;
  int wave = t >> 6, lane = t & 63;
  int wm = (wave >> 1) * 32, wn = (wave & 1) * 32;
  int lm = lane & 15, quad = lane >> 4;
  f32x4_t zero = {0.f, 0.f, 0.f, 0.f};
  f32x4_t acc[2][2];
  #pragma unroll
  for (int i = 0; i < 2; ++i)
    #pragma unroll
    for (int j = 0; j < 2; ++j) acc[i][j] = zero;

  int sr = t >> 2, sc = (t & 3) * 8;
  for (int kk = 0; kk < K; kk += 32) {
    *(uint4*)&As[sr][sc] = *(const uint4*)&A[(size_t)(m0 + sr) * K + kk + sc];
    *(uint4*)&Bs[sr][sc] = *(const uint4*)&B[(size_t)(n0 + sr) * K + kk + sc];
    __syncthreads();
    short8 af[2], bfr[2];
    #pragma unroll
    for (int mt = 0; mt < 2; ++mt)
      af[mt] = *(const short8*)&As[wm + mt * 16 + lm][quad * 8];
    #pragma unroll
    for (int nt = 0; nt < 2; ++nt)
      bfr[nt] = *(const short8*)&Bs[wn + nt * 16 + lm][quad * 8];
    #pragma unroll
    for (int mt = 0; mt < 2; ++mt)
      #pragma unroll
      for (int nt = 0; nt < 2; ++nt)
        acc[mt][nt] = __builtin_amdgcn_mfma_f32_16x16x32_bf16(af[mt], bfr[nt], acc[mt][nt], 0, 0, 0);
    __syncthreads();
  }
  #pragma unroll
  for (int mt = 0; mt < 2; ++mt) {
    #pragma unroll
    for (int reg = 0; reg < 4; ++reg) {
      int gm = m0 + wm + mt * 16 + quad * 4 + reg;
      float mk = maskrow ? maskrow[gm] : 0.f;
      #pragma unroll
      for (int nt = 0; nt < 2; ++nt) {
        int gn = n0 + wn + nt * 16 + lm;
        float v = acc[mt][nt][reg];
        if (addmat) v = addmat[(size_t)gm * Nout + gn] + v * mk;
        C[(size_t)gm * Nout + gn] = v;
      }
    }
  }
}

// ---------------- per-head LN (no affine), Q and K regions of QKVG (ld=2048) ----------------
__global__ __launch_bounds__(256) void headln(float* __restrict__ base, int ld) {
  int g = blockIdx.x * 256 + threadIdx.x;
  int i = g & (N_TOK - 1), hh = g >> 10;    // hh 0..31
  float* p = base + (size_t)i * ld + hh * DHEAD;
  float s = 0.f, s2 = 0.f;
  #pragma unroll
  for (int k = 0; k < DHEAD; ++k) { float v = p[k]; s += v; s2 += v*v; }
  float m = s * (1.f / DHEAD);
  float var = s2 * (1.f / DHEAD) - m * m;
  float r = rsqrtf(var + 1e-5f);
  #pragma unroll
  for (int k = 0; k < DHEAD; ++k) p[k] = (p[k] - m) * r;
}

// ---------------- build logK (H, N, N) in bf16, row-major AND transposed ----------------
__global__ __launch_bounds__(256) void build_logK(const float* __restrict__ Q0,
                                                  const float* __restrict__ K0,
                                                  int ld,
                                                  const float* __restrict__ xres,
                                                  const int* __restrict__ bins,
                                                  const float* __restrict__ posw,
                                                  const float* __restrict__ wdl,
                                                  const float* __restrict__ epsp,
                                                  const float* __restrict__ mask,
                                                  unsigned short* __restrict__ logK,
                                                  unsigned short* __restrict__ logKT) {
  int h = blockIdx.z;
  int i0 = blockIdx.y * 32, j0 = blockIdx.x * 32;
  __shared__ float Qs[32][33], Ks[32][33], tileS[32][33];
  __shared__ float xi[32][3], xj[32][3], mi_s[32], mj_s[32];
  int tid = threadIdx.x;
  #pragma unroll
  for (int r = 0; r < 4; ++r) {
    int idx = tid + r * 256;
    int ii = idx >> 5, k = idx & 31;
    Qs[ii][k] = Q0[(size_t)(i0 + ii) * ld + h * DHEAD + k];
    Ks[ii][k] = K0[(size_t)(j0 + ii) * ld + h * DHEAD + k];
  }
  if (tid < 32) {
    xi[tid][0] = xres[(i0 + tid) * 3 + 0];
    xi[tid][1] = xres[(i0 + tid) * 3 + 1];
    xi[tid][2] = xres[(i0 + tid) * 3 + 2];
    xj[tid][0] = xres[(j0 + tid) * 3 + 0];
    xj[tid][1] = xres[(j0 + tid) * 3 + 1];
    xj[tid][2] = xres[(j0 + tid) * 3 + 2];
    mi_s[tid] = mask[i0 + tid];
    mj_s[tid] = mask[j0 + tid];
  }
  __syncthreads();
  float wd = sigmoidf_(wdl[h]);
  float inv_eps = 1.f / epsp[h];
  const float inv_sqrt = 0.17677669529663687f; // 1/sqrt(32)
  #pragma unroll
  for (int r = 0; r < 4; ++r) {
    int jl = tid & 31;
    int il = (tid >> 5) + r * 8;
    float dot = 0.f;
    #pragma unroll
    for (int k = 0; k < 32; ++k) dot += Qs[il][k] * Ks[jl][k];
    float d0 = xi[il][0] - xj[jl][0];
    float d1 = xi[il][1] - xj[jl][1];
    float d2c = xi[il][2] - xj[jl][2];
    float d2 = d0*d0 + d1*d1 + d2c*d2c;
    int gi = i0 + il, gj = j0 + jl;
    float bias = posw[bins[(size_t)gi * N_TOK + gj] * H_HEADS + h];
    float logit = dot * inv_sqrt + bias - wd * d2 * 0.01f;
    float outv = (mi_s[il] * mj_s[jl] > 0.f) ? logit * inv_eps : -1e9f;
    tileS[il][jl] = outv;
  }
  __syncthreads();
  {
    int il8 = tid >> 3, c8 = (tid & 7) * 4;
    unsigned lo = ((unsigned)f2bf(tileS[il8][c8 + 1]) << 16) | f2bf(tileS[il8][c8 + 0]);
    unsigned hi = ((unsigned)f2bf(tileS[il8][c8 + 3]) << 16) | f2bf(tileS[il8][c8 + 2]);
    uint2* dst = (uint2*)(logK + ((size_t)h * N_TOK + (i0 + il8)) * N_TOK + j0 + c8);
    *dst = make_uint2(lo, hi);
  }
  {
    int jt = tid >> 3, c8 = (tid & 7) * 4;
    unsigned lo = ((unsigned)f2bf(tileS[c8 + 1][jt]) << 16) | f2bf(tileS[c8 + 0][jt]);
    unsigned hi = ((unsigned)f2bf(tileS[c8 + 3][jt]) << 16) | f2bf(tileS[c8 + 2][jt]);
    uint2* dst = (uint2*)(logKT + ((size_t)h * N_TOK + (j0 + jt)) * N_TOK + i0 + c8);
    *dst = make_uint2(lo, hi);
  }
}

// ---------------- build VxT: Vxt[h][48][1024] bf16 = [V^T ; x^T ; ones ; pad] ----------------
__global__ __launch_bounds__(256) void build_vxt(const float* __restrict__ QKVG_,
                                                 const float* __restrict__ xres,
                                                 unsigned short* __restrict__ Vxt) {
  int h = blockIdx.x, j0 = blockIdx.y * 64;
  __shared__ float T[48][72];
  int t = threadIdx.x;
  {
    int j = t >> 2, c8 = (t & 3) * 8;
    const float* src = QKVG_ + (size_t)(j0 + j) * 2048 + 1024 + h * DHEAD + c8;
    float4 a = *(const float4*)src, b = *(const float4*)(src + 4);
    T[c8 + 0][j] = a.x; T[c8 + 1][j] = a.y; T[c8 + 2][j] = a.z; T[c8 + 3][j] = a.w;
    T[c8 + 4][j] = b.x; T[c8 + 5][j] = b.y; T[c8 + 6][j] = b.z; T[c8 + 7][j] = b.w;
  }
  if (t < 64) {
    int j = t;
    T[32][j] = xres[(j0 + j) * 3 + 0];
    T[33][j] = xres[(j0 + j) * 3 + 1];
    T[34][j] = xres[(j0 + j) * 3 + 2];
    T[35][j] = 1.f;
    #pragma unroll
    for (int d = 36; d < 48; ++d) T[d][j] = 0.f;
  }
  __syncthreads();
  for (int task = t; task < 384; task += 256) {
    int d = task >> 3, jc = (task & 7) * 8;
    float* s = &T[d][jc];
    unsigned a0 = ((unsigned)f2bf(s[1]) << 16) | f2bf(s[0]);
    unsigned a1 = ((unsigned)f2bf(s[3]) << 16) | f2bf(s[2]);
    unsigned a2 = ((unsigned)f2bf(s[5]) << 16) | f2bf(s[4]);
    unsigned a3 = ((unsigned)f2bf(s[7]) << 16) | f2bf(s[6]);
    *(uint4*)(Vxt + ((size_t)h * 48 + d) * N_TOK + j0 + jc) = make_uint4(a0, a1, a2, a3);
  }
}

// ---------------- online-lse over one bf16 row + dual-vector ----------------
__device__ __forceinline__ float row_lse(const unsigned short* __restrict__ rp,
                                         const float* ov, int lane) {
  const uint4* p = (const uint4*)rp;
  float m8[8], s8[8];
  #pragma unroll
  for (int c = 0; c < 8; ++c) { m8[c] = -3.0e38f; s8[c] = 0.f; }
  #pragma unroll
  for (int it = 0; it < 2; ++it) {
    int j0 = it * 512 + lane * 8;
    uint4 u = p[it * 64 + lane];
    float4 lva = ((const float4*)ov)[j0 >> 2];
    float4 lvb = ((const float4*)ov)[(j0 >> 2) + 1];
    float xv[8];
    xv[0] = bf_lo(u.x) + lva.x; xv[1] = bf_hi(u.x) + lva.y;
    xv[2] = bf_lo(u.y) + lva.z; xv[3] = bf_hi(u.y) + lva.w;
    xv[4] = bf_lo(u.z) + lvb.x; xv[5] = bf_hi(u.z) + lvb.y;
    xv[6] = bf_lo(u.w) + lvb.z; xv[7] = bf_hi(u.w) + lvb.w;
    #pragma unroll
    for (int c = 0; c < 8; ++c) {
      float M = fmaxf(m8[c], xv[c]);
      s8[c] = s8[c] * __expf(m8[c] - M) + __expf(xv[c] - M);
      m8[c] = M;
    }
  }
  #pragma unroll
  for (int st = 4; st; st >>= 1)
    #pragma unroll
    for (int c = 0; c < 4; ++c) if (c < st) {
      float M = fmaxf(m8[c], m8[c + st]);
      s8[c] = s8[c] * __expf(m8[c] - M) + s8[c + st] * __expf(m8[c + st] - M);
      m8[c] = M;
    }
  float m = m8[0], s = s8[0];
  #pragma unroll
  for (int off = 32; off; off >>= 1) {
    float m2 = __shfl_xor(m, off);
    float s2 = __shfl_xor(s, off);
    float M = fmaxf(m, m2);
    s = s * __expf(m - M) + s2 * __expf(m2 - M);
    m = M;
  }
  return m + __logf(s);
}

// ---------------- Sinkhorn pass: 16 rows per block (4 per wave) ----------------
// out[h,i] = fi_h * (log(max(marg[h,i],1e-8)) - lse_j(src[h,i,j] + other[h,j]))
__global__ __launch_bounds__(256) void sink_pass(const unsigned short* __restrict__ src,
                                                 const float* __restrict__ other,
                                                 const float* __restrict__ marg,
                                                 float* __restrict__ outlog,
                                                 const float* __restrict__ epsp) {
  __shared__ float ov[N_TOK];
  int t = threadIdx.x, wave = t >> 6, lane = t & 63;
  int rblk = blockIdx.x * 16;               // 1024 blocks x 16 rows = 16384 rows
  int h = rblk >> 10;                        // 16 | 1024 -> uniform per block
  ((float4*)ov)[t] = ((const float4*)(other + h * N_TOK))[t];
  __syncthreads();
  float fi = 1.f / (1.f + epsp[h]);          // LAM=1
  #pragma unroll
  for (int q = 0; q < 4; ++q) {
    int row = rblk + wave * 4 + q;
    int i = row & (N_TOK - 1);
    float lse = row_lse(src + (size_t)row * N_TOK, ov, lane);
    if (lane == 0) {
      float lm = __logf(fmaxf(marg[h * N_TOK + i], 1e-8f));
      outlog[h * N_TOK + i] = fi * (lm - lse);
    }
  }
}

// ---------------- MFMA finalize: P computed in-register -> A-frag; B = Vxt ----------------
// D[row][0..31]=O_unnorm, [32..34]=x_cent_unnorm, [35]=rowsum
__global__ __launch_bounds__(256) void finalize_mfma(const unsigned short* __restrict__ logK,
                                                     const float* __restrict__ logu,
                                                     const float* __restrict__ logv,
                                                     const unsigned short* __restrict__ Vxt,
                                                     const float* __restrict__ G0, int ld,
                                                     const float* __restrict__ xres,
                                                     const float* __restrict__ mask,
                                                     unsigned short* __restrict__ o,
                                                     float* __restrict__ x_out,
                                                     const float* __restrict__ gamma) {
  int mt = blockIdx.x;           // 16 m-tiles of 64 rows
  int h = blockIdx.y;
  int t = threadIdx.x, wave = t >> 6, lane = t & 63;
  int lm = lane & 15, quad = lane >> 4;
  __shared__ float lvs[N_TOK];
  ((float4*)lvs)[t] = ((const float4*)(logv + h * N_TOK))[t];
  __syncthreads();
  int arow = mt * 64 + wave * 16 + lm;        // A-operand row for this lane
  float lu = logu[h * N_TOK + arow];
  const unsigned short* Kr = logK + ((size_t)h * N_TOK + arow) * N_TOK + quad * 8;
  const unsigned short* Bb = Vxt + (size_t)h * 48 * N_TOK + quad * 8;
  f32x4_t zero = {0.f, 0.f, 0.f, 0.f};
  f32x4_t acc[3] = {zero, zero, zero};
  for (int kk = 0; kk < N_TOK; kk += 32) {
    uint4 u = *(const uint4*)(Kr + kk);
    float4 la = *(const float4*)&lvs[kk + quad * 8];
    float4 lb = *(const float4*)&lvs[kk + quad * 8 + 4];
    float p0 = __expf(bf_lo(u.x) + lu + la.x);
    float p1 = __expf(bf_hi(u.x) + lu + la.y);
    float p2 = __expf(bf_lo(u.y) + lu + la.z);
    float p3 = __expf(bf_hi(u.y) + lu + la.w);
    float p4 = __expf(bf_lo(u.z) + lu + lb.x);
    float p5 = __expf(bf_hi(u.z) + lu + lb.y);
    float p6 = __expf(bf_lo(u.w) + lu + lb.z);
    float p7 = __expf(bf_hi(u.w) + lu + lb.w);
    union { uint4 u4; short8 s8; } pk;
    pk.u4 = make_uint4(((unsigned)f2bf(p1) << 16) | f2bf(p0),
                       ((unsigned)f2bf(p3) << 16) | f2bf(p2),
                       ((unsigned)f2bf(p5) << 16) | f2bf(p4),
                       ((unsigned)f2bf(p7) << 16) | f2bf(p6));
    short8 af = pk.s8;
    #pragma unroll
    for (int nt = 0; nt < 3; ++nt) {
      short8 bfrag = *(const short8*)(Bb + (size_t)(nt * 16 + lm) * N_TOK + kk);
      acc[nt] = __builtin_amdgcn_mfma_f32_16x16x32_bf16(af, bfrag, acc[nt], 0, 0, 0);
    }
  }
  // epilogue: C-layout row = quad*4+reg, col = nt*16+lm; rowsum at col 35 (nt=2, lm=3)
  float inv[4];
  #pragma unroll
  for (int reg = 0; reg < 4; ++reg) {
    float rsum = __shfl(acc[2][reg], (quad << 4) | 3, 64);
    inv[reg] = 1.f / fmaxf(rsum, 1e-8f);
  }
  #pragma unroll
  for (int nt = 0; nt < 2; ++nt) {
    int c = nt * 16 + lm;
    #pragma unroll
    for (int reg = 0; reg < 4; ++reg) {
      int r = mt * 64 + wave * 16 + quad * 4 + reg;
      float gv = G0[(size_t)r * ld + h * DHEAD + c];
      float ovl = acc[nt][reg] * inv[reg] * sigmoidf_(gv);
      o[(size_t)r * D_MODEL + h * DHEAD + c] = f2bf(ovl);
    }
  }
  if (lm < 3) {
    float tg = tanhf(gamma[h]) * (1.f / H_HEADS);
    #pragma unroll
    for (int reg = 0; reg < 4; ++reg) {
      int r = mt * 64 + wave * 16 + quad * 4 + reg;
      float xc = acc[2][reg] * inv[reg];
      float mi = mask[r];
      atomicAdd(&x_out[r * 3 + lm], tg * mi * (xres[r * 3 + lm] - xc));
    }
  }
}

// ---------------- silu+mul from fused ffab (1024x4096) -> bf16 (1024x2048) ----------------
__global__ __launch_bounds__(256) void silu_mul_bf(const float* __restrict__ ffab,
                                                   unsigned short* __restrict__ out, int n) {
  int i = blockIdx.x * 256 + threadIdx.x;
  if (i >= n) return;
  int row = i >> 11, col = i & 2047;
  float a = ffab[(size_t)row * 4096 + col];
  float bb = ffab[(size_t)row * 4096 + 2048 + col];
  out[i] = f2bf(a * sigmoidf_(a) * bb);
}

__global__ __launch_bounds__(256) void copyf(const float* __restrict__ src,
                                             float* __restrict__ dst, int n) {
  int i = blockIdx.x * 256 + threadIdx.x;
  if (i < n) dst[i] = src[i];
}

extern "C" void kernel_launch(void* const* d_in, const int* in_sizes, int n_in,
                              void* d_out, int out_size, void* d_ws, size_t ws_size,
                              hipStream_t stream) {
  const float* h_in  = (const float*)d_in[0];
  const float* x_res = (const float*)d_in[1];
  const float* mu    = (const float*)d_in[2];
  const float* nu    = (const float*)d_in[3];
  const float* lu0   = (const float*)d_in[4];
  const float* lv0   = (const float*)d_in[5];
  const float* mask  = (const float*)d_in[6];
  const float* lnw   = (const float*)d_in[7];
  const float* lnb   = (const float*)d_in[8];
  const float* wq    = (const float*)d_in[9];
  const float* wk    = (const float*)d_in[10];
  const float* wv    = (const float*)d_in[11];
  const float* wg    = (const float*)d_in[12];
  const float* wo    = (const float*)d_in[13];
  const float* gamma = (const float*)d_in[14];
  const float* posw  = (const float*)d_in[15];
  const float* wdl   = (const float*)d_in[16];
  const float* lnfw  = (const float*)d_in[17];
  const float* lnfb  = (const float*)d_in[18];
  const float* w1    = (const float*)d_in[19];
  const float* w3    = (const float*)d_in[20];
  const float* w2    = (const float*)d_in[21];
  const int*   bins  = (const int*)d_in[22];
  const float* eps   = (const float*)d_in[23];

  float* out    = (float*)d_out;
  float* out_h  = out;                     // 1024*512
  float* out_x  = out + 524288;            // 1024*3
  float* out_lu = out + 527360;            // 16*1024
  float* out_lv = out + 543744;            // 16*1024

  float* ws = (float*)d_ws;
  float* QKVG  = ws;                       // 1024 x 2048 (Q|K|V|G)
  float* h_mid = ws + 2097152;             // 1024 x 512
  unsigned short* U = (unsigned short*)(ws + 2621440);
  unsigned short* h_n_b  = U;              // 1024x512
  unsigned short* h2_b   = U + 524288;     // 1024x512
  unsigned short* o_b    = U + 1048576;    // 1024x512
  unsigned short* wB     = U + 1572864;    // 4456448 bf16 weights
  unsigned short* logKb  = (unsigned short*)(ws + 5636096);  // H*N*N bf16
  unsigned short* logKTb = logKb + (size_t)H_HEADS * N_TOK * N_TOK;
  unsigned short* Vxt    = logKTb + (size_t)H_HEADS * N_TOK * N_TOK; // 16*48*1024 bf16
  float* ffab            = (float*)logKb;        // reuse after finalize
  unsigned short* ff_b   = logKTb;

  unsigned short* wQKVGb = wB;                 // 2048 x 512
  unsigned short* wob    = wB + 1048576;       // 512 x 512
  unsigned short* wFFb   = wB + 1310720;       // 4096 x 512
  unsigned short* w2b    = wB + 3407872;       // 512 x 2048

  dim3 b256(256);

  conv_weights<<<4352, b256, 0, stream>>>(wq, wk, wv, wg, wo, w1, w3, w2, wB);
  ln_rows<<<N_TOK, b256, 0, stream>>>(h_in, lnw, lnb, h_n_b);

  gemm_mfma<<<dim3(16, 8), b256, 0, stream>>>(h_n_b, wQKVGb, QKVG,
                                              N_TOK, D_MODEL, 2048, nullptr, nullptr);

  headln<<<128, b256, 0, stream>>>(QKVG, 2048);

  copyf<<<64, b256, 0, stream>>>(lu0, out_lu, H_HEADS * N_TOK);
  copyf<<<64, b256, 0, stream>>>(lv0, out_lv, H_HEADS * N_TOK);
  copyf<<<12, b256, 0, stream>>>(x_res, out_x, N_TOK * 3);

  build_logK<<<dim3(N_TOK / 32, N_TOK / 32, H_HEADS), b256, 0, stream>>>(
      QKVG, QKVG + 512, 2048, x_res, bins, posw, wdl, eps, mask, logKb, logKTb);
  build_vxt<<<dim3(H_HEADS, N_TOK / 64), b256, 0, stream>>>(QKVG, x_res, Vxt);

  for (int it = 0; it < 20; ++it) {
    sink_pass<<<H_HEADS * N_TOK / 16, b256, 0, stream>>>(logKb, out_lv, mu, out_lu, eps);
    sink_pass<<<H_HEADS * N_TOK / 16, b256, 0, stream>>>(logKTb, out_lu, nu, out_lv, eps);
  }

  finalize_mfma<<<dim3(16, H_HEADS), b256, 0, stream>>>(
      logKb, out_lu, out_lv, Vxt, QKVG + 1536, 2048, x_res, mask, o_b, out_x, gamma);

  gemm_mfma64<<<dim3(8, 16), b256, 0, stream>>>(o_b, wob, h_mid,
                                                N_TOK, D_MODEL, D_MODEL, h_in, mask);

  ln_rows<<<N_TOK, b256, 0, stream>>>(h_mid, lnfw, lnfb, h2_b);

  gemm_mfma<<<dim3(32, 8), b256, 0, stream>>>(h2_b, wFFb, ffab,
                                              N_TOK, D_MODEL, 4096, nullptr, nullptr);
  silu_mul_bf<<<(N_TOK * DFF) / 256, b256, 0, stream>>>(ffab, ff_b, N_TOK * DFF);

  gemm_mfma64<<<dim3(8, 16), b256, 0, stream>>>(ff_b, w2b, out_h,
                                                N_TOK, DFF, D_MODEL, h_mid, mask);
}

// Round 6
// 617.410 us; speedup vs baseline: 4.6001x; 1.3841x over previous
//
#include <hip/hip_runtime.h>
#include <cstddef>
#include <cstdint>

#define N_TOK 1024
#define D_MODEL 512
#define H_HEADS 16
#define DHEAD 32
#define DFF 2048

typedef __attribute__((ext_vector_type(8))) short short8;
typedef __attribute__((ext_vector_type(4))) float f32x4_t;

__device__ __forceinline__ float sigmoidf_(float x){ return 1.f/(1.f+__expf(-x)); }

__device__ __forceinline__ unsigned short f2bf(float f){
  union { float f; unsigned u; } v; v.f = f;
  unsigned r = (v.u + 0x7FFFu + ((v.u >> 16) & 1u)) >> 16;
  return (unsigned short)r;
}
__device__ __forceinline__ float bf_lo(unsigned u){ return __uint_as_float(u << 16); }
__device__ __forceinline__ float bf_hi(unsigned u){ return __uint_as_float(u & 0xFFFF0000u); }

// ---------------- LayerNorm over rows -> bf16 out ----------------
__global__ __launch_bounds__(256) void ln_rows(const float* __restrict__ x,
                                               const float* __restrict__ w,
                                               const float* __restrict__ b,
                                               unsigned short* __restrict__ y) {
  int row = blockIdx.x;
  const float* xr = x + (size_t)row * D_MODEL;
  float s = 0.f, s2 = 0.f;
  for (int i = threadIdx.x; i < D_MODEL; i += 256) { float v = xr[i]; s += v; s2 += v*v; }
  #pragma unroll
  for (int off = 32; off; off >>= 1) { s += __shfl_down(s, off); s2 += __shfl_down(s2, off); }
  __shared__ float rs[4], rs2[4];
  int wave = threadIdx.x >> 6, lane = threadIdx.x & 63;
  if (lane == 0) { rs[wave] = s; rs2[wave] = s2; }
  __syncthreads();
  s  = rs[0] + rs[1] + rs[2] + rs[3];
  s2 = rs2[0] + rs2[1] + rs2[2] + rs2[3];
  float mean = s * (1.f / D_MODEL);
  float var  = s2 * (1.f / D_MODEL) - mean * mean;
  float r = rsqrtf(var + 1e-5f);
  unsigned short* yr = y + (size_t)row * D_MODEL;
  for (int i = threadIdx.x; i < D_MODEL; i += 256)
    yr[i] = f2bf((xr[i] - mean) * r * w[i] + b[i]);
}

// ---------------- weight conversion fp32 -> bf16 ----------------
__global__ __launch_bounds__(256) void conv_weights(const float* __restrict__ wq,
                                                    const float* __restrict__ wk,
                                                    const float* __restrict__ wv,
                                                    const float* __restrict__ wg,
                                                    const float* __restrict__ wo,
                                                    const float* __restrict__ w1,
                                                    const float* __restrict__ w3,
                                                    const float* __restrict__ w2,
                                                    unsigned short* __restrict__ dst) {
  size_t i = ((size_t)blockIdx.x * 256 + threadIdx.x) * 4;
  const float* src; size_t off;
  if      (i < 262144)  { src = wq; off = i; }
  else if (i < 524288)  { src = wk; off = i - 262144; }
  else if (i < 786432)  { src = wv; off = i - 524288; }
  else if (i < 1048576) { src = wg; off = i - 786432; }
  else if (i < 1310720) { src = wo; off = i - 1048576; }
  else if (i < 2359296) { src = w1; off = i - 1310720; }
  else if (i < 3407872) { src = w3; off = i - 2359296; }
  else                  { src = w2; off = i - 3407872; }
  float4 v = *(const float4*)&src[off];
  unsigned lo = ((unsigned)f2bf(v.y) << 16) | f2bf(v.x);
  unsigned hi = ((unsigned)f2bf(v.w) << 16) | f2bf(v.z);
  *(uint2*)&dst[i] = make_uint2(lo, hi);
}

// ---------------- bf16 MFMA GEMM 128x128: C = A @ B^T ----------------
__global__ __launch_bounds__(256) void gemm_mfma(const unsigned short* __restrict__ A,
                                                 const unsigned short* __restrict__ B,
                                                 float* __restrict__ C,
                                                 int M, int K, int Nout,
                                                 const float* __restrict__ addmat,
                                                 const float* __restrict__ maskrow) {
  __shared__ unsigned short As[128][40];
  __shared__ unsigned short Bs[128][40];
  int t = threadIdx.x;
  int m0 = blockIdx.y * 128, n0 = blockIdx.x * 128;
  int wave = t >> 6, lane = t & 63;
  int wm = (wave >> 1) * 64, wn = (wave & 1) * 64;
  int lm = lane & 15, quad = lane >> 4;
  f32x4_t zero = {0.f, 0.f, 0.f, 0.f};
  f32x4_t acc[4][4];
  #pragma unroll
  for (int i = 0; i < 4; ++i)
    #pragma unroll
    for (int j = 0; j < 4; ++j) acc[i][j] = zero;

  int sr = t >> 2, sc = (t & 3) * 8;
  for (int kk = 0; kk < K; kk += 32) {
    #pragma unroll
    for (int c = 0; c < 2; ++c) {
      int r = sr + c * 64;
      *(uint4*)&As[r][sc] = *(const uint4*)&A[(size_t)(m0 + r) * K + kk + sc];
      *(uint4*)&Bs[r][sc] = *(const uint4*)&B[(size_t)(n0 + r) * K + kk + sc];
    }
    __syncthreads();
    short8 af[4], bfr[4];
    #pragma unroll
    for (int mt = 0; mt < 4; ++mt)
      af[mt] = *(const short8*)&As[wm + mt * 16 + lm][quad * 8];
    #pragma unroll
    for (int nt = 0; nt < 4; ++nt)
      bfr[nt] = *(const short8*)&Bs[wn + nt * 16 + lm][quad * 8];
    #pragma unroll
    for (int mt = 0; mt < 4; ++mt)
      #pragma unroll
      for (int nt = 0; nt < 4; ++nt)
        acc[mt][nt] = __builtin_amdgcn_mfma_f32_16x16x32_bf16(af[mt], bfr[nt], acc[mt][nt], 0, 0, 0);
    __syncthreads();
  }
  #pragma unroll
  for (int mt = 0; mt < 4; ++mt) {
    #pragma unroll
    for (int reg = 0; reg < 4; ++reg) {
      int gm = m0 + wm + mt * 16 + quad * 4 + reg;
      float mk = maskrow ? maskrow[gm] : 0.f;
      #pragma unroll
      for (int nt = 0; nt < 4; ++nt) {
        int gn = n0 + wn + nt * 16 + lm;
        float v = acc[mt][nt][reg];
        if (addmat) v = addmat[(size_t)gm * Nout + gn] + v * mk;
        C[(size_t)gm * Nout + gn] = v;
      }
    }
  }
}

// ---------------- bf16 MFMA GEMM 64x64 (for small GEMMs, 4x the blocks) ----------------
__global__ __launch_bounds__(256) void gemm_mfma64(const unsigned short* __restrict__ A,
                                                   const unsigned short* __restrict__ B,
                                                   float* __restrict__ C,
                                                   int M, int K, int Nout,
                                                   const float* __restrict__ addmat,
                                                   const float* __restrict__ maskrow) {
  __shared__ unsigned short As[64][40];
  __shared__ unsigned short Bs[64][40];
  int t = threadIdx.x;
  int m0 = blockIdx.y * 64, n0 = blockIdx.x * 64;
  int wave = t >> 6, lane = t & 63;
  int wm = (wave >> 1) * 32, wn = (wave & 1) * 32;
  int lm = lane & 15, quad = lane >> 4;
  f32x4_t zero = {0.f, 0.f, 0.f, 0.f};
  f32x4_t acc[2][2];
  #pragma unroll
  for (int i = 0; i < 2; ++i)
    #pragma unroll
    for (int j = 0; j < 2; ++j) acc[i][j] = zero;

  int sr = t >> 2, sc = (t & 3) * 8;
  for (int kk = 0; kk < K; kk += 32) {
    *(uint4*)&As[sr][sc] = *(const uint4*)&A[(size_t)(m0 + sr) * K + kk + sc];
    *(uint4*)&Bs[sr][sc] = *(const uint4*)&B[(size_t)(n0 + sr) * K + kk + sc];
    __syncthreads();
    short8 af[2], bfr[2];
    #pragma unroll
    for (int mt = 0; mt < 2; ++mt)
      af[mt] = *(const short8*)&As[wm + mt * 16 + lm][quad * 8];
    #pragma unroll
    for (int nt = 0; nt < 2; ++nt)
      bfr[nt] = *(const short8*)&Bs[wn + nt * 16 + lm][quad * 8];
    #pragma unroll
    for (int mt = 0; mt < 2; ++mt)
      #pragma unroll
      for (int nt = 0; nt < 2; ++nt)
        acc[mt][nt] = __builtin_amdgcn_mfma_f32_16x16x32_bf16(af[mt], bfr[nt], acc[mt][nt], 0, 0, 0);
    __syncthreads();
  }
  #pragma unroll
  for (int mt = 0; mt < 2; ++mt) {
    #pragma unroll
    for (int reg = 0; reg < 4; ++reg) {
      int gm = m0 + wm + mt * 16 + quad * 4 + reg;
      float mk = maskrow ? maskrow[gm] : 0.f;
      #pragma unroll
      for (int nt = 0; nt < 2; ++nt) {
        int gn = n0 + wn + nt * 16 + lm;
        float v = acc[mt][nt][reg];
        if (addmat) v = addmat[(size_t)gm * Nout + gn] + v * mk;
        C[(size_t)gm * Nout + gn] = v;
      }
    }
  }
}

// ---------------- per-head LN (no affine), Q and K regions of QKVG (ld=2048) ----------------
__global__ __launch_bounds__(256) void headln(float* __restrict__ base, int ld) {
  int g = blockIdx.x * 256 + threadIdx.x;
  int i = g & (N_TOK - 1), hh = g >> 10;    // hh 0..31
  float* p = base + (size_t)i * ld + hh * DHEAD;
  float s = 0.f, s2 = 0.f;
  #pragma unroll
  for (int k = 0; k < DHEAD; ++k) { float v = p[k]; s += v; s2 += v*v; }
  float m = s * (1.f / DHEAD);
  float var = s2 * (1.f / DHEAD) - m * m;
  float r = rsqrtf(var + 1e-5f);
  #pragma unroll
  for (int k = 0; k < DHEAD; ++k) p[k] = (p[k] - m) * r;
}

// ---------------- build W (H, N, N) = exp(logK) in bf16, row-major AND transposed --------
__global__ __launch_bounds__(256) void build_W(const float* __restrict__ Q0,
                                               const float* __restrict__ K0,
                                               int ld,
                                               const float* __restrict__ xres,
                                               const int* __restrict__ bins,
                                               const float* __restrict__ posw,
                                               const float* __restrict__ wdl,
                                               const float* __restrict__ epsp,
                                               const float* __restrict__ mask,
                                               unsigned short* __restrict__ Wm,
                                               unsigned short* __restrict__ WmT) {
  int h = blockIdx.z;
  int i0 = blockIdx.y * 32, j0 = blockIdx.x * 32;
  __shared__ float Qs[32][33], Ks[32][33], tileS[32][33];
  __shared__ float xi[32][3], xj[32][3], mi_s[32], mj_s[32];
  int tid = threadIdx.x;
  #pragma unroll
  for (int r = 0; r < 4; ++r) {
    int idx = tid + r * 256;
    int ii = idx >> 5, k = idx & 31;
    Qs[ii][k] = Q0[(size_t)(i0 + ii) * ld + h * DHEAD + k];
    Ks[ii][k] = K0[(size_t)(j0 + ii) * ld + h * DHEAD + k];
  }
  if (tid < 32) {
    xi[tid][0] = xres[(i0 + tid) * 3 + 0];
    xi[tid][1] = xres[(i0 + tid) * 3 + 1];
    xi[tid][2] = xres[(i0 + tid) * 3 + 2];
    xj[tid][0] = xres[(j0 + tid) * 3 + 0];
    xj[tid][1] = xres[(j0 + tid) * 3 + 1];
    xj[tid][2] = xres[(j0 + tid) * 3 + 2];
    mi_s[tid] = mask[i0 + tid];
    mj_s[tid] = mask[j0 + tid];
  }
  __syncthreads();
  float wd = sigmoidf_(wdl[h]);
  float inv_eps = 1.f / epsp[h];
  const float inv_sqrt = 0.17677669529663687f; // 1/sqrt(32)
  #pragma unroll
  for (int r = 0; r < 4; ++r) {
    int jl = tid & 31;
    int il = (tid >> 5) + r * 8;
    float dot = 0.f;
    #pragma unroll
    for (int k = 0; k < 32; ++k) dot += Qs[il][k] * Ks[jl][k];
    float d0 = xi[il][0] - xj[jl][0];
    float d1 = xi[il][1] - xj[jl][1];
    float d2c = xi[il][2] - xj[jl][2];
    float d2 = d0*d0 + d1*d1 + d2c*d2c;
    int gi = i0 + il, gj = j0 + jl;
    float bias = posw[bins[(size_t)gi * N_TOK + gj] * H_HEADS + h];
    float logit = dot * inv_sqrt + bias - wd * d2 * 0.01f;
    // W = exp(logK); masked pairs -> exactly 0 (equivalent to -inf in log domain)
    float outv = (mi_s[il] * mj_s[jl] > 0.f) ? __expf(logit * inv_eps) : 0.f;
    tileS[il][jl] = outv;
  }
  __syncthreads();
  {
    int il8 = tid >> 3, c8 = (tid & 7) * 4;
    unsigned lo = ((unsigned)f2bf(tileS[il8][c8 + 1]) << 16) | f2bf(tileS[il8][c8 + 0]);
    unsigned hi = ((unsigned)f2bf(tileS[il8][c8 + 3]) << 16) | f2bf(tileS[il8][c8 + 2]);
    uint2* dst = (uint2*)(Wm + ((size_t)h * N_TOK + (i0 + il8)) * N_TOK + j0 + c8);
    *dst = make_uint2(lo, hi);
  }
  {
    int jt = tid >> 3, c8 = (tid & 7) * 4;
    unsigned lo = ((unsigned)f2bf(tileS[c8 + 1][jt]) << 16) | f2bf(tileS[c8 + 0][jt]);
    unsigned hi = ((unsigned)f2bf(tileS[c8 + 3][jt]) << 16) | f2bf(tileS[c8 + 2][jt]);
    uint2* dst = (uint2*)(WmT + ((size_t)h * N_TOK + (j0 + jt)) * N_TOK + i0 + c8);
    *dst = make_uint2(lo, hi);
  }
}

// ---------------- build VxT: Vxt[h][48][1024] bf16 = [V^T ; x^T ; ones ; pad] ----------------
__global__ __launch_bounds__(256) void build_vxt(const float* __restrict__ QKVG_,
                                                 const float* __restrict__ xres,
                                                 unsigned short* __restrict__ Vxt) {
  int h = blockIdx.x, j0 = blockIdx.y * 64;
  __shared__ float T[48][72];
  int t = threadIdx.x;
  {
    int j = t >> 2, c8 = (t & 3) * 8;
    const float* src = QKVG_ + (size_t)(j0 + j) * 2048 + 1024 + h * DHEAD + c8;
    float4 a = *(const float4*)src, b = *(const float4*)(src + 4);
    T[c8 + 0][j] = a.x; T[c8 + 1][j] = a.y; T[c8 + 2][j] = a.z; T[c8 + 3][j] = a.w;
    T[c8 + 4][j] = b.x; T[c8 + 5][j] = b.y; T[c8 + 6][j] = b.z; T[c8 + 7][j] = b.w;
  }
  if (t < 64) {
    int j = t;
    T[32][j] = xres[(j0 + j) * 3 + 0];
    T[33][j] = xres[(j0 + j) * 3 + 1];
    T[34][j] = xres[(j0 + j) * 3 + 2];
    T[35][j] = 1.f;
    #pragma unroll
    for (int d = 36; d < 48; ++d) T[d][j] = 0.f;
  }
  __syncthreads();
  for (int task = t; task < 384; task += 256) {
    int d = task >> 3, jc = (task & 7) * 8;
    float* s = &T[d][jc];
    unsigned a0 = ((unsigned)f2bf(s[1]) << 16) | f2bf(s[0]);
    unsigned a1 = ((unsigned)f2bf(s[3]) << 16) | f2bf(s[2]);
    unsigned a2 = ((unsigned)f2bf(s[5]) << 16) | f2bf(s[4]);
    unsigned a3 = ((unsigned)f2bf(s[7]) << 16) | f2bf(s[6]);
    *(uint4*)(Vxt + ((size_t)h * 48 + d) * N_TOK + j0 + jc) = make_uint4(a0, a1, a2, a3);
  }
}

// ---------------- linear-domain Sinkhorn pass: 16 rows/block ----------------
// out[h,i] = fi_h * (log(max(marg,1e-8)) - log(Sum_j W[h,i,j] * exp(other[h,j])))
__global__ __launch_bounds__(256) void sink_lin(const unsigned short* __restrict__ Wsrc,
                                                const float* __restrict__ otherlog,
                                                const float* __restrict__ marg,
                                                float* __restrict__ outlog,
                                                const float* __restrict__ epsp) {
  __shared__ float vt[N_TOK];
  int t = threadIdx.x, wave = t >> 6, lane = t & 63;
  int rblk = blockIdx.x * 16;               // 1024 blocks x 16 rows
  int h = rblk >> 10;
  {
    float4 lv = ((const float4*)(otherlog + h * N_TOK))[t];
    float4 ev;
    ev.x = __expf(lv.x); ev.y = __expf(lv.y);
    ev.z = __expf(lv.z); ev.w = __expf(lv.w);
    ((float4*)vt)[t] = ev;
  }
  __syncthreads();
  float fi = 1.f / (1.f + epsp[h]);          // LAM=1
  #pragma unroll
  for (int q = 0; q < 4; ++q) {
    int row = rblk + wave * 4 + q;
    int i = row & (N_TOK - 1);
    const uint4* p = (const uint4*)(Wsrc + (size_t)row * N_TOK);
    float s8[8];
    #pragma unroll
    for (int c = 0; c < 8; ++c) s8[c] = 0.f;
    #pragma unroll
    for (int it = 0; it < 2; ++it) {
      int j0 = it * 512 + lane * 8;
      uint4 u = p[it * 64 + lane];
      float4 va = ((const float4*)vt)[j0 >> 2];
      float4 vb = ((const float4*)vt)[(j0 >> 2) + 1];
      s8[0] += bf_lo(u.x) * va.x; s8[1] += bf_hi(u.x) * va.y;
      s8[2] += bf_lo(u.y) * va.z; s8[3] += bf_hi(u.y) * va.w;
      s8[4] += bf_lo(u.z) * vb.x; s8[5] += bf_hi(u.z) * vb.y;
      s8[6] += bf_lo(u.w) * vb.z; s8[7] += bf_hi(u.w) * vb.w;
    }
    float s = ((s8[0] + s8[1]) + (s8[2] + s8[3])) + ((s8[4] + s8[5]) + (s8[6] + s8[7]));
    #pragma unroll
    for (int off = 32; off; off >>= 1) s += __shfl_xor(s, off);
    if (lane == 0) {
      float lm = __logf(fmaxf(marg[h * N_TOK + i], 1e-8f));
      outlog[h * N_TOK + i] = fi * (lm - __logf(fmaxf(s, 1e-35f)));
    }
  }
}

// ---------------- MFMA finalize (linear): A-frag = W * vtilde; B = Vxt ----------------
// u-factor cancels in row normalization, so only vtilde = exp(logv) is needed.
// D[row][0..31]=O_unnorm, [32..34]=x_cent_unnorm, [35]=rowsum
__global__ __launch_bounds__(256) void finalize_mfma(const unsigned short* __restrict__ Wm,
                                                     const float* __restrict__ logv,
                                                     const unsigned short* __restrict__ Vxt,
                                                     const float* __restrict__ G0, int ld,
                                                     const float* __restrict__ xres,
                                                     const float* __restrict__ mask,
                                                     unsigned short* __restrict__ o,
                                                     float* __restrict__ x_out,
                                                     const float* __restrict__ gamma) {
  int mt = blockIdx.x;           // 16 m-tiles of 64 rows
  int h = blockIdx.y;
  int t = threadIdx.x, wave = t >> 6, lane = t & 63;
  int lm = lane & 15, quad = lane >> 4;
  __shared__ float vts[N_TOK];
  {
    float4 lv = ((const float4*)(logv + h * N_TOK))[t];
    float4 ev;
    ev.x = __expf(lv.x); ev.y = __expf(lv.y);
    ev.z = __expf(lv.z); ev.w = __expf(lv.w);
    ((float4*)vts)[t] = ev;
  }
  __syncthreads();
  int arow = mt * 64 + wave * 16 + lm;        // A-operand row for this lane
  const unsigned short* Kr = Wm + ((size_t)h * N_TOK + arow) * N_TOK + quad * 8;
  const unsigned short* Bb = Vxt + (size_t)h * 48 * N_TOK + quad * 8;
  f32x4_t zero = {0.f, 0.f, 0.f, 0.f};
  f32x4_t acc[3] = {zero, zero, zero};
  for (int kk = 0; kk < N_TOK; kk += 32) {
    uint4 u = *(const uint4*)(Kr + kk);
    float4 la = *(const float4*)&vts[kk + quad * 8];
    float4 lb = *(const float4*)&vts[kk + quad * 8 + 4];
    float p0 = bf_lo(u.x) * la.x;
    float p1 = bf_hi(u.x) * la.y;
    float p2 = bf_lo(u.y) * la.z;
    float p3 = bf_hi(u.y) * la.w;
    float p4 = bf_lo(u.z) * lb.x;
    float p5 = bf_hi(u.z) * lb.y;
    float p6 = bf_lo(u.w) * lb.z;
    float p7 = bf_hi(u.w) * lb.w;
    union { uint4 u4; short8 s8; } pk;
    pk.u4 = make_uint4(((unsigned)f2bf(p1) << 16) | f2bf(p0),
                       ((unsigned)f2bf(p3) << 16) | f2bf(p2),
                       ((unsigned)f2bf(p5) << 16) | f2bf(p4),
                       ((unsigned)f2bf(p7) << 16) | f2bf(p6));
    short8 af = pk.s8;
    #pragma unroll
    for (int nt = 0; nt < 3; ++nt) {
      short8 bfrag = *(const short8*)(Bb + (size_t)(nt * 16 + lm) * N_TOK + kk);
      acc[nt] = __builtin_amdgcn_mfma_f32_16x16x32_bf16(af, bfrag, acc[nt], 0, 0, 0);
    }
  }
  // epilogue: C-layout row = quad*4+reg, col = nt*16+lm; rowsum at col 35 (nt=2, lm=3)
  float inv[4];
  #pragma unroll
  for (int reg = 0; reg < 4; ++reg) {
    float rsum = __shfl(acc[2][reg], (quad << 4) | 3, 64);
    inv[reg] = 1.f / fmaxf(rsum, 1e-30f);
  }
  #pragma unroll
  for (int nt = 0; nt < 2; ++nt) {
    int c = nt * 16 + lm;
    #pragma unroll
    for (int reg = 0; reg < 4; ++reg) {
      int r = mt * 64 + wave * 16 + quad * 4 + reg;
      float gv = G0[(size_t)r * ld + h * DHEAD + c];
      float ovl = acc[nt][reg] * inv[reg] * sigmoidf_(gv);
      o[(size_t)r * D_MODEL + h * DHEAD + c] = f2bf(ovl);
    }
  }
  if (lm < 3) {
    float tg = tanhf(gamma[h]) * (1.f / H_HEADS);
    #pragma unroll
    for (int reg = 0; reg < 4; ++reg) {
      int r = mt * 64 + wave * 16 + quad * 4 + reg;
      float xc = acc[2][reg] * inv[reg];
      float mi = mask[r];
      atomicAdd(&x_out[r * 3 + lm], tg * mi * (xres[r * 3 + lm] - xc));
    }
  }
}

// ---------------- silu+mul from fused ffab (1024x4096) -> bf16 (1024x2048) ----------------
__global__ __launch_bounds__(256) void silu_mul_bf(const float* __restrict__ ffab,
                                                   unsigned short* __restrict__ out, int n) {
  int i = blockIdx.x * 256 + threadIdx.x;
  if (i >= n) return;
  int row = i >> 11, col = i & 2047;
  float a = ffab[(size_t)row * 4096 + col];
  float bb = ffab[(size_t)row * 4096 + 2048 + col];
  out[i] = f2bf(a * sigmoidf_(a) * bb);
}

__global__ __launch_bounds__(256) void copyf(const float* __restrict__ src,
                                             float* __restrict__ dst, int n) {
  int i = blockIdx.x * 256 + threadIdx.x;
  if (i < n) dst[i] = src[i];
}

extern "C" void kernel_launch(void* const* d_in, const int* in_sizes, int n_in,
                              void* d_out, int out_size, void* d_ws, size_t ws_size,
                              hipStream_t stream) {
  const float* h_in  = (const float*)d_in[0];
  const float* x_res = (const float*)d_in[1];
  const float* mu    = (const float*)d_in[2];
  const float* nu    = (const float*)d_in[3];
  const float* lu0   = (const float*)d_in[4];
  const float* lv0   = (const float*)d_in[5];
  const float* mask  = (const float*)d_in[6];
  const float* lnw   = (const float*)d_in[7];
  const float* lnb   = (const float*)d_in[8];
  const float* wq    = (const float*)d_in[9];
  const float* wk    = (const float*)d_in[10];
  const float* wv    = (const float*)d_in[11];
  const float* wg    = (const float*)d_in[12];
  const float* wo    = (const float*)d_in[13];
  const float* gamma = (const float*)d_in[14];
  const float* posw  = (const float*)d_in[15];
  const float* wdl   = (const float*)d_in[16];
  const float* lnfw  = (const float*)d_in[17];
  const float* lnfb  = (const float*)d_in[18];
  const float* w1    = (const float*)d_in[19];
  const float* w3    = (const float*)d_in[20];
  const float* w2    = (const float*)d_in[21];
  const int*   bins  = (const int*)d_in[22];
  const float* eps   = (const float*)d_in[23];

  float* out    = (float*)d_out;
  float* out_h  = out;                     // 1024*512
  float* out_x  = out + 524288;            // 1024*3
  float* out_lu = out + 527360;            // 16*1024
  float* out_lv = out + 543744;            // 16*1024

  float* ws = (float*)d_ws;
  float* QKVG  = ws;                       // 1024 x 2048 (Q|K|V|G)
  float* h_mid = ws + 2097152;             // 1024 x 512
  unsigned short* U = (unsigned short*)(ws + 2621440);
  unsigned short* h_n_b  = U;              // 1024x512
  unsigned short* h2_b   = U + 524288;     // 1024x512
  unsigned short* o_b    = U + 1048576;    // 1024x512
  unsigned short* wB     = U + 1572864;    // 4456448 bf16 weights
  unsigned short* Wb   = (unsigned short*)(ws + 5636096);  // H*N*N bf16 (exp domain)
  unsigned short* WTb  = Wb + (size_t)H_HEADS * N_TOK * N_TOK;
  unsigned short* Vxt  = WTb + (size_t)H_HEADS * N_TOK * N_TOK; // 16*48*1024 bf16
  float* ffab          = (float*)Wb;        // reuse after finalize
  unsigned short* ff_b = WTb;

  unsigned short* wQKVGb = wB;                 // 2048 x 512
  unsigned short* wob    = wB + 1048576;       // 512 x 512
  unsigned short* wFFb   = wB + 1310720;       // 4096 x 512
  unsigned short* w2b    = wB + 3407872;       // 512 x 2048

  dim3 b256(256);

  conv_weights<<<4352, b256, 0, stream>>>(wq, wk, wv, wg, wo, w1, w3, w2, wB);
  ln_rows<<<N_TOK, b256, 0, stream>>>(h_in, lnw, lnb, h_n_b);

  gemm_mfma<<<dim3(16, 8), b256, 0, stream>>>(h_n_b, wQKVGb, QKVG,
                                              N_TOK, D_MODEL, 2048, nullptr, nullptr);

  headln<<<128, b256, 0, stream>>>(QKVG, 2048);

  copyf<<<64, b256, 0, stream>>>(lu0, out_lu, H_HEADS * N_TOK);
  copyf<<<64, b256, 0, stream>>>(lv0, out_lv, H_HEADS * N_TOK);
  copyf<<<12, b256, 0, stream>>>(x_res, out_x, N_TOK * 3);

  build_W<<<dim3(N_TOK / 32, N_TOK / 32, H_HEADS), b256, 0, stream>>>(
      QKVG, QKVG + 512, 2048, x_res, bins, posw, wdl, eps, mask, Wb, WTb);
  build_vxt<<<dim3(H_HEADS, N_TOK / 64), b256, 0, stream>>>(QKVG, x_res, Vxt);

  for (int it = 0; it < 20; ++it) {
    sink_lin<<<H_HEADS * N_TOK / 16, b256, 0, stream>>>(Wb, out_lv, mu, out_lu, eps);
    sink_lin<<<H_HEADS * N_TOK / 16, b256, 0, stream>>>(WTb, out_lu, nu, out_lv, eps);
  }

  finalize_mfma<<<dim3(16, H_HEADS), b256, 0, stream>>>(
      Wb, out_lv, Vxt, QKVG + 1536, 2048, x_res, mask, o_b, out_x, gamma);

  gemm_mfma64<<<dim3(8, 16), b256, 0, stream>>>(o_b, wob, h_mid,
                                                N_TOK, D_MODEL, D_MODEL, h_in, mask);

  ln_rows<<<N_TOK, b256, 0, stream>>>(h_mid, lnfw, lnfb, h2_b);

  gemm_mfma<<<dim3(32, 8), b256, 0, stream>>>(h2_b, wFFb, ffab,
                                              N_TOK, D_MODEL, 4096, nullptr, nullptr);
  silu_mul_bf<<<(N_TOK * DFF) / 256, b256, 0, stream>>>(ffab, ff_b, N_TOK * DFF);

  gemm_mfma64<<<dim3(8, 16), b256, 0, stream>>>(ff_b, w2b, out_h,
                                                N_TOK, DFF, D_MODEL, h_mid, mask);
}

// Round 7
// 540.540 us; speedup vs baseline: 5.2543x; 1.1422x over previous
//
#include <hip/hip_runtime.h>
#include <cstddef>
#include <cstdint>

#define N_TOK 1024
#define D_MODEL 512
#define H_HEADS 16
#define DHEAD 32
#define DFF 2048

typedef __attribute__((ext_vector_type(8))) short short8;
typedef __attribute__((ext_vector_type(4))) float f32x4_t;

__device__ __forceinline__ float sigmoidf_(float x){ return 1.f/(1.f+__expf(-x)); }

__device__ __forceinline__ unsigned short f2bf(float f){
  union { float f; unsigned u; } v; v.f = f;
  unsigned r = (v.u + 0x7FFFu + ((v.u >> 16) & 1u)) >> 16;
  return (unsigned short)r;
}
__device__ __forceinline__ float bf_lo(unsigned u){ return __uint_as_float(u << 16); }
__device__ __forceinline__ float bf_hi(unsigned u){ return __uint_as_float(u & 0xFFFF0000u); }

// ---------------- LayerNorm over rows -> bf16 out ----------------
__global__ __launch_bounds__(256) void ln_rows(const float* __restrict__ x,
                                               const float* __restrict__ w,
                                               const float* __restrict__ b,
                                               unsigned short* __restrict__ y) {
  int row = blockIdx.x;
  const float* xr = x + (size_t)row * D_MODEL;
  float s = 0.f, s2 = 0.f;
  for (int i = threadIdx.x; i < D_MODEL; i += 256) { float v = xr[i]; s += v; s2 += v*v; }
  #pragma unroll
  for (int off = 32; off; off >>= 1) { s += __shfl_down(s, off); s2 += __shfl_down(s2, off); }
  __shared__ float rs[4], rs2[4];
  int wave = threadIdx.x >> 6, lane = threadIdx.x & 63;
  if (lane == 0) { rs[wave] = s; rs2[wave] = s2; }
  __syncthreads();
  s  = rs[0] + rs[1] + rs[2] + rs[3];
  s2 = rs2[0] + rs2[1] + rs2[2] + rs2[3];
  float mean = s * (1.f / D_MODEL);
  float var  = s2 * (1.f / D_MODEL) - mean * mean;
  float r = rsqrtf(var + 1e-5f);
  unsigned short* yr = y + (size_t)row * D_MODEL;
  for (int i = threadIdx.x; i < D_MODEL; i += 256)
    yr[i] = f2bf((xr[i] - mean) * r * w[i] + b[i]);
}

// ---------------- weight conversion fp32 -> bf16 ----------------
__global__ __launch_bounds__(256) void conv_weights(const float* __restrict__ wq,
                                                    const float* __restrict__ wk,
                                                    const float* __restrict__ wv,
                                                    const float* __restrict__ wg,
                                                    const float* __restrict__ wo,
                                                    const float* __restrict__ w1,
                                                    const float* __restrict__ w3,
                                                    const float* __restrict__ w2,
                                                    unsigned short* __restrict__ dst) {
  size_t i = ((size_t)blockIdx.x * 256 + threadIdx.x) * 4;
  const float* src; size_t off;
  if      (i < 262144)  { src = wq; off = i; }
  else if (i < 524288)  { src = wk; off = i - 262144; }
  else if (i < 786432)  { src = wv; off = i - 524288; }
  else if (i < 1048576) { src = wg; off = i - 786432; }
  else if (i < 1310720) { src = wo; off = i - 1048576; }
  else if (i < 2359296) { src = w1; off = i - 1310720; }
  else if (i < 3407872) { src = w3; off = i - 2359296; }
  else                  { src = w2; off = i - 3407872; }
  float4 v = *(const float4*)&src[off];
  unsigned lo = ((unsigned)f2bf(v.y) << 16) | f2bf(v.x);
  unsigned hi = ((unsigned)f2bf(v.w) << 16) | f2bf(v.z);
  *(uint2*)&dst[i] = make_uint2(lo, hi);
}

// ---------------- bf16 MFMA GEMM 128x128: C = A @ B^T ----------------
__global__ __launch_bounds__(256) void gemm_mfma(const unsigned short* __restrict__ A,
                                                 const unsigned short* __restrict__ B,
                                                 float* __restrict__ C,
                                                 int M, int K, int Nout,
                                                 const float* __restrict__ addmat,
                                                 const float* __restrict__ maskrow) {
  __shared__ unsigned short As[128][40];
  __shared__ unsigned short Bs[128][40];
  int t = threadIdx.x;
  int m0 = blockIdx.y * 128, n0 = blockIdx.x * 128;
  int wave = t >> 6, lane = t & 63;
  int wm = (wave >> 1) * 64, wn = (wave & 1) * 64;
  int lm = lane & 15, quad = lane >> 4;
  f32x4_t zero = {0.f, 0.f, 0.f, 0.f};
  f32x4_t acc[4][4];
  #pragma unroll
  for (int i = 0; i < 4; ++i)
    #pragma unroll
    for (int j = 0; j < 4; ++j) acc[i][j] = zero;

  int sr = t >> 2, sc = (t & 3) * 8;
  for (int kk = 0; kk < K; kk += 32) {
    #pragma unroll
    for (int c = 0; c < 2; ++c) {
      int r = sr + c * 64;
      *(uint4*)&As[r][sc] = *(const uint4*)&A[(size_t)(m0 + r) * K + kk + sc];
      *(uint4*)&Bs[r][sc] = *(const uint4*)&B[(size_t)(n0 + r) * K + kk + sc];
    }
    __syncthreads();
    short8 af[4], bfr[4];
    #pragma unroll
    for (int mt = 0; mt < 4; ++mt)
      af[mt] = *(const short8*)&As[wm + mt * 16 + lm][quad * 8];
    #pragma unroll
    for (int nt = 0; nt < 4; ++nt)
      bfr[nt] = *(const short8*)&Bs[wn + nt * 16 + lm][quad * 8];
    #pragma unroll
    for (int mt = 0; mt < 4; ++mt)
      #pragma unroll
      for (int nt = 0; nt < 4; ++nt)
        acc[mt][nt] = __builtin_amdgcn_mfma_f32_16x16x32_bf16(af[mt], bfr[nt], acc[mt][nt], 0, 0, 0);
    __syncthreads();
  }
  #pragma unroll
  for (int mt = 0; mt < 4; ++mt) {
    #pragma unroll
    for (int reg = 0; reg < 4; ++reg) {
      int gm = m0 + wm + mt * 16 + quad * 4 + reg;
      float mk = maskrow ? maskrow[gm] : 0.f;
      #pragma unroll
      for (int nt = 0; nt < 4; ++nt) {
        int gn = n0 + wn + nt * 16 + lm;
        float v = acc[mt][nt][reg];
        if (addmat) v = addmat[(size_t)gm * Nout + gn] + v * mk;
        C[(size_t)gm * Nout + gn] = v;
      }
    }
  }
}

// ---------------- bf16 MFMA GEMM 64x64 ----------------
__global__ __launch_bounds__(256) void gemm_mfma64(const unsigned short* __restrict__ A,
                                                   const unsigned short* __restrict__ B,
                                                   float* __restrict__ C,
                                                   int M, int K, int Nout,
                                                   const float* __restrict__ addmat,
                                                   const float* __restrict__ maskrow) {
  __shared__ unsigned short As[64][40];
  __shared__ unsigned short Bs[64][40];
  int t = threadIdx.x;
  int m0 = blockIdx.y * 64, n0 = blockIdx.x * 64;
  int wave = t >> 6, lane = t & 63;
  int wm = (wave >> 1) * 32, wn = (wave & 1) * 32;
  int lm = lane & 15, quad = lane >> 4;
  f32x4_t zero = {0.f, 0.f, 0.f, 0.f};
  f32x4_t acc[2][2];
  #pragma unroll
  for (int i = 0; i < 2; ++i)
    #pragma unroll
    for (int j = 0; j < 2; ++j) acc[i][j] = zero;

  int sr = t >> 2, sc = (t & 3) * 8;
  for (int kk = 0; kk < K; kk += 32) {
    *(uint4*)&As[sr][sc] = *(const uint4*)&A[(size_t)(m0 + sr) * K + kk + sc];
    *(uint4*)&Bs[sr][sc] = *(const uint4*)&B[(size_t)(n0 + sr) * K + kk + sc];
    __syncthreads();
    short8 af[2], bfr[2];
    #pragma unroll
    for (int mt = 0; mt < 2; ++mt)
      af[mt] = *(const short8*)&As[wm + mt * 16 + lm][quad * 8];
    #pragma unroll
    for (int nt = 0; nt < 2; ++nt)
      bfr[nt] = *(const short8*)&Bs[wn + nt * 16 + lm][quad * 8];
    #pragma unroll
    for (int mt = 0; mt < 2; ++mt)
      #pragma unroll
      for (int nt = 0; nt < 2; ++nt)
        acc[mt][nt] = __builtin_amdgcn_mfma_f32_16x16x32_bf16(af[mt], bfr[nt], acc[mt][nt], 0, 0, 0);
    __syncthreads();
  }
  #pragma unroll
  for (int mt = 0; mt < 2; ++mt) {
    #pragma unroll
    for (int reg = 0; reg < 4; ++reg) {
      int gm = m0 + wm + mt * 16 + quad * 4 + reg;
      float mk = maskrow ? maskrow[gm] : 0.f;
      #pragma unroll
      for (int nt = 0; nt < 2; ++nt) {
        int gn = n0 + wn + nt * 16 + lm;
        float v = acc[mt][nt][reg];
        if (addmat) v = addmat[(size_t)gm * Nout + gn] + v * mk;
        C[(size_t)gm * Nout + gn] = v;
      }
    }
  }
}

// ---------------- per-head LN (no affine), Q and K regions of QKVG (ld=2048) ----------------
__global__ __launch_bounds__(256) void headln(float* __restrict__ base, int ld) {
  int g = blockIdx.x * 256 + threadIdx.x;
  int i = g & (N_TOK - 1), hh = g >> 10;    // hh 0..31
  float* p = base + (size_t)i * ld + hh * DHEAD;
  float s = 0.f, s2 = 0.f;
  #pragma unroll
  for (int k = 0; k < DHEAD; ++k) { float v = p[k]; s += v; s2 += v*v; }
  float m = s * (1.f / DHEAD);
  float var = s2 * (1.f / DHEAD) - m * m;
  float r = rsqrtf(var + 1e-5f);
  #pragma unroll
  for (int k = 0; k < DHEAD; ++k) p[k] = (p[k] - m) * r;
}

// ---------------- build W = exp(logK) via MFMA QK^T; 64x64 tile per block ----------------
__global__ __launch_bounds__(256) void build_W_mfma(const float* __restrict__ Q0,
                                                    const float* __restrict__ K0,
                                                    int ld,
                                                    const float* __restrict__ xres,
                                                    const int* __restrict__ bins,
                                                    const float* __restrict__ posw,
                                                    const float* __restrict__ wdl,
                                                    const float* __restrict__ epsp,
                                                    const float* __restrict__ mask,
                                                    unsigned short* __restrict__ Wm,
                                                    unsigned short* __restrict__ WmT) {
  int h = blockIdx.z;
  int i0 = blockIdx.y * 64, j0 = blockIdx.x * 64;
  __shared__ unsigned short Qs[64][40];    // 80B stride: 16B-aligned, 2-way banks (free)
  __shared__ unsigned short Ks[64][40];
  __shared__ int   binsS[64][65];
  __shared__ float tileS[64][65];
  __shared__ float xi0[64], xi1[64], xi2[64], xj0[64], xj1[64], xj2[64];
  __shared__ float mi_s[64], mj_s[64], poswS[68];
  int t = threadIdx.x;
  // stage Q,K rows as bf16 (64 rows x 32 k each)
  {
    int r = t >> 2, c8 = (t & 3) * 8;
    const float* qsrc = Q0 + (size_t)(i0 + r) * ld + h * DHEAD + c8;
    const float* ksrc = K0 + (size_t)(j0 + r) * ld + h * DHEAD + c8;
    float4 qa = *(const float4*)qsrc, qb = *(const float4*)(qsrc + 4);
    float4 ka = *(const float4*)ksrc, kb = *(const float4*)(ksrc + 4);
    unsigned short* qd = &Qs[r][c8];
    qd[0]=f2bf(qa.x); qd[1]=f2bf(qa.y); qd[2]=f2bf(qa.z); qd[3]=f2bf(qa.w);
    qd[4]=f2bf(qb.x); qd[5]=f2bf(qb.y); qd[6]=f2bf(qb.z); qd[7]=f2bf(qb.w);
    unsigned short* kd = &Ks[r][c8];
    kd[0]=f2bf(ka.x); kd[1]=f2bf(ka.y); kd[2]=f2bf(ka.z); kd[3]=f2bf(ka.w);
    kd[4]=f2bf(kb.x); kd[5]=f2bf(kb.y); kd[6]=f2bf(kb.z); kd[7]=f2bf(kb.w);
  }
  // stage bins tile (coalesced)
  {
    int rb = t >> 2, cb = (t & 3) * 16;
    const int* bsrc = bins + (size_t)(i0 + rb) * N_TOK + j0 + cb;
    #pragma unroll
    for (int c = 0; c < 4; ++c) {
      int4 b4 = *(const int4*)(bsrc + c * 4);
      binsS[rb][cb + c*4 + 0] = b4.x; binsS[rb][cb + c*4 + 1] = b4.y;
      binsS[rb][cb + c*4 + 2] = b4.z; binsS[rb][cb + c*4 + 3] = b4.w;
    }
  }
  if (t < 64) {
    xi0[t] = xres[(i0 + t) * 3 + 0]; xi1[t] = xres[(i0 + t) * 3 + 1]; xi2[t] = xres[(i0 + t) * 3 + 2];
    xj0[t] = xres[(j0 + t) * 3 + 0]; xj1[t] = xres[(j0 + t) * 3 + 1]; xj2[t] = xres[(j0 + t) * 3 + 2];
    mi_s[t] = mask[i0 + t]; mj_s[t] = mask[j0 + t];
  }
  if (t >= 64 && t < 132) poswS[t - 64] = posw[(t - 64) * H_HEADS + h];
  __syncthreads();
  int wave = t >> 6, lane = t & 63;
  int lm = lane & 15, quad = lane >> 4;
  int wm = (wave >> 1) * 32, wn = (wave & 1) * 32;
  f32x4_t zero = {0.f, 0.f, 0.f, 0.f};
  f32x4_t acc[2][2] = {{zero, zero}, {zero, zero}};
  short8 af[2], bfr[2];
  #pragma unroll
  for (int mt = 0; mt < 2; ++mt) af[mt] = *(const short8*)&Qs[wm + mt * 16 + lm][quad * 8];
  #pragma unroll
  for (int nt = 0; nt < 2; ++nt) bfr[nt] = *(const short8*)&Ks[wn + nt * 16 + lm][quad * 8];
  #pragma unroll
  for (int mt = 0; mt < 2; ++mt)
    #pragma unroll
    for (int nt = 0; nt < 2; ++nt)
      acc[mt][nt] = __builtin_amdgcn_mfma_f32_16x16x32_bf16(af[mt], bfr[nt], acc[mt][nt], 0, 0, 0);
  float wd = sigmoidf_(wdl[h]);
  float inv_eps = 1.f / epsp[h];
  const float inv_sqrt = 0.17677669529663687f; // 1/sqrt(32)
  #pragma unroll
  for (int mt = 0; mt < 2; ++mt) {
    #pragma unroll
    for (int nt = 0; nt < 2; ++nt) {
      int col = wn + nt * 16 + lm;
      float xj0v = xj0[col], xj1v = xj1[col], xj2v = xj2[col], mj = mj_s[col];
      #pragma unroll
      for (int reg = 0; reg < 4; ++reg) {
        int row = wm + mt * 16 + quad * 4 + reg;
        float d0 = xi0[row] - xj0v, d1 = xi1[row] - xj1v, d2c = xi2[row] - xj2v;
        float d2 = d0*d0 + d1*d1 + d2c*d2c;
        float bias = poswS[binsS[row][col]];
        float logit = acc[mt][nt][reg] * inv_sqrt + bias - wd * d2 * 0.01f;
        float outv = (mi_s[row] * mj > 0.f) ? __expf(logit * inv_eps) : 0.f;
        tileS[row][col] = outv;
      }
    }
  }
  __syncthreads();
  // dual writes: row-major and transposed, vectorized bf16x8
  {
    int r = t >> 2, cb = (t & 3) * 16;
    unsigned short* dst = Wm + ((size_t)h * N_TOK + (i0 + r)) * N_TOK + j0 + cb;
    #pragma unroll
    for (int half = 0; half < 2; ++half) {
      float* s = &tileS[r][cb + half * 8];
      unsigned a0 = ((unsigned)f2bf(s[1]) << 16) | f2bf(s[0]);
      unsigned a1 = ((unsigned)f2bf(s[3]) << 16) | f2bf(s[2]);
      unsigned a2 = ((unsigned)f2bf(s[5]) << 16) | f2bf(s[4]);
      unsigned a3 = ((unsigned)f2bf(s[7]) << 16) | f2bf(s[6]);
      *(uint4*)(dst + half * 8) = make_uint4(a0, a1, a2, a3);
    }
  }
  {
    int jt = t >> 2, cb = (t & 3) * 16;
    unsigned short* dst = WmT + ((size_t)h * N_TOK + (j0 + jt)) * N_TOK + i0 + cb;
    #pragma unroll
    for (int half = 0; half < 2; ++half) {
      int ib = cb + half * 8;
      unsigned a0 = ((unsigned)f2bf(tileS[ib+1][jt]) << 16) | f2bf(tileS[ib+0][jt]);
      unsigned a1 = ((unsigned)f2bf(tileS[ib+3][jt]) << 16) | f2bf(tileS[ib+2][jt]);
      unsigned a2 = ((unsigned)f2bf(tileS[ib+5][jt]) << 16) | f2bf(tileS[ib+4][jt]);
      unsigned a3 = ((unsigned)f2bf(tileS[ib+7][jt]) << 16) | f2bf(tileS[ib+6][jt]);
      *(uint4*)(dst + half * 8) = make_uint4(a0, a1, a2, a3);
    }
  }
}

// ---------------- build VxT: Vxt[h][48][1024] bf16 = [V^T ; x^T ; ones ; pad] ----------------
__global__ __launch_bounds__(256) void build_vxt(const float* __restrict__ QKVG_,
                                                 const float* __restrict__ xres,
                                                 unsigned short* __restrict__ Vxt) {
  int h = blockIdx.x, j0 = blockIdx.y * 64;
  __shared__ float T[48][72];
  int t = threadIdx.x;
  {
    int j = t >> 2, c8 = (t & 3) * 8;
    const float* src = QKVG_ + (size_t)(j0 + j) * 2048 + 1024 + h * DHEAD + c8;
    float4 a = *(const float4*)src, b = *(const float4*)(src + 4);
    T[c8 + 0][j] = a.x; T[c8 + 1][j] = a.y; T[c8 + 2][j] = a.z; T[c8 + 3][j] = a.w;
    T[c8 + 4][j] = b.x; T[c8 + 5][j] = b.y; T[c8 + 6][j] = b.z; T[c8 + 7][j] = b.w;
  }
  if (t < 64) {
    int j = t;
    T[32][j] = xres[(j0 + j) * 3 + 0];
    T[33][j] = xres[(j0 + j) * 3 + 1];
    T[34][j] = xres[(j0 + j) * 3 + 2];
    T[35][j] = 1.f;
    #pragma unroll
    for (int d = 36; d < 48; ++d) T[d][j] = 0.f;
  }
  __syncthreads();
  for (int task = t; task < 384; task += 256) {
    int d = task >> 3, jc = (task & 7) * 8;
    float* s = &T[d][jc];
    unsigned a0 = ((unsigned)f2bf(s[1]) << 16) | f2bf(s[0]);
    unsigned a1 = ((unsigned)f2bf(s[3]) << 16) | f2bf(s[2]);
    unsigned a2 = ((unsigned)f2bf(s[5]) << 16) | f2bf(s[4]);
    unsigned a3 = ((unsigned)f2bf(s[7]) << 16) | f2bf(s[6]);
    *(uint4*)(Vxt + ((size_t)h * 48 + d) * N_TOK + j0 + jc) = make_uint4(a0, a1, a2, a3);
  }
}

// ---------------- linear Sinkhorn pass: 16 rows/block, 16 lanes per row ----------------
// out[h,i] = fi_h * (log(max(marg,1e-8)) - log(Sum_j W[h,i,j] * exp(other[h,j])))
__global__ __launch_bounds__(256) void sink_lin(const unsigned short* __restrict__ Wsrc,
                                                const float* __restrict__ otherlog,
                                                const float* __restrict__ marg,
                                                float* __restrict__ outlog,
                                                const float* __restrict__ epsp) {
  __shared__ float vt[N_TOK];
  int t = threadIdx.x;
  int rblk = blockIdx.x * 16;               // 1024 blocks x 16 rows
  int h = rblk >> 10;
  {
    float4 lv = ((const float4*)(otherlog + h * N_TOK))[t];
    float4 ev;
    ev.x = __expf(lv.x); ev.y = __expf(lv.y);
    ev.z = __expf(lv.z); ev.w = __expf(lv.w);
    ((float4*)vt)[t] = ev;
  }
  __syncthreads();
  int wave = t >> 6, lane = t & 63;
  int sub = lane >> 4, l16 = lane & 15;     // 4 rows per wave, 16 lanes per row
  int row = rblk + wave * 4 + sub;
  int i = row & (N_TOK - 1);
  const uint4* p = (const uint4*)(Wsrc + (size_t)row * N_TOK);
  float s8[8];
  #pragma unroll
  for (int c = 0; c < 8; ++c) s8[c] = 0.f;
  #pragma unroll
  for (int it = 0; it < 8; ++it) {          // 8 independent 16B loads per lane
    int j0 = it * 128 + l16 * 8;
    uint4 u = p[j0 >> 3];
    float4 va = ((const float4*)vt)[j0 >> 2];
    float4 vb = ((const float4*)vt)[(j0 >> 2) + 1];
    s8[0] += bf_lo(u.x) * va.x; s8[1] += bf_hi(u.x) * va.y;
    s8[2] += bf_lo(u.y) * va.z; s8[3] += bf_hi(u.y) * va.w;
    s8[4] += bf_lo(u.z) * vb.x; s8[5] += bf_hi(u.z) * vb.y;
    s8[6] += bf_lo(u.w) * vb.z; s8[7] += bf_hi(u.w) * vb.w;
  }
  float s = ((s8[0] + s8[1]) + (s8[2] + s8[3])) + ((s8[4] + s8[5]) + (s8[6] + s8[7]));
  #pragma unroll
  for (int off = 1; off <= 8; off <<= 1) s += __shfl_xor(s, off);
  if (l16 == 0) {
    float fi = 1.f / (1.f + epsp[h]);        // LAM=1
    float lm = __logf(fmaxf(marg[h * N_TOK + i], 1e-8f));
    outlog[h * N_TOK + i] = fi * (lm - __logf(fmaxf(s, 1e-35f)));
  }
}

// ---------------- MFMA finalize (linear): A-frag = W * vtilde; B = Vxt ----------------
__global__ __launch_bounds__(256) void finalize_mfma(const unsigned short* __restrict__ Wm,
                                                     const float* __restrict__ logv,
                                                     const unsigned short* __restrict__ Vxt,
                                                     const float* __restrict__ G0, int ld,
                                                     const float* __restrict__ xres,
                                                     const float* __restrict__ mask,
                                                     unsigned short* __restrict__ o,
                                                     float* __restrict__ x_out,
                                                     const float* __restrict__ gamma) {
  int mt = blockIdx.x;           // 16 m-tiles of 64 rows
  int h = blockIdx.y;
  int t = threadIdx.x, wave = t >> 6, lane = t & 63;
  int lm = lane & 15, quad = lane >> 4;
  __shared__ float vts[N_TOK];
  {
    float4 lv = ((const float4*)(logv + h * N_TOK))[t];
    float4 ev;
    ev.x = __expf(lv.x); ev.y = __expf(lv.y);
    ev.z = __expf(lv.z); ev.w = __expf(lv.w);
    ((float4*)vts)[t] = ev;
  }
  __syncthreads();
  int arow = mt * 64 + wave * 16 + lm;
  const unsigned short* Kr = Wm + ((size_t)h * N_TOK + arow) * N_TOK + quad * 8;
  const unsigned short* Bb = Vxt + (size_t)h * 48 * N_TOK + quad * 8;
  f32x4_t zero = {0.f, 0.f, 0.f, 0.f};
  f32x4_t acc[3] = {zero, zero, zero};
  for (int kk = 0; kk < N_TOK; kk += 32) {
    uint4 u = *(const uint4*)(Kr + kk);
    float4 la = *(const float4*)&vts[kk + quad * 8];
    float4 lb = *(const float4*)&vts[kk + quad * 8 + 4];
    float p0 = bf_lo(u.x) * la.x;
    float p1 = bf_hi(u.x) * la.y;
    float p2 = bf_lo(u.y) * la.z;
    float p3 = bf_hi(u.y) * la.w;
    float p4 = bf_lo(u.z) * lb.x;
    float p5 = bf_hi(u.z) * lb.y;
    float p6 = bf_lo(u.w) * lb.z;
    float p7 = bf_hi(u.w) * lb.w;
    union { uint4 u4; short8 s8; } pk;
    pk.u4 = make_uint4(((unsigned)f2bf(p1) << 16) | f2bf(p0),
                       ((unsigned)f2bf(p3) << 16) | f2bf(p2),
                       ((unsigned)f2bf(p5) << 16) | f2bf(p4),
                       ((unsigned)f2bf(p7) << 16) | f2bf(p6));
    short8 af = pk.s8;
    #pragma unroll
    for (int nt = 0; nt < 3; ++nt) {
      short8 bfrag = *(const short8*)(Bb + (size_t)(nt * 16 + lm) * N_TOK + kk);
      acc[nt] = __builtin_amdgcn_mfma_f32_16x16x32_bf16(af, bfrag, acc[nt], 0, 0, 0);
    }
  }
  float inv[4];
  #pragma unroll
  for (int reg = 0; reg < 4; ++reg) {
    float rsum = __shfl(acc[2][reg], (quad << 4) | 3, 64);
    inv[reg] = 1.f / fmaxf(rsum, 1e-30f);
  }
  #pragma unroll
  for (int nt = 0; nt < 2; ++nt) {
    int c = nt * 16 + lm;
    #pragma unroll
    for (int reg = 0; reg < 4; ++reg) {
      int r = mt * 64 + wave * 16 + quad * 4 + reg;
      float gv = G0[(size_t)r * ld + h * DHEAD + c];
      float ovl = acc[nt][reg] * inv[reg] * sigmoidf_(gv);
      o[(size_t)r * D_MODEL + h * DHEAD + c] = f2bf(ovl);
    }
  }
  if (lm < 3) {
    float tg = tanhf(gamma[h]) * (1.f / H_HEADS);
    #pragma unroll
    for (int reg = 0; reg < 4; ++reg) {
      int r = mt * 64 + wave * 16 + quad * 4 + reg;
      float xc = acc[2][reg] * inv[reg];
      float mi = mask[r];
      atomicAdd(&x_out[r * 3 + lm], tg * mi * (xres[r * 3 + lm] - xc));
    }
  }
}

// ---------------- silu+mul from fused ffab (1024x4096) -> bf16 (1024x2048) ----------------
__global__ __launch_bounds__(256) void silu_mul_bf(const float* __restrict__ ffab,
                                                   unsigned short* __restrict__ out, int n) {
  int i = blockIdx.x * 256 + threadIdx.x;
  if (i >= n) return;
  int row = i >> 11, col = i & 2047;
  float a = ffab[(size_t)row * 4096 + col];
  float bb = ffab[(size_t)row * 4096 + 2048 + col];
  out[i] = f2bf(a * sigmoidf_(a) * bb);
}

__global__ __launch_bounds__(256) void copyf(const float* __restrict__ src,
                                             float* __restrict__ dst, int n) {
  int i = blockIdx.x * 256 + threadIdx.x;
  if (i < n) dst[i] = src[i];
}

extern "C" void kernel_launch(void* const* d_in, const int* in_sizes, int n_in,
                              void* d_out, int out_size, void* d_ws, size_t ws_size,
                              hipStream_t stream) {
  const float* h_in  = (const float*)d_in[0];
  const float* x_res = (const float*)d_in[1];
  const float* mu    = (const float*)d_in[2];
  const float* nu    = (const float*)d_in[3];
  const float* lu0   = (const float*)d_in[4];
  const float* lv0   = (const float*)d_in[5];
  const float* mask  = (const float*)d_in[6];
  const float* lnw   = (const float*)d_in[7];
  const float* lnb   = (const float*)d_in[8];
  const float* wq    = (const float*)d_in[9];
  const float* wk    = (const float*)d_in[10];
  const float* wv    = (const float*)d_in[11];
  const float* wg    = (const float*)d_in[12];
  const float* wo    = (const float*)d_in[13];
  const float* gamma = (const float*)d_in[14];
  const float* posw  = (const float*)d_in[15];
  const float* wdl   = (const float*)d_in[16];
  const float* lnfw  = (const float*)d_in[17];
  const float* lnfb  = (const float*)d_in[18];
  const float* w1    = (const float*)d_in[19];
  const float* w3    = (const float*)d_in[20];
  const float* w2    = (const float*)d_in[21];
  const int*   bins  = (const int*)d_in[22];
  const float* eps   = (const float*)d_in[23];

  float* out    = (float*)d_out;
  float* out_h  = out;                     // 1024*512
  float* out_x  = out + 524288;            // 1024*3
  float* out_lu = out + 527360;            // 16*1024
  float* out_lv = out + 543744;            // 16*1024

  float* ws = (float*)d_ws;
  float* QKVG  = ws;                       // 1024 x 2048 (Q|K|V|G)
  float* h_mid = ws + 2097152;             // 1024 x 512
  unsigned short* U = (unsigned short*)(ws + 2621440);
  unsigned short* h_n_b  = U;              // 1024x512
  unsigned short* h2_b   = U + 524288;     // 1024x512
  unsigned short* o_b    = U + 1048576;    // 1024x512
  unsigned short* wB     = U + 1572864;    // 4456448 bf16 weights
  unsigned short* Wb   = (unsigned short*)(ws + 5636096);  // H*N*N bf16 (exp domain)
  unsigned short* WTb  = Wb + (size_t)H_HEADS * N_TOK * N_TOK;
  unsigned short* Vxt  = WTb + (size_t)H_HEADS * N_TOK * N_TOK; // 16*48*1024 bf16
  float* ffab          = (float*)Wb;        // reuse after finalize
  unsigned short* ff_b = WTb;

  unsigned short* wQKVGb = wB;                 // 2048 x 512
  unsigned short* wob    = wB + 1048576;       // 512 x 512
  unsigned short* wFFb   = wB + 1310720;       // 4096 x 512
  unsigned short* w2b    = wB + 3407872;       // 512 x 2048

  dim3 b256(256);

  conv_weights<<<4352, b256, 0, stream>>>(wq, wk, wv, wg, wo, w1, w3, w2, wB);
  ln_rows<<<N_TOK, b256, 0, stream>>>(h_in, lnw, lnb, h_n_b);

  gemm_mfma<<<dim3(16, 8), b256, 0, stream>>>(h_n_b, wQKVGb, QKVG,
                                              N_TOK, D_MODEL, 2048, nullptr, nullptr);

  headln<<<128, b256, 0, stream>>>(QKVG, 2048);

  copyf<<<64, b256, 0, stream>>>(lu0, out_lu, H_HEADS * N_TOK);
  copyf<<<64, b256, 0, stream>>>(lv0, out_lv, H_HEADS * N_TOK);
  copyf<<<12, b256, 0, stream>>>(x_res, out_x, N_TOK * 3);

  build_W_mfma<<<dim3(16, 16, H_HEADS), b256, 0, stream>>>(
      QKVG, QKVG + 512, 2048, x_res, bins, posw, wdl, eps, mask, Wb, WTb);
  build_vxt<<<dim3(H_HEADS, N_TOK / 64), b256, 0, stream>>>(QKVG, x_res, Vxt);

  for (int it = 0; it < 20; ++it) {
    sink_lin<<<H_HEADS * N_TOK / 16, b256, 0, stream>>>(Wb, out_lv, mu, out_lu, eps);
    sink_lin<<<H_HEADS * N_TOK / 16, b256, 0, stream>>>(WTb, out_lu, nu, out_lv, eps);
  }

  finalize_mfma<<<dim3(16, H_HEADS), b256, 0, stream>>>(
      Wb, out_lv, Vxt, QKVG + 1536, 2048, x_res, mask, o_b, out_x, gamma);

  gemm_mfma64<<<dim3(8, 16), b256, 0, stream>>>(o_b, wob, h_mid,
                                                N_TOK, D_MODEL, D_MODEL, h_in, mask);

  ln_rows<<<N_TOK, b256, 0, stream>>>(h_mid, lnfw, lnfb, h2_b);

  gemm_mfma<<<dim3(32, 8), b256, 0, stream>>>(h2_b, wFFb, ffab,
                                              N_TOK, D_MODEL, 4096, nullptr, nullptr);
  silu_mul_bf<<<(N_TOK * DFF) / 256, b256, 0, stream>>>(ffab, ff_b, N_TOK * DFF);

  gemm_mfma64<<<dim3(8, 16), b256, 0, stream>>>(ff_b, w2b, out_h,
                                                N_TOK, DFF, D_MODEL, h_mid, mask);
}

// Round 8
// 526.545 us; speedup vs baseline: 5.3939x; 1.0266x over previous
//
#include <hip/hip_runtime.h>
#include <cstddef>
#include <cstdint>

#define N_TOK 1024
#define D_MODEL 512
#define H_HEADS 16
#define DHEAD 32
#define DFF 2048

typedef __attribute__((ext_vector_type(8))) short short8;
typedef __attribute__((ext_vector_type(4))) float f32x4_t;

__device__ __forceinline__ float sigmoidf_(float x){ return 1.f/(1.f+__expf(-x)); }

__device__ __forceinline__ unsigned short f2bf(float f){
  union { float f; unsigned u; } v; v.f = f;
  unsigned r = (v.u + 0x7FFFu + ((v.u >> 16) & 1u)) >> 16;
  return (unsigned short)r;
}
__device__ __forceinline__ float bf_lo(unsigned u){ return __uint_as_float(u << 16); }
__device__ __forceinline__ float bf_hi(unsigned u){ return __uint_as_float(u & 0xFFFF0000u); }

// ---------------- LayerNorm over rows -> bf16 out ----------------
__global__ __launch_bounds__(256) void ln_rows(const float* __restrict__ x,
                                               const float* __restrict__ w,
                                               const float* __restrict__ b,
                                               unsigned short* __restrict__ y) {
  int row = blockIdx.x;
  const float* xr = x + (size_t)row * D_MODEL;
  float s = 0.f, s2 = 0.f;
  for (int i = threadIdx.x; i < D_MODEL; i += 256) { float v = xr[i]; s += v; s2 += v*v; }
  #pragma unroll
  for (int off = 32; off; off >>= 1) { s += __shfl_down(s, off); s2 += __shfl_down(s2, off); }
  __shared__ float rs[4], rs2[4];
  int wave = threadIdx.x >> 6, lane = threadIdx.x & 63;
  if (lane == 0) { rs[wave] = s; rs2[wave] = s2; }
  __syncthreads();
  s  = rs[0] + rs[1] + rs[2] + rs[3];
  s2 = rs2[0] + rs2[1] + rs2[2] + rs2[3];
  float mean = s * (1.f / D_MODEL);
  float var  = s2 * (1.f / D_MODEL) - mean * mean;
  float r = rsqrtf(var + 1e-5f);
  unsigned short* yr = y + (size_t)row * D_MODEL;
  for (int i = threadIdx.x; i < D_MODEL; i += 256)
    yr[i] = f2bf((xr[i] - mean) * r * w[i] + b[i]);
}

// ---------------- weight conversion fp32 -> bf16 ----------------
__global__ __launch_bounds__(256) void conv_weights(const float* __restrict__ wq,
                                                    const float* __restrict__ wk,
                                                    const float* __restrict__ wv,
                                                    const float* __restrict__ wg,
                                                    const float* __restrict__ wo,
                                                    const float* __restrict__ w1,
                                                    const float* __restrict__ w3,
                                                    const float* __restrict__ w2,
                                                    unsigned short* __restrict__ dst) {
  size_t i = ((size_t)blockIdx.x * 256 + threadIdx.x) * 4;
  const float* src; size_t off;
  if      (i < 262144)  { src = wq; off = i; }
  else if (i < 524288)  { src = wk; off = i - 262144; }
  else if (i < 786432)  { src = wv; off = i - 524288; }
  else if (i < 1048576) { src = wg; off = i - 786432; }
  else if (i < 1310720) { src = wo; off = i - 1048576; }
  else if (i < 2359296) { src = w1; off = i - 1310720; }
  else if (i < 3407872) { src = w3; off = i - 2359296; }
  else                  { src = w2; off = i - 3407872; }
  float4 v = *(const float4*)&src[off];
  unsigned lo = ((unsigned)f2bf(v.y) << 16) | f2bf(v.x);
  unsigned hi = ((unsigned)f2bf(v.w) << 16) | f2bf(v.z);
  *(uint2*)&dst[i] = make_uint2(lo, hi);
}

// ---------------- bf16 MFMA GEMM 128x128: C = A @ B^T ----------------
__global__ __launch_bounds__(256) void gemm_mfma(const unsigned short* __restrict__ A,
                                                 const unsigned short* __restrict__ B,
                                                 float* __restrict__ C,
                                                 int M, int K, int Nout,
                                                 const float* __restrict__ addmat,
                                                 const float* __restrict__ maskrow) {
  __shared__ unsigned short As[128][40];
  __shared__ unsigned short Bs[128][40];
  int t = threadIdx.x;
  int m0 = blockIdx.y * 128, n0 = blockIdx.x * 128;
  int wave = t >> 6, lane = t & 63;
  int wm = (wave >> 1) * 64, wn = (wave & 1) * 64;
  int lm = lane & 15, quad = lane >> 4;
  f32x4_t zero = {0.f, 0.f, 0.f, 0.f};
  f32x4_t acc[4][4];
  #pragma unroll
  for (int i = 0; i < 4; ++i)
    #pragma unroll
    for (int j = 0; j < 4; ++j) acc[i][j] = zero;

  int sr = t >> 2, sc = (t & 3) * 8;
  for (int kk = 0; kk < K; kk += 32) {
    #pragma unroll
    for (int c = 0; c < 2; ++c) {
      int r = sr + c * 64;
      *(uint4*)&As[r][sc] = *(const uint4*)&A[(size_t)(m0 + r) * K + kk + sc];
      *(uint4*)&Bs[r][sc] = *(const uint4*)&B[(size_t)(n0 + r) * K + kk + sc];
    }
    __syncthreads();
    short8 af[4], bfr[4];
    #pragma unroll
    for (int mt = 0; mt < 4; ++mt)
      af[mt] = *(const short8*)&As[wm + mt * 16 + lm][quad * 8];
    #pragma unroll
    for (int nt = 0; nt < 4; ++nt)
      bfr[nt] = *(const short8*)&Bs[wn + nt * 16 + lm][quad * 8];
    #pragma unroll
    for (int mt = 0; mt < 4; ++mt)
      #pragma unroll
      for (int nt = 0; nt < 4; ++nt)
        acc[mt][nt] = __builtin_amdgcn_mfma_f32_16x16x32_bf16(af[mt], bfr[nt], acc[mt][nt], 0, 0, 0);
    __syncthreads();
  }
  #pragma unroll
  for (int mt = 0; mt < 4; ++mt) {
    #pragma unroll
    for (int reg = 0; reg < 4; ++reg) {
      int gm = m0 + wm + mt * 16 + quad * 4 + reg;
      float mk = maskrow ? maskrow[gm] : 0.f;
      #pragma unroll
      for (int nt = 0; nt < 4; ++nt) {
        int gn = n0 + wn + nt * 16 + lm;
        float v = acc[mt][nt][reg];
        if (addmat) v = addmat[(size_t)gm * Nout + gn] + v * mk;
        C[(size_t)gm * Nout + gn] = v;
      }
    }
  }
}

// ---------------- bf16 MFMA GEMM 64x64 ----------------
__global__ __launch_bounds__(256) void gemm_mfma64(const unsigned short* __restrict__ A,
                                                   const unsigned short* __restrict__ B,
                                                   float* __restrict__ C,
                                                   int M, int K, int Nout,
                                                   const float* __restrict__ addmat,
                                                   const float* __restrict__ maskrow) {
  __shared__ unsigned short As[64][40];
  __shared__ unsigned short Bs[64][40];
  int t = threadIdx.x;
  int m0 = blockIdx.y * 64, n0 = blockIdx.x * 64;
  int wave = t >> 6, lane = t & 63;
  int wm = (wave >> 1) * 32, wn = (wave & 1) * 32;
  int lm = lane & 15, quad = lane >> 4;
  f32x4_t zero = {0.f, 0.f, 0.f, 0.f};
  f32x4_t acc[2][2];
  #pragma unroll
  for (int i = 0; i < 2; ++i)
    #pragma unroll
    for (int j = 0; j < 2; ++j) acc[i][j] = zero;

  int sr = t >> 2, sc = (t & 3) * 8;
  for (int kk = 0; kk < K; kk += 32) {
    *(uint4*)&As[sr][sc] = *(const uint4*)&A[(size_t)(m0 + sr) * K + kk + sc];
    *(uint4*)&Bs[sr][sc] = *(const uint4*)&B[(size_t)(n0 + sr) * K + kk + sc];
    __syncthreads();
    short8 af[2], bfr[2];
    #pragma unroll
    for (int mt = 0; mt < 2; ++mt)
      af[mt] = *(const short8*)&As[wm + mt * 16 + lm][quad * 8];
    #pragma unroll
    for (int nt = 0; nt < 2; ++nt)
      bfr[nt] = *(const short8*)&Bs[wn + nt * 16 + lm][quad * 8];
    #pragma unroll
    for (int mt = 0; mt < 2; ++mt)
      #pragma unroll
      for (int nt = 0; nt < 2; ++nt)
        acc[mt][nt] = __builtin_amdgcn_mfma_f32_16x16x32_bf16(af[mt], bfr[nt], acc[mt][nt], 0, 0, 0);
    __syncthreads();
  }
  #pragma unroll
  for (int mt = 0; mt < 2; ++mt) {
    #pragma unroll
    for (int reg = 0; reg < 4; ++reg) {
      int gm = m0 + wm + mt * 16 + quad * 4 + reg;
      float mk = maskrow ? maskrow[gm] : 0.f;
      #pragma unroll
      for (int nt = 0; nt < 2; ++nt) {
        int gn = n0 + wn + nt * 16 + lm;
        float v = acc[mt][nt][reg];
        if (addmat) v = addmat[(size_t)gm * Nout + gn] + v * mk;
        C[(size_t)gm * Nout + gn] = v;
      }
    }
  }
}

// ---------------- per-head LN (no affine), Q and K regions of QKVG (ld=2048) ----------------
__global__ __launch_bounds__(256) void headln(float* __restrict__ base, int ld) {
  int g = blockIdx.x * 256 + threadIdx.x;
  int i = g & (N_TOK - 1), hh = g >> 10;    // hh 0..31
  float* p = base + (size_t)i * ld + hh * DHEAD;
  float s = 0.f, s2 = 0.f;
  #pragma unroll
  for (int k = 0; k < DHEAD; ++k) { float v = p[k]; s += v; s2 += v*v; }
  float m = s * (1.f / DHEAD);
  float var = s2 * (1.f / DHEAD) - m * m;
  float r = rsqrtf(var + 1e-5f);
  #pragma unroll
  for (int k = 0; k < DHEAD; ++k) p[k] = (p[k] - m) * r;
}

// ---------------- build W = exp(logK) via MFMA QK^T; 64x64 tile; slim LDS ----------------
__global__ __launch_bounds__(256) void build_W_mfma(const float* __restrict__ Q0,
                                                    const float* __restrict__ K0,
                                                    int ld,
                                                    const float* __restrict__ xres,
                                                    const int* __restrict__ bins,
                                                    const float* __restrict__ posw,
                                                    const float* __restrict__ wdl,
                                                    const float* __restrict__ epsp,
                                                    const float* __restrict__ mask,
                                                    unsigned short* __restrict__ Wm,
                                                    unsigned short* __restrict__ WmT) {
  int h = blockIdx.z;
  int i0 = blockIdx.y * 64, j0 = blockIdx.x * 64;
  __shared__ unsigned short Qs[64][40];
  __shared__ unsigned short Ks[64][40];
  __shared__ unsigned char  binsU[64][68];
  __shared__ unsigned short tileB[64][68];   // result in packed bf16
  __shared__ float xi0[64], xi1[64], xi2[64], xj0[64], xj1[64], xj2[64];
  __shared__ float mi_s[64], mj_s[64], poswS[68];
  int t = threadIdx.x;
  // stage Q,K rows as bf16
  {
    int r = t >> 2, c8 = (t & 3) * 8;
    const float* qsrc = Q0 + (size_t)(i0 + r) * ld + h * DHEAD + c8;
    const float* ksrc = K0 + (size_t)(j0 + r) * ld + h * DHEAD + c8;
    float4 qa = *(const float4*)qsrc, qb = *(const float4*)(qsrc + 4);
    float4 ka = *(const float4*)ksrc, kb = *(const float4*)(ksrc + 4);
    unsigned short* qd = &Qs[r][c8];
    qd[0]=f2bf(qa.x); qd[1]=f2bf(qa.y); qd[2]=f2bf(qa.z); qd[3]=f2bf(qa.w);
    qd[4]=f2bf(qb.x); qd[5]=f2bf(qb.y); qd[6]=f2bf(qb.z); qd[7]=f2bf(qb.w);
    unsigned short* kd = &Ks[r][c8];
    kd[0]=f2bf(ka.x); kd[1]=f2bf(ka.y); kd[2]=f2bf(ka.z); kd[3]=f2bf(ka.w);
    kd[4]=f2bf(kb.x); kd[5]=f2bf(kb.y); kd[6]=f2bf(kb.z); kd[7]=f2bf(kb.w);
  }
  // stage bins tile as uchar (NBINS=68 < 256)
  {
    int rb = t >> 2, cb = (t & 3) * 16;
    const int* bsrc = bins + (size_t)(i0 + rb) * N_TOK + j0 + cb;
    #pragma unroll
    for (int c = 0; c < 4; ++c) {
      int4 b4 = *(const int4*)(bsrc + c * 4);
      uchar4 u4 = make_uchar4((unsigned char)b4.x, (unsigned char)b4.y,
                              (unsigned char)b4.z, (unsigned char)b4.w);
      *(uchar4*)&binsU[rb][cb + c * 4] = u4;
    }
  }
  if (t < 64) {
    xi0[t] = xres[(i0 + t) * 3 + 0]; xi1[t] = xres[(i0 + t) * 3 + 1]; xi2[t] = xres[(i0 + t) * 3 + 2];
    xj0[t] = xres[(j0 + t) * 3 + 0]; xj1[t] = xres[(j0 + t) * 3 + 1]; xj2[t] = xres[(j0 + t) * 3 + 2];
    mi_s[t] = mask[i0 + t]; mj_s[t] = mask[j0 + t];
  }
  if (t >= 64 && t < 132) poswS[t - 64] = posw[(t - 64) * H_HEADS + h];
  __syncthreads();
  int wave = t >> 6, lane = t & 63;
  int lm = lane & 15, quad = lane >> 4;
  int wm = (wave >> 1) * 32, wn = (wave & 1) * 32;
  f32x4_t zero = {0.f, 0.f, 0.f, 0.f};
  f32x4_t acc[2][2] = {{zero, zero}, {zero, zero}};
  short8 af[2], bfr[2];
  #pragma unroll
  for (int mt = 0; mt < 2; ++mt) af[mt] = *(const short8*)&Qs[wm + mt * 16 + lm][quad * 8];
  #pragma unroll
  for (int nt = 0; nt < 2; ++nt) bfr[nt] = *(const short8*)&Ks[wn + nt * 16 + lm][quad * 8];
  #pragma unroll
  for (int mt = 0; mt < 2; ++mt)
    #pragma unroll
    for (int nt = 0; nt < 2; ++nt)
      acc[mt][nt] = __builtin_amdgcn_mfma_f32_16x16x32_bf16(af[mt], bfr[nt], acc[mt][nt], 0, 0, 0);
  float wd = sigmoidf_(wdl[h]);
  float inv_eps = 1.f / epsp[h];
  const float inv_sqrt = 0.17677669529663687f; // 1/sqrt(32)
  #pragma unroll
  for (int mt = 0; mt < 2; ++mt) {
    #pragma unroll
    for (int nt = 0; nt < 2; ++nt) {
      int col = wn + nt * 16 + lm;
      float xj0v = xj0[col], xj1v = xj1[col], xj2v = xj2[col], mj = mj_s[col];
      #pragma unroll
      for (int reg = 0; reg < 4; ++reg) {
        int row = wm + mt * 16 + quad * 4 + reg;
        float d0 = xi0[row] - xj0v, d1 = xi1[row] - xj1v, d2c = xi2[row] - xj2v;
        float d2 = d0*d0 + d1*d1 + d2c*d2c;
        float bias = poswS[binsU[row][col]];
        float logit = acc[mt][nt][reg] * inv_sqrt + bias - wd * d2 * 0.01f;
        float outv = (mi_s[row] * mj > 0.f) ? __expf(logit * inv_eps) : 0.f;
        tileB[row][col] = f2bf(outv);
      }
    }
  }
  __syncthreads();
  // row-major write: straight copy of 16 packed bf16 per thread
  {
    int r = t >> 2, cb = (t & 3) * 16;
    unsigned short* dst = Wm + ((size_t)h * N_TOK + (i0 + r)) * N_TOK + j0 + cb;
    uint4 w0 = *(uint4*)&tileB[r][cb];
    uint4 w1v = *(uint4*)&tileB[r][cb + 8];
    *(uint4*)dst = w0;
    *(uint4*)(dst + 8) = w1v;
  }
  // transposed write: gather 16 rows at col jt
  {
    int jt = t >> 2, cb = (t & 3) * 16;
    unsigned short* dst = WmT + ((size_t)h * N_TOK + (j0 + jt)) * N_TOK + i0 + cb;
    #pragma unroll
    for (int half = 0; half < 2; ++half) {
      int ib = cb + half * 8;
      unsigned a0 = ((unsigned)tileB[ib+1][jt] << 16) | tileB[ib+0][jt];
      unsigned a1 = ((unsigned)tileB[ib+3][jt] << 16) | tileB[ib+2][jt];
      unsigned a2 = ((unsigned)tileB[ib+5][jt] << 16) | tileB[ib+4][jt];
      unsigned a3 = ((unsigned)tileB[ib+7][jt] << 16) | tileB[ib+6][jt];
      *(uint4*)(dst + half * 8) = make_uint4(a0, a1, a2, a3);
    }
  }
}

// ---------------- build VxT: Vxt[h][48][1024] bf16 = [V^T ; x^T ; ones ; pad] ----------------
__global__ __launch_bounds__(256) void build_vxt(const float* __restrict__ QKVG_,
                                                 const float* __restrict__ xres,
                                                 unsigned short* __restrict__ Vxt) {
  int h = blockIdx.x, j0 = blockIdx.y * 64;
  __shared__ float T[48][72];
  int t = threadIdx.x;
  {
    int j = t >> 2, c8 = (t & 3) * 8;
    const float* src = QKVG_ + (size_t)(j0 + j) * 2048 + 1024 + h * DHEAD + c8;
    float4 a = *(const float4*)src, b = *(const float4*)(src + 4);
    T[c8 + 0][j] = a.x; T[c8 + 1][j] = a.y; T[c8 + 2][j] = a.z; T[c8 + 3][j] = a.w;
    T[c8 + 4][j] = b.x; T[c8 + 5][j] = b.y; T[c8 + 6][j] = b.z; T[c8 + 7][j] = b.w;
  }
  if (t < 64) {
    int j = t;
    T[32][j] = xres[(j0 + j) * 3 + 0];
    T[33][j] = xres[(j0 + j) * 3 + 1];
    T[34][j] = xres[(j0 + j) * 3 + 2];
    T[35][j] = 1.f;
    #pragma unroll
    for (int d = 36; d < 48; ++d) T[d][j] = 0.f;
  }
  __syncthreads();
  for (int task = t; task < 384; task += 256) {
    int d = task >> 3, jc = (task & 7) * 8;
    float* s = &T[d][jc];
    unsigned a0 = ((unsigned)f2bf(s[1]) << 16) | f2bf(s[0]);
    unsigned a1 = ((unsigned)f2bf(s[3]) << 16) | f2bf(s[2]);
    unsigned a2 = ((unsigned)f2bf(s[5]) << 16) | f2bf(s[4]);
    unsigned a3 = ((unsigned)f2bf(s[7]) << 16) | f2bf(s[6]);
    *(uint4*)(Vxt + ((size_t)h * 48 + d) * N_TOK + j0 + jc) = make_uint4(a0, a1, a2, a3);
  }
}

// ---------------- Sinkhorn init: log-marginals + exp warm-start ----------------
__global__ __launch_bounds__(256) void sink_init(const float* __restrict__ mu,
                                                 const float* __restrict__ nu,
                                                 const float* __restrict__ lv0,
                                                 float* __restrict__ lmu,
                                                 float* __restrict__ lnu,
                                                 float* __restrict__ vtilde) {
  int i = blockIdx.x * 256 + threadIdx.x;   // 16384
  lmu[i] = __logf(fmaxf(mu[i], 1e-8f));
  lnu[i] = __logf(fmaxf(nu[i], 1e-8f));
  vtilde[i] = __expf(lv0[i]);
}

// ---------------- linear Sinkhorn pass: no LDS, no barrier; writes log + exp ----------------
// s = Sum_j W[h,i,j]*othert[h,j]; out = fi*(lmarg - log s); outexp = exp(out)
__global__ __launch_bounds__(256) void sink_lin(const unsigned short* __restrict__ Wsrc,
                                                const float* __restrict__ othert,
                                                const float* __restrict__ lmarg,
                                                float* __restrict__ outlog,
                                                float* __restrict__ outexp,
                                                const float* __restrict__ epsp) {
  int t = threadIdx.x;
  int rblk = blockIdx.x * 16;               // 1024 blocks x 16 rows
  int h = rblk >> 10;
  int wave = t >> 6, lane = t & 63;
  int sub = lane >> 4, l16 = lane & 15;     // 4 rows per wave, 16 lanes per row
  int row = rblk + wave * 4 + sub;
  int i = row & (N_TOK - 1);
  const uint4* p = (const uint4*)(Wsrc + (size_t)row * N_TOK);
  const float4* vt = (const float4*)(othert + h * N_TOK);
  float s8[8];
  #pragma unroll
  for (int c = 0; c < 8; ++c) s8[c] = 0.f;
  #pragma unroll
  for (int it = 0; it < 8; ++it) {          // 8 independent 16B W loads per lane
    int j0 = it * 128 + l16 * 8;
    uint4 u = p[j0 >> 3];
    float4 va = vt[j0 >> 2];
    float4 vb = vt[(j0 >> 2) + 1];
    s8[0] += bf_lo(u.x) * va.x; s8[1] += bf_hi(u.x) * va.y;
    s8[2] += bf_lo(u.y) * va.z; s8[3] += bf_hi(u.y) * va.w;
    s8[4] += bf_lo(u.z) * vb.x; s8[5] += bf_hi(u.z) * vb.y;
    s8[6] += bf_lo(u.w) * vb.z; s8[7] += bf_hi(u.w) * vb.w;
  }
  float s = ((s8[0] + s8[1]) + (s8[2] + s8[3])) + ((s8[4] + s8[5]) + (s8[6] + s8[7]));
  #pragma unroll
  for (int off = 1; off <= 8; off <<= 1) s += __shfl_xor(s, off);
  if (l16 == 0) {
    float fi = 1.f / (1.f + epsp[h]);        // LAM=1
    float val = fi * (lmarg[h * N_TOK + i] - __logf(fmaxf(s, 1e-35f)));
    outlog[h * N_TOK + i] = val;
    outexp[h * N_TOK + i] = __expf(val);
  }
}

// ---------------- MFMA finalize (linear): A-frag = W * vtilde; B = Vxt ----------------
__global__ __launch_bounds__(256) void finalize_mfma(const unsigned short* __restrict__ Wm,
                                                     const float* __restrict__ vtilde,
                                                     const unsigned short* __restrict__ Vxt,
                                                     const float* __restrict__ G0, int ld,
                                                     const float* __restrict__ xres,
                                                     const float* __restrict__ mask,
                                                     unsigned short* __restrict__ o,
                                                     float* __restrict__ x_out,
                                                     const float* __restrict__ gamma) {
  int mt = blockIdx.x;           // 16 m-tiles of 64 rows
  int h = blockIdx.y;
  int t = threadIdx.x, wave = t >> 6, lane = t & 63;
  int lm = lane & 15, quad = lane >> 4;
  __shared__ float vts[N_TOK];
  ((float4*)vts)[t] = ((const float4*)(vtilde + h * N_TOK))[t];
  __syncthreads();
  int arow = mt * 64 + wave * 16 + lm;
  const unsigned short* Kr = Wm + ((size_t)h * N_TOK + arow) * N_TOK + quad * 8;
  const unsigned short* Bb = Vxt + (size_t)h * 48 * N_TOK + quad * 8;
  f32x4_t zero = {0.f, 0.f, 0.f, 0.f};
  f32x4_t acc[3] = {zero, zero, zero};
  for (int kk = 0; kk < N_TOK; kk += 32) {
    uint4 u = *(const uint4*)(Kr + kk);
    float4 la = *(const float4*)&vts[kk + quad * 8];
    float4 lb = *(const float4*)&vts[kk + quad * 8 + 4];
    float p0 = bf_lo(u.x) * la.x;
    float p1 = bf_hi(u.x) * la.y;
    float p2 = bf_lo(u.y) * la.z;
    float p3 = bf_hi(u.y) * la.w;
    float p4 = bf_lo(u.z) * lb.x;
    float p5 = bf_hi(u.z) * lb.y;
    float p6 = bf_lo(u.w) * lb.z;
    float p7 = bf_hi(u.w) * lb.w;
    union { uint4 u4; short8 s8; } pk;
    pk.u4 = make_uint4(((unsigned)f2bf(p1) << 16) | f2bf(p0),
                       ((unsigned)f2bf(p3) << 16) | f2bf(p2),
                       ((unsigned)f2bf(p5) << 16) | f2bf(p4),
                       ((unsigned)f2bf(p7) << 16) | f2bf(p6));
    short8 af = pk.s8;
    #pragma unroll
    for (int nt = 0; nt < 3; ++nt) {
      short8 bfrag = *(const short8*)(Bb + (size_t)(nt * 16 + lm) * N_TOK + kk);
      acc[nt] = __builtin_amdgcn_mfma_f32_16x16x32_bf16(af, bfrag, acc[nt], 0, 0, 0);
    }
  }
  float inv[4];
  #pragma unroll
  for (int reg = 0; reg < 4; ++reg) {
    float rsum = __shfl(acc[2][reg], (quad << 4) | 3, 64);
    inv[reg] = 1.f / fmaxf(rsum, 1e-30f);
  }
  #pragma unroll
  for (int nt = 0; nt < 2; ++nt) {
    int c = nt * 16 + lm;
    #pragma unroll
    for (int reg = 0; reg < 4; ++reg) {
      int r = mt * 64 + wave * 16 + quad * 4 + reg;
      float gv = G0[(size_t)r * ld + h * DHEAD + c];
      float ovl = acc[nt][reg] * inv[reg] * sigmoidf_(gv);
      o[(size_t)r * D_MODEL + h * DHEAD + c] = f2bf(ovl);
    }
  }
  if (lm < 3) {
    float tg = tanhf(gamma[h]) * (1.f / H_HEADS);
    #pragma unroll
    for (int reg = 0; reg < 4; ++reg) {
      int r = mt * 64 + wave * 16 + quad * 4 + reg;
      float xc = acc[2][reg] * inv[reg];
      float mi = mask[r];
      atomicAdd(&x_out[r * 3 + lm], tg * mi * (xres[r * 3 + lm] - xc));
    }
  }
}

// ---------------- silu+mul from fused ffab (1024x4096) -> bf16 (1024x2048) ----------------
__global__ __launch_bounds__(256) void silu_mul_bf(const float* __restrict__ ffab,
                                                   unsigned short* __restrict__ out, int n) {
  int i = blockIdx.x * 256 + threadIdx.x;
  if (i >= n) return;
  int row = i >> 11, col = i & 2047;
  float a = ffab[(size_t)row * 4096 + col];
  float bb = ffab[(size_t)row * 4096 + 2048 + col];
  out[i] = f2bf(a * sigmoidf_(a) * bb);
}

__global__ __launch_bounds__(256) void copyf(const float* __restrict__ src,
                                             float* __restrict__ dst, int n) {
  int i = blockIdx.x * 256 + threadIdx.x;
  if (i < n) dst[i] = src[i];
}

extern "C" void kernel_launch(void* const* d_in, const int* in_sizes, int n_in,
                              void* d_out, int out_size, void* d_ws, size_t ws_size,
                              hipStream_t stream) {
  const float* h_in  = (const float*)d_in[0];
  const float* x_res = (const float*)d_in[1];
  const float* mu    = (const float*)d_in[2];
  const float* nu    = (const float*)d_in[3];
  const float* lu0   = (const float*)d_in[4];
  const float* lv0   = (const float*)d_in[5];
  const float* mask  = (const float*)d_in[6];
  const float* lnw   = (const float*)d_in[7];
  const float* lnb   = (const float*)d_in[8];
  const float* wq    = (const float*)d_in[9];
  const float* wk    = (const float*)d_in[10];
  const float* wv    = (const float*)d_in[11];
  const float* wg    = (const float*)d_in[12];
  const float* wo    = (const float*)d_in[13];
  const float* gamma = (const float*)d_in[14];
  const float* posw  = (const float*)d_in[15];
  const float* wdl   = (const float*)d_in[16];
  const float* lnfw  = (const float*)d_in[17];
  const float* lnfb  = (const float*)d_in[18];
  const float* w1    = (const float*)d_in[19];
  const float* w3    = (const float*)d_in[20];
  const float* w2    = (const float*)d_in[21];
  const int*   bins  = (const int*)d_in[22];
  const float* eps   = (const float*)d_in[23];

  float* out    = (float*)d_out;
  float* out_h  = out;                     // 1024*512
  float* out_x  = out + 524288;            // 1024*3
  float* out_lu = out + 527360;            // 16*1024
  float* out_lv = out + 543744;            // 16*1024

  float* ws = (float*)d_ws;
  float* QKVG  = ws;                       // 1024 x 2048 (Q|K|V|G)
  float* h_mid = ws + 2097152;             // 1024 x 512
  unsigned short* U = (unsigned short*)(ws + 2621440);
  unsigned short* h_n_b  = U;              // 1024x512
  unsigned short* h2_b   = U + 524288;     // 1024x512
  unsigned short* o_b    = U + 1048576;    // 1024x512
  unsigned short* wB     = U + 1572864;    // 4456448 bf16 weights
  unsigned short* Wb   = (unsigned short*)(ws + 5636096);  // H*N*N bf16 (exp domain)
  unsigned short* WTb  = Wb + (size_t)H_HEADS * N_TOK * N_TOK;
  unsigned short* Vxt  = WTb + (size_t)H_HEADS * N_TOK * N_TOK; // 16*48*1024 bf16
  float* vtilde = (float*)(Vxt + 786432);   // 16384 floats
  float* utilde = vtilde + 16384;
  float* lmu    = utilde + 16384;
  float* lnu    = lmu + 16384;
  float* ffab          = (float*)Wb;        // reuse after finalize
  unsigned short* ff_b = WTb;

  unsigned short* wQKVGb = wB;                 // 2048 x 512
  unsigned short* wob    = wB + 1048576;       // 512 x 512
  unsigned short* wFFb   = wB + 1310720;       // 4096 x 512
  unsigned short* w2b    = wB + 3407872;       // 512 x 2048

  dim3 b256(256);

  conv_weights<<<4352, b256, 0, stream>>>(wq, wk, wv, wg, wo, w1, w3, w2, wB);
  ln_rows<<<N_TOK, b256, 0, stream>>>(h_in, lnw, lnb, h_n_b);

  gemm_mfma<<<dim3(16, 8), b256, 0, stream>>>(h_n_b, wQKVGb, QKVG,
                                              N_TOK, D_MODEL, 2048, nullptr, nullptr);

  headln<<<128, b256, 0, stream>>>(QKVG, 2048);

  copyf<<<12, b256, 0, stream>>>(x_res, out_x, N_TOK * 3);

  build_W_mfma<<<dim3(16, 16, H_HEADS), b256, 0, stream>>>(
      QKVG, QKVG + 512, 2048, x_res, bins, posw, wdl, eps, mask, Wb, WTb);
  build_vxt<<<dim3(H_HEADS, N_TOK / 64), b256, 0, stream>>>(QKVG, x_res, Vxt);

  sink_init<<<64, b256, 0, stream>>>(mu, nu, lv0, lmu, lnu, vtilde);
  for (int it = 0; it < 20; ++it) {
    sink_lin<<<1024, b256, 0, stream>>>(Wb, vtilde, lmu, out_lu, utilde, eps);
    sink_lin<<<1024, b256, 0, stream>>>(WTb, utilde, lnu, out_lv, vtilde, eps);
  }

  finalize_mfma<<<dim3(16, H_HEADS), b256, 0, stream>>>(
      Wb, vtilde, Vxt, QKVG + 1536, 2048, x_res, mask, o_b, out_x, gamma);

  gemm_mfma64<<<dim3(8, 16), b256, 0, stream>>>(o_b, wob, h_mid,
                                                N_TOK, D_MODEL, D_MODEL, h_in, mask);

  ln_rows<<<N_TOK, b256, 0, stream>>>(h_mid, lnfw, lnfb, h2_b);

  gemm_mfma<<<dim3(32, 8), b256, 0, stream>>>(h2_b, wFFb, ffab,
                                              N_TOK, D_MODEL, 4096, nullptr, nullptr);
  silu_mul_bf<<<(N_TOK * DFF) / 256, b256, 0, stream>>>(ffab, ff_b, N_TOK * DFF);

  gemm_mfma64<<<dim3(8, 16), b256, 0, stream>>>(ff_b, w2b, out_h,
                                                N_TOK, DFF, D_MODEL, h_mid, mask);
}

// Round 9
// 449.347 us; speedup vs baseline: 6.3206x; 1.1718x over previous
//
#include <hip/hip_runtime.h>
#include <cstddef>
#include <cstdint>

#define N_TOK 1024
#define D_MODEL 512
#define H_HEADS 16
#define DHEAD 32
#define DFF 2048

typedef __attribute__((ext_vector_type(8))) short short8;
typedef __attribute__((ext_vector_type(4))) float f32x4_t;

__device__ __forceinline__ float sigmoidf_(float x){ return 1.f/(1.f+__expf(-x)); }

__device__ __forceinline__ unsigned short f2bf(float f){
  union { float f; unsigned u; } v; v.f = f;
  unsigned r = (v.u + 0x7FFFu + ((v.u >> 16) & 1u)) >> 16;
  return (unsigned short)r;
}
__device__ __forceinline__ float bf_lo(unsigned u){ return __uint_as_float(u << 16); }
__device__ __forceinline__ float bf_hi(unsigned u){ return __uint_as_float(u & 0xFFFF0000u); }

// XCD-pinning swizzle: blocks b with b%8 == x land on XCD x (round-robin dispatch
// heuristic). head h = (b&7) + 8*((b>>3)&1) keeps each head's W tile on one XCD.
__device__ __forceinline__ int swz_head(int b){ return (b & 7) + 8 * ((b >> 3) & 1); }

// ---------------- LayerNorm over rows -> bf16 out ----------------
__global__ __launch_bounds__(256) void ln_rows(const float* __restrict__ x,
                                               const float* __restrict__ w,
                                               const float* __restrict__ b,
                                               unsigned short* __restrict__ y) {
  int row = blockIdx.x;
  const float* xr = x + (size_t)row * D_MODEL;
  float s = 0.f, s2 = 0.f;
  for (int i = threadIdx.x; i < D_MODEL; i += 256) { float v = xr[i]; s += v; s2 += v*v; }
  #pragma unroll
  for (int off = 32; off; off >>= 1) { s += __shfl_down(s, off); s2 += __shfl_down(s2, off); }
  __shared__ float rs[4], rs2[4];
  int wave = threadIdx.x >> 6, lane = threadIdx.x & 63;
  if (lane == 0) { rs[wave] = s; rs2[wave] = s2; }
  __syncthreads();
  s  = rs[0] + rs[1] + rs[2] + rs[3];
  s2 = rs2[0] + rs2[1] + rs2[2] + rs2[3];
  float mean = s * (1.f / D_MODEL);
  float var  = s2 * (1.f / D_MODEL) - mean * mean;
  float r = rsqrtf(var + 1e-5f);
  unsigned short* yr = y + (size_t)row * D_MODEL;
  for (int i = threadIdx.x; i < D_MODEL; i += 256)
    yr[i] = f2bf((xr[i] - mean) * r * w[i] + b[i]);
}

// ---------------- weight conversion fp32 -> bf16 ----------------
__global__ __launch_bounds__(256) void conv_weights(const float* __restrict__ wq,
                                                    const float* __restrict__ wk,
                                                    const float* __restrict__ wv,
                                                    const float* __restrict__ wg,
                                                    const float* __restrict__ wo,
                                                    const float* __restrict__ w1,
                                                    const float* __restrict__ w3,
                                                    const float* __restrict__ w2,
                                                    unsigned short* __restrict__ dst) {
  size_t i = ((size_t)blockIdx.x * 256 + threadIdx.x) * 4;
  const float* src; size_t off;
  if      (i < 262144)  { src = wq; off = i; }
  else if (i < 524288)  { src = wk; off = i - 262144; }
  else if (i < 786432)  { src = wv; off = i - 524288; }
  else if (i < 1048576) { src = wg; off = i - 786432; }
  else if (i < 1310720) { src = wo; off = i - 1048576; }
  else if (i < 2359296) { src = w1; off = i - 1310720; }
  else if (i < 3407872) { src = w3; off = i - 2359296; }
  else                  { src = w2; off = i - 3407872; }
  float4 v = *(const float4*)&src[off];
  unsigned lo = ((unsigned)f2bf(v.y) << 16) | f2bf(v.x);
  unsigned hi = ((unsigned)f2bf(v.w) << 16) | f2bf(v.z);
  *(uint2*)&dst[i] = make_uint2(lo, hi);
}

// ---------------- bf16 MFMA GEMM 128x128: C = A @ B^T ----------------
__global__ __launch_bounds__(256) void gemm_mfma(const unsigned short* __restrict__ A,
                                                 const unsigned short* __restrict__ B,
                                                 float* __restrict__ C,
                                                 int M, int K, int Nout,
                                                 const float* __restrict__ addmat,
                                                 const float* __restrict__ maskrow) {
  __shared__ unsigned short As[128][40];
  __shared__ unsigned short Bs[128][40];
  int t = threadIdx.x;
  int m0 = blockIdx.y * 128, n0 = blockIdx.x * 128;
  int wave = t >> 6, lane = t & 63;
  int wm = (wave >> 1) * 64, wn = (wave & 1) * 64;
  int lm = lane & 15, quad = lane >> 4;
  f32x4_t zero = {0.f, 0.f, 0.f, 0.f};
  f32x4_t acc[4][4];
  #pragma unroll
  for (int i = 0; i < 4; ++i)
    #pragma unroll
    for (int j = 0; j < 4; ++j) acc[i][j] = zero;

  int sr = t >> 2, sc = (t & 3) * 8;
  for (int kk = 0; kk < K; kk += 32) {
    #pragma unroll
    for (int c = 0; c < 2; ++c) {
      int r = sr + c * 64;
      *(uint4*)&As[r][sc] = *(const uint4*)&A[(size_t)(m0 + r) * K + kk + sc];
      *(uint4*)&Bs[r][sc] = *(const uint4*)&B[(size_t)(n0 + r) * K + kk + sc];
    }
    __syncthreads();
    short8 af[4], bfr[4];
    #pragma unroll
    for (int mt = 0; mt < 4; ++mt)
      af[mt] = *(const short8*)&As[wm + mt * 16 + lm][quad * 8];
    #pragma unroll
    for (int nt = 0; nt < 4; ++nt)
      bfr[nt] = *(const short8*)&Bs[wn + nt * 16 + lm][quad * 8];
    #pragma unroll
    for (int mt = 0; mt < 4; ++mt)
      #pragma unroll
      for (int nt = 0; nt < 4; ++nt)
        acc[mt][nt] = __builtin_amdgcn_mfma_f32_16x16x32_bf16(af[mt], bfr[nt], acc[mt][nt], 0, 0, 0);
    __syncthreads();
  }
  #pragma unroll
  for (int mt = 0; mt < 4; ++mt) {
    #pragma unroll
    for (int reg = 0; reg < 4; ++reg) {
      int gm = m0 + wm + mt * 16 + quad * 4 + reg;
      float mk = maskrow ? maskrow[gm] : 0.f;
      #pragma unroll
      for (int nt = 0; nt < 4; ++nt) {
        int gn = n0 + wn + nt * 16 + lm;
        float v = acc[mt][nt][reg];
        if (addmat) v = addmat[(size_t)gm * Nout + gn] + v * mk;
        C[(size_t)gm * Nout + gn] = v;
      }
    }
  }
}

// ---------------- bf16 MFMA GEMM 64x64 ----------------
__global__ __launch_bounds__(256) void gemm_mfma64(const unsigned short* __restrict__ A,
                                                   const unsigned short* __restrict__ B,
                                                   float* __restrict__ C,
                                                   int M, int K, int Nout,
                                                   const float* __restrict__ addmat,
                                                   const float* __restrict__ maskrow) {
  __shared__ unsigned short As[64][40];
  __shared__ unsigned short Bs[64][40];
  int t = threadIdx.x;
  int m0 = blockIdx.y * 64, n0 = blockIdx.x * 64;
  int wave = t >> 6, lane = t & 63;
  int wm = (wave >> 1) * 32, wn = (wave & 1) * 32;
  int lm = lane & 15, quad = lane >> 4;
  f32x4_t zero = {0.f, 0.f, 0.f, 0.f};
  f32x4_t acc[2][2];
  #pragma unroll
  for (int i = 0; i < 2; ++i)
    #pragma unroll
    for (int j = 0; j < 2; ++j) acc[i][j] = zero;

  int sr = t >> 2, sc = (t & 3) * 8;
  for (int kk = 0; kk < K; kk += 32) {
    *(uint4*)&As[sr][sc] = *(const uint4*)&A[(size_t)(m0 + sr) * K + kk + sc];
    *(uint4*)&Bs[sr][sc] = *(const uint4*)&B[(size_t)(n0 + sr) * K + kk + sc];
    __syncthreads();
    short8 af[2], bfr[2];
    #pragma unroll
    for (int mt = 0; mt < 2; ++mt)
      af[mt] = *(const short8*)&As[wm + mt * 16 + lm][quad * 8];
    #pragma unroll
    for (int nt = 0; nt < 2; ++nt)
      bfr[nt] = *(const short8*)&Bs[wn + nt * 16 + lm][quad * 8];
    #pragma unroll
    for (int mt = 0; mt < 2; ++mt)
      #pragma unroll
      for (int nt = 0; nt < 2; ++nt)
        acc[mt][nt] = __builtin_amdgcn_mfma_f32_16x16x32_bf16(af[mt], bfr[nt], acc[mt][nt], 0, 0, 0);
    __syncthreads();
  }
  #pragma unroll
  for (int mt = 0; mt < 2; ++mt) {
    #pragma unroll
    for (int reg = 0; reg < 4; ++reg) {
      int gm = m0 + wm + mt * 16 + quad * 4 + reg;
      float mk = maskrow ? maskrow[gm] : 0.f;
      #pragma unroll
      for (int nt = 0; nt < 2; ++nt) {
        int gn = n0 + wn + nt * 16 + lm;
        float v = acc[mt][nt][reg];
        if (addmat) v = addmat[(size_t)gm * Nout + gn] + v * mk;
        C[(size_t)gm * Nout + gn] = v;
      }
    }
  }
}

// ---------------- per-head LN (no affine), Q and K regions of QKVG (ld=2048) ----------------
__global__ __launch_bounds__(256) void headln(float* __restrict__ base, int ld) {
  int g = blockIdx.x * 256 + threadIdx.x;
  int i = g & (N_TOK - 1), hh = g >> 10;    // hh 0..31
  float* p = base + (size_t)i * ld + hh * DHEAD;
  float s = 0.f, s2 = 0.f;
  #pragma unroll
  for (int k = 0; k < DHEAD; ++k) { float v = p[k]; s += v; s2 += v*v; }
  float m = s * (1.f / DHEAD);
  float var = s2 * (1.f / DHEAD) - m * m;
  float r = rsqrtf(var + 1e-5f);
  #pragma unroll
  for (int k = 0; k < DHEAD; ++k) p[k] = (p[k] - m) * r;
}

// ---------------- build W = exp(logK) via MFMA QK^T; 64x64 tile; XCD-pinned ----------------
__global__ __launch_bounds__(256) void build_W_mfma(const float* __restrict__ Q0,
                                                    const float* __restrict__ K0,
                                                    int ld,
                                                    const float* __restrict__ xres,
                                                    const int* __restrict__ bins,
                                                    const float* __restrict__ posw,
                                                    const float* __restrict__ wdl,
                                                    const float* __restrict__ epsp,
                                                    const float* __restrict__ mask,
                                                    unsigned short* __restrict__ Wm) {
  int b = blockIdx.x;                 // 4096 blocks, 256 tiles per head
  int h = swz_head(b);
  int tile = b >> 4;                  // 0..255
  int i0 = (tile >> 4) * 64, j0 = (tile & 15) * 64;
  __shared__ unsigned short Qs[64][40];
  __shared__ unsigned short Ks[64][40];
  __shared__ unsigned char  binsU[64][68];
  __shared__ unsigned short tileB[64][68];   // result in packed bf16
  __shared__ float xi0[64], xi1[64], xi2[64], xj0[64], xj1[64], xj2[64];
  __shared__ float mi_s[64], mj_s[64], poswS[68];
  int t = threadIdx.x;
  {
    int r = t >> 2, c8 = (t & 3) * 8;
    const float* qsrc = Q0 + (size_t)(i0 + r) * ld + h * DHEAD + c8;
    const float* ksrc = K0 + (size_t)(j0 + r) * ld + h * DHEAD + c8;
    float4 qa = *(const float4*)qsrc, qb = *(const float4*)(qsrc + 4);
    float4 ka = *(const float4*)ksrc, kb = *(const float4*)(ksrc + 4);
    unsigned short* qd = &Qs[r][c8];
    qd[0]=f2bf(qa.x); qd[1]=f2bf(qa.y); qd[2]=f2bf(qa.z); qd[3]=f2bf(qa.w);
    qd[4]=f2bf(qb.x); qd[5]=f2bf(qb.y); qd[6]=f2bf(qb.z); qd[7]=f2bf(qb.w);
    unsigned short* kd = &Ks[r][c8];
    kd[0]=f2bf(ka.x); kd[1]=f2bf(ka.y); kd[2]=f2bf(ka.z); kd[3]=f2bf(ka.w);
    kd[4]=f2bf(kb.x); kd[5]=f2bf(kb.y); kd[6]=f2bf(kb.z); kd[7]=f2bf(kb.w);
  }
  {
    int rb = t >> 2, cb = (t & 3) * 16;
    const int* bsrc = bins + (size_t)(i0 + rb) * N_TOK + j0 + cb;
    #pragma unroll
    for (int c = 0; c < 4; ++c) {
      int4 b4 = *(const int4*)(bsrc + c * 4);
      uchar4 u4 = make_uchar4((unsigned char)b4.x, (unsigned char)b4.y,
                              (unsigned char)b4.z, (unsigned char)b4.w);
      *(uchar4*)&binsU[rb][cb + c * 4] = u4;
    }
  }
  if (t < 64) {
    xi0[t] = xres[(i0 + t) * 3 + 0]; xi1[t] = xres[(i0 + t) * 3 + 1]; xi2[t] = xres[(i0 + t) * 3 + 2];
    xj0[t] = xres[(j0 + t) * 3 + 0]; xj1[t] = xres[(j0 + t) * 3 + 1]; xj2[t] = xres[(j0 + t) * 3 + 2];
    mi_s[t] = mask[i0 + t]; mj_s[t] = mask[j0 + t];
  }
  if (t >= 64 && t < 132) poswS[t - 64] = posw[(t - 64) * H_HEADS + h];
  __syncthreads();
  int wave = t >> 6, lane = t & 63;
  int lm = lane & 15, quad = lane >> 4;
  int wm = (wave >> 1) * 32, wn = (wave & 1) * 32;
  f32x4_t zero = {0.f, 0.f, 0.f, 0.f};
  f32x4_t acc[2][2] = {{zero, zero}, {zero, zero}};
  short8 af[2], bfr[2];
  #pragma unroll
  for (int mt = 0; mt < 2; ++mt) af[mt] = *(const short8*)&Qs[wm + mt * 16 + lm][quad * 8];
  #pragma unroll
  for (int nt = 0; nt < 2; ++nt) bfr[nt] = *(const short8*)&Ks[wn + nt * 16 + lm][quad * 8];
  #pragma unroll
  for (int mt = 0; mt < 2; ++mt)
    #pragma unroll
    for (int nt = 0; nt < 2; ++nt)
      acc[mt][nt] = __builtin_amdgcn_mfma_f32_16x16x32_bf16(af[mt], bfr[nt], acc[mt][nt], 0, 0, 0);
  float wd = sigmoidf_(wdl[h]);
  float inv_eps = 1.f / epsp[h];
  const float inv_sqrt = 0.17677669529663687f; // 1/sqrt(32)
  #pragma unroll
  for (int mt = 0; mt < 2; ++mt) {
    #pragma unroll
    for (int nt = 0; nt < 2; ++nt) {
      int col = wn + nt * 16 + lm;
      float xj0v = xj0[col], xj1v = xj1[col], xj2v = xj2[col], mj = mj_s[col];
      #pragma unroll
      for (int reg = 0; reg < 4; ++reg) {
        int row = wm + mt * 16 + quad * 4 + reg;
        float d0 = xi0[row] - xj0v, d1 = xi1[row] - xj1v, d2c = xi2[row] - xj2v;
        float d2 = d0*d0 + d1*d1 + d2c*d2c;
        float bias = poswS[binsU[row][col]];
        float logit = acc[mt][nt][reg] * inv_sqrt + bias - wd * d2 * 0.01f;
        float outv = (mi_s[row] * mj > 0.f) ? __expf(logit * inv_eps) : 0.f;
        tileB[row][col] = f2bf(outv);
      }
    }
  }
  __syncthreads();
  // row-major write only (no transposed copy needed anymore)
  {
    int r = t >> 2, cb = (t & 3) * 16;
    unsigned short* dst = Wm + ((size_t)h * N_TOK + (i0 + r)) * N_TOK + j0 + cb;
    uint4 w0 = *(uint4*)&tileB[r][cb];
    uint4 w1v = *(uint4*)&tileB[r][cb + 8];
    *(uint4*)dst = w0;
    *(uint4*)(dst + 8) = w1v;
  }
}

// ---------------- build VxT: Vxt[h][48][1024] bf16 = [V^T ; x^T ; ones ; pad] ----------------
__global__ __launch_bounds__(256) void build_vxt(const float* __restrict__ QKVG_,
                                                 const float* __restrict__ xres,
                                                 unsigned short* __restrict__ Vxt) {
  int h = blockIdx.x, j0 = blockIdx.y * 64;
  __shared__ float T[48][72];
  int t = threadIdx.x;
  {
    int j = t >> 2, c8 = (t & 3) * 8;
    const float* src = QKVG_ + (size_t)(j0 + j) * 2048 + 1024 + h * DHEAD + c8;
    float4 a = *(const float4*)src, b = *(const float4*)(src + 4);
    T[c8 + 0][j] = a.x; T[c8 + 1][j] = a.y; T[c8 + 2][j] = a.z; T[c8 + 3][j] = a.w;
    T[c8 + 4][j] = b.x; T[c8 + 5][j] = b.y; T[c8 + 6][j] = b.z; T[c8 + 7][j] = b.w;
  }
  if (t < 64) {
    int j = t;
    T[32][j] = xres[(j0 + j) * 3 + 0];
    T[33][j] = xres[(j0 + j) * 3 + 1];
    T[34][j] = xres[(j0 + j) * 3 + 2];
    T[35][j] = 1.f;
    #pragma unroll
    for (int d = 36; d < 48; ++d) T[d][j] = 0.f;
  }
  __syncthreads();
  for (int task = t; task < 384; task += 256) {
    int d = task >> 3, jc = (task & 7) * 8;
    float* s = &T[d][jc];
    unsigned a0 = ((unsigned)f2bf(s[1]) << 16) | f2bf(s[0]);
    unsigned a1 = ((unsigned)f2bf(s[3]) << 16) | f2bf(s[2]);
    unsigned a2 = ((unsigned)f2bf(s[5]) << 16) | f2bf(s[4]);
    unsigned a3 = ((unsigned)f2bf(s[7]) << 16) | f2bf(s[6]);
    *(uint4*)(Vxt + ((size_t)h * 48 + d) * N_TOK + j0 + jc) = make_uint4(a0, a1, a2, a3);
  }
}

// ---------------- Sinkhorn init: log-marginals + exp warm-start ----------------
__global__ __launch_bounds__(256) void sink_init(const float* __restrict__ mu,
                                                 const float* __restrict__ nu,
                                                 const float* __restrict__ lv0,
                                                 float* __restrict__ lmu,
                                                 float* __restrict__ lnu,
                                                 float* __restrict__ vtilde) {
  int i = blockIdx.x * 256 + threadIdx.x;   // 16384
  lmu[i] = __logf(fmaxf(mu[i], 1e-8f));
  lnu[i] = __logf(fmaxf(nu[i], 1e-8f));
  vtilde[i] = __expf(lv0[i]);
}

// ---------------- Sinkhorn row pass (XCD-pinned): s_i = Sum_j W[i,j] * vtilde[j] ---------
__global__ __launch_bounds__(256) void sink_row(const unsigned short* __restrict__ Wm,
                                                const float* __restrict__ vtilde,
                                                const float* __restrict__ lmu,
                                                float* __restrict__ outlog,
                                                float* __restrict__ outexp,
                                                const float* __restrict__ epsp) {
  int b = blockIdx.x;                        // 1024 blocks, 64 per head
  int h = swz_head(b);
  int grp = b >> 4;                          // 0..63 (16 rows each)
  int t = threadIdx.x;
  int wave = t >> 6, lane = t & 63;
  int sub = lane >> 4, l16 = lane & 15;      // 4 rows per wave, 16 lanes per row
  int i = grp * 16 + wave * 4 + sub;         // row within head
  const uint4* p = (const uint4*)(Wm + ((size_t)h * N_TOK + i) * N_TOK);
  const float4* vt = (const float4*)(vtilde + h * N_TOK);
  float s8[8];
  #pragma unroll
  for (int c = 0; c < 8; ++c) s8[c] = 0.f;
  #pragma unroll
  for (int it = 0; it < 8; ++it) {
    int j0 = it * 128 + l16 * 8;
    uint4 u = p[j0 >> 3];
    float4 va = vt[j0 >> 2];
    float4 vb = vt[(j0 >> 2) + 1];
    s8[0] += bf_lo(u.x) * va.x; s8[1] += bf_hi(u.x) * va.y;
    s8[2] += bf_lo(u.y) * va.z; s8[3] += bf_hi(u.y) * va.w;
    s8[4] += bf_lo(u.z) * vb.x; s8[5] += bf_hi(u.z) * vb.y;
    s8[6] += bf_lo(u.w) * vb.z; s8[7] += bf_hi(u.w) * vb.w;
  }
  float s = ((s8[0] + s8[1]) + (s8[2] + s8[3])) + ((s8[4] + s8[5]) + (s8[6] + s8[7]));
  #pragma unroll
  for (int off = 1; off <= 8; off <<= 1) s += __shfl_xor(s, off);
  if (l16 == 0) {
    float fi = 1.f / (1.f + epsp[h]);        // LAM=1
    float val = fi * (lmu[h * N_TOK + i] - __logf(fmaxf(s, 1e-35f)));
    outlog[h * N_TOK + i] = val;
    outexp[h * N_TOK + i] = __expf(val);
  }
}

// ---------------- Sinkhorn col pass from ROW-major W (coalesced), XCD-pinned -------------
// s_j = Sum_i W[i,j] * utilde[i] ; block = (head, 64-col tile), 16 i-groups x 16 j-lanes
__global__ __launch_bounds__(256) void sink_col(const unsigned short* __restrict__ Wm,
                                                const float* __restrict__ utilde,
                                                const float* __restrict__ lnu,
                                                float* __restrict__ outlog,
                                                float* __restrict__ outexp,
                                                const float* __restrict__ epsp) {
  int b = blockIdx.x;                        // 256 blocks, 16 col-tiles per head
  int h = swz_head(b);
  int j0 = (b >> 4) * 64;
  int t = threadIdx.x;
  int jl = (t & 15) * 4;                     // 4 cols per thread via uint2
  int ig = t >> 4;                           // 16 i-groups of 64 rows
  const unsigned short* base = Wm + ((size_t)h * N_TOK + ig * 64) * N_TOK + j0 + jl;
  const float* ut = utilde + h * N_TOK + ig * 64;
  float a0 = 0.f, a1 = 0.f, a2 = 0.f, a3 = 0.f;
  #pragma unroll 8
  for (int r = 0; r < 64; ++r) {
    uint2 w = *(const uint2*)(base + (size_t)r * N_TOK);
    float u = ut[r];
    a0 += bf_lo(w.x) * u; a1 += bf_hi(w.x) * u;
    a2 += bf_lo(w.y) * u; a3 += bf_hi(w.y) * u;
  }
  __shared__ float red[16][68];
  red[ig][jl + 0] = a0; red[ig][jl + 1] = a1;
  red[ig][jl + 2] = a2; red[ig][jl + 3] = a3;
  __syncthreads();
  if (t < 64) {
    float s = 0.f;
    #pragma unroll
    for (int g = 0; g < 16; ++g) s += red[g][t];
    int j = j0 + t;
    float fi = 1.f / (1.f + epsp[h]);
    float val = fi * (lnu[h * N_TOK + j] - __logf(fmaxf(s, 1e-35f)));
    outlog[h * N_TOK + j] = val;
    outexp[h * N_TOK + j] = __expf(val);
  }
}

// ---------------- MFMA finalize (linear): A-frag = W * vtilde; B = Vxt; XCD-pinned -------
__global__ __launch_bounds__(256) void finalize_mfma(const unsigned short* __restrict__ Wm,
                                                     const float* __restrict__ vtilde,
                                                     const unsigned short* __restrict__ Vxt,
                                                     const float* __restrict__ G0, int ld,
                                                     const float* __restrict__ xres,
                                                     const float* __restrict__ mask,
                                                     unsigned short* __restrict__ o,
                                                     float* __restrict__ x_out,
                                                     const float* __restrict__ gamma) {
  int b = blockIdx.x;                        // 256 blocks: 16 m-tiles per head
  int h = swz_head(b);
  int mt = b >> 4;
  int t = threadIdx.x, wave = t >> 6, lane = t & 63;
  int lm = lane & 15, quad = lane >> 4;
  __shared__ float vts[N_TOK];
  ((float4*)vts)[t] = ((const float4*)(vtilde + h * N_TOK))[t];
  __syncthreads();
  int arow = mt * 64 + wave * 16 + lm;
  const unsigned short* Kr = Wm + ((size_t)h * N_TOK + arow) * N_TOK + quad * 8;
  const unsigned short* Bb = Vxt + (size_t)h * 48 * N_TOK + quad * 8;
  f32x4_t zero = {0.f, 0.f, 0.f, 0.f};
  f32x4_t acc[3] = {zero, zero, zero};
  for (int kk = 0; kk < N_TOK; kk += 32) {
    uint4 u = *(const uint4*)(Kr + kk);
    float4 la = *(const float4*)&vts[kk + quad * 8];
    float4 lb = *(const float4*)&vts[kk + quad * 8 + 4];
    float p0 = bf_lo(u.x) * la.x;
    float p1 = bf_hi(u.x) * la.y;
    float p2 = bf_lo(u.y) * la.z;
    float p3 = bf_hi(u.y) * la.w;
    float p4 = bf_lo(u.z) * lb.x;
    float p5 = bf_hi(u.z) * lb.y;
    float p6 = bf_lo(u.w) * lb.z;
    float p7 = bf_hi(u.w) * lb.w;
    union { uint4 u4; short8 s8; } pk;
    pk.u4 = make_uint4(((unsigned)f2bf(p1) << 16) | f2bf(p0),
                       ((unsigned)f2bf(p3) << 16) | f2bf(p2),
                       ((unsigned)f2bf(p5) << 16) | f2bf(p4),
                       ((unsigned)f2bf(p7) << 16) | f2bf(p6));
    short8 af = pk.s8;
    #pragma unroll
    for (int nt = 0; nt < 3; ++nt) {
      short8 bfrag = *(const short8*)(Bb + (size_t)(nt * 16 + lm) * N_TOK + kk);
      acc[nt] = __builtin_amdgcn_mfma_f32_16x16x32_bf16(af, bfrag, acc[nt], 0, 0, 0);
    }
  }
  float inv[4];
  #pragma unroll
  for (int reg = 0; reg < 4; ++reg) {
    float rsum = __shfl(acc[2][reg], (quad << 4) | 3, 64);
    inv[reg] = 1.f / fmaxf(rsum, 1e-30f);
  }
  #pragma unroll
  for (int nt = 0; nt < 2; ++nt) {
    int c = nt * 16 + lm;
    #pragma unroll
    for (int reg = 0; reg < 4; ++reg) {
      int r = mt * 64 + wave * 16 + quad * 4 + reg;
      float gv = G0[(size_t)r * ld + h * DHEAD + c];
      float ovl = acc[nt][reg] * inv[reg] * sigmoidf_(gv);
      o[(size_t)r * D_MODEL + h * DHEAD + c] = f2bf(ovl);
    }
  }
  if (lm < 3) {
    float tg = tanhf(gamma[h]) * (1.f / H_HEADS);
    #pragma unroll
    for (int reg = 0; reg < 4; ++reg) {
      int r = mt * 64 + wave * 16 + quad * 4 + reg;
      float xc = acc[2][reg] * inv[reg];
      float mi = mask[r];
      atomicAdd(&x_out[r * 3 + lm], tg * mi * (xres[r * 3 + lm] - xc));
    }
  }
}

// ---------------- silu+mul from fused ffab (1024x4096) -> bf16 (1024x2048) ----------------
__global__ __launch_bounds__(256) void silu_mul_bf(const float* __restrict__ ffab,
                                                   unsigned short* __restrict__ out, int n) {
  int i = blockIdx.x * 256 + threadIdx.x;
  if (i >= n) return;
  int row = i >> 11, col = i & 2047;
  float a = ffab[(size_t)row * 4096 + col];
  float bb = ffab[(size_t)row * 4096 + 2048 + col];
  out[i] = f2bf(a * sigmoidf_(a) * bb);
}

__global__ __launch_bounds__(256) void copyf(const float* __restrict__ src,
                                             float* __restrict__ dst, int n) {
  int i = blockIdx.x * 256 + threadIdx.x;
  if (i < n) dst[i] = src[i];
}

extern "C" void kernel_launch(void* const* d_in, const int* in_sizes, int n_in,
                              void* d_out, int out_size, void* d_ws, size_t ws_size,
                              hipStream_t stream) {
  const float* h_in  = (const float*)d_in[0];
  const float* x_res = (const float*)d_in[1];
  const float* mu    = (const float*)d_in[2];
  const float* nu    = (const float*)d_in[3];
  const float* lu0   = (const float*)d_in[4];
  const float* lv0   = (const float*)d_in[5];
  const float* mask  = (const float*)d_in[6];
  const float* lnw   = (const float*)d_in[7];
  const float* lnb   = (const float*)d_in[8];
  const float* wq    = (const float*)d_in[9];
  const float* wk    = (const float*)d_in[10];
  const float* wv    = (const float*)d_in[11];
  const float* wg    = (const float*)d_in[12];
  const float* wo    = (const float*)d_in[13];
  const float* gamma = (const float*)d_in[14];
  const float* posw  = (const float*)d_in[15];
  const float* wdl   = (const float*)d_in[16];
  const float* lnfw  = (const float*)d_in[17];
  const float* lnfb  = (const float*)d_in[18];
  const float* w1    = (const float*)d_in[19];
  const float* w3    = (const float*)d_in[20];
  const float* w2    = (const float*)d_in[21];
  const int*   bins  = (const int*)d_in[22];
  const float* eps   = (const float*)d_in[23];

  float* out    = (float*)d_out;
  float* out_h  = out;                     // 1024*512
  float* out_x  = out + 524288;            // 1024*3
  float* out_lu = out + 527360;            // 16*1024
  float* out_lv = out + 543744;            // 16*1024

  float* ws = (float*)d_ws;
  float* QKVG  = ws;                       // 1024 x 2048 (Q|K|V|G)
  float* h_mid = ws + 2097152;             // 1024 x 512
  unsigned short* U = (unsigned short*)(ws + 2621440);
  unsigned short* h_n_b  = U;              // 1024x512
  unsigned short* h2_b   = U + 524288;     // 1024x512
  unsigned short* o_b    = U + 1048576;    // 1024x512
  unsigned short* wB     = U + 1572864;    // 4456448 bf16 weights
  unsigned short* Wb   = (unsigned short*)(ws + 5636096);  // H*N*N bf16 (exp domain, 32 MB)
  unsigned short* Vxt  = Wb + (size_t)H_HEADS * N_TOK * N_TOK; // 16*48*1024 bf16
  float* vtilde = (float*)(Vxt + 786432);   // 16384 floats
  float* utilde = vtilde + 16384;
  float* lmu    = utilde + 16384;
  float* lnu    = lmu + 16384;
  unsigned short* ff_b = (unsigned short*)(lnu + 16384);  // 1024x2048 bf16 (4 MB)
  float* ffab          = (float*)Wb;        // reuse W region after finalize (16 MB)

  unsigned short* wQKVGb = wB;                 // 2048 x 512
  unsigned short* wob    = wB + 1048576;       // 512 x 512
  unsigned short* wFFb   = wB + 1310720;       // 4096 x 512
  unsigned short* w2b    = wB + 3407872;       // 512 x 2048

  dim3 b256(256);

  conv_weights<<<4352, b256, 0, stream>>>(wq, wk, wv, wg, wo, w1, w3, w2, wB);
  ln_rows<<<N_TOK, b256, 0, stream>>>(h_in, lnw, lnb, h_n_b);

  gemm_mfma<<<dim3(16, 8), b256, 0, stream>>>(h_n_b, wQKVGb, QKVG,
                                              N_TOK, D_MODEL, 2048, nullptr, nullptr);

  headln<<<128, b256, 0, stream>>>(QKVG, 2048);

  copyf<<<12, b256, 0, stream>>>(x_res, out_x, N_TOK * 3);

  build_W_mfma<<<4096, b256, 0, stream>>>(
      QKVG, QKVG + 512, 2048, x_res, bins, posw, wdl, eps, mask, Wb);
  build_vxt<<<dim3(H_HEADS, N_TOK / 64), b256, 0, stream>>>(QKVG, x_res, Vxt);

  sink_init<<<64, b256, 0, stream>>>(mu, nu, lv0, lmu, lnu, vtilde);
  for (int it = 0; it < 20; ++it) {
    sink_row<<<1024, b256, 0, stream>>>(Wb, vtilde, lmu, out_lu, utilde, eps);
    sink_col<<<256, b256, 0, stream>>>(Wb, utilde, lnu, out_lv, vtilde, eps);
  }

  finalize_mfma<<<256, b256, 0, stream>>>(
      Wb, vtilde, Vxt, QKVG + 1536, 2048, x_res, mask, o_b, out_x, gamma);

  gemm_mfma64<<<dim3(8, 16), b256, 0, stream>>>(o_b, wob, h_mid,
                                                N_TOK, D_MODEL, D_MODEL, h_in, mask);

  ln_rows<<<N_TOK, b256, 0, stream>>>(h_mid, lnfw, lnfb, h2_b);

  gemm_mfma<<<dim3(32, 8), b256, 0, stream>>>(h2_b, wFFb, ffab,
                                              N_TOK, D_MODEL, 4096, nullptr, nullptr);
  silu_mul_bf<<<(N_TOK * DFF) / 256, b256, 0, stream>>>(ffab, ff_b, N_TOK * DFF);

  gemm_mfma64<<<dim3(8, 16), b256, 0, stream>>>(ff_b, w2b, out_h,
                                                N_TOK, DFF, D_MODEL, h_mid, mask);
}